// Round 2
// baseline (3409.457 us; speedup 1.0000x reference)
//
#include <hip/hip_runtime.h>
#include <hip/hip_bf16.h>
#include <math.h>

// ---------------------------------------------------------------------------
// VQGAN forward, round 11.
//  - mfenc v4: 2 output rows (oh0, oh0+1) per block.
//    * Weight fragments (A) are shared by both rows -> 2x MFMA per weight
//      byte (was the zero-reuse bottleneck; round-10 counters: MfmaUtil 20%,
//      occupancy 12%, all pipes idle -> latency-bound on the weight stream).
//    * 6 staged input rows serve 2 output rows (was 4 rows per 1) -> staging
//      per output -25%.
//    * LDS 78336 B -> 2 blocks/CU; grid halves (enc1 1024, enc2 512 blocks).
//    * Same staged bits, weight bits, and per-acc-element accumulation order
//      as round 9/10 -> z bit-identical -> idx exact.
//    * s_setprio(1) around the tap-compute phase (T5).
//  - decoder: round-7/8 kernels unchanged.
// d_out = [recon 16*3*256*256 | q 16*32*32*32 | idx-as-float 16384]
// ---------------------------------------------------------------------------

#define EPS 1e-5f
typedef unsigned short ushort_t;
typedef unsigned int uint32;
typedef __attribute__((ext_vector_type(8))) short bf16x8;
typedef __attribute__((ext_vector_type(4))) float f32x4;
typedef __attribute__((ext_vector_type(4))) unsigned int u32x4;

__device__ __forceinline__ ushort_t f2bf(float x) {
    __hip_bfloat16 h = __float2bfloat16(x);
    return __builtin_bit_cast(ushort_t, h);
}
__device__ __forceinline__ float bf2f(ushort_t u) {
    __hip_bfloat16 h = __builtin_bit_cast(__hip_bfloat16, u);
    return __bfloat162float(h);
}
template <int NS>
__device__ __forceinline__ void splitNS(float x, ushort_t* p) {
    float r = x;
    #pragma unroll
    for (int s = 0; s < NS; ++s) {
        ushort_t u = f2bf(r);
        p[s] = u;
        if (s + 1 < NS) r -= bf2f(u);
    }
}

// ============ encoder weight pre-split: fragment-order layout ==============
// o[(((((s*16+tap)*KCH + kc)*CB + cb)*64 + lane)*8 + e]
//   kc = ci>>5, q = (ci>>3)&3, e = ci&7, cb = co>>4, l15 = co&15,
//   lane = q*16 + l15  (exactly the mfenc wave lane id)
template <int Cout, int Cin>
__global__ __launch_bounds__(256) void wsplit_enc(
    const float* __restrict__ w, ushort_t* __restrict__ o)
{
    constexpr int KCH = Cin / 32, CB = Cout / 16;
    int idx = blockIdx.x * 256 + threadIdx.x;
    if (idx >= Cout * Cin * 16) return;
    int tap = idx & 15;
    int ci  = (idx >> 4) % Cin;
    int co  = (idx >> 4) / Cin;
    ushort_t sp[3];
    splitNS<3>(w[idx], sp);
    const int kc = ci >> 5, q = (ci >> 3) & 3, e = ci & 7;
    const int cb = co >> 4, l15 = co & 15;
    const int lane = q * 16 + l15;
    #pragma unroll
    for (int s = 0; s < 3; ++s)
        o[((((size_t)(s * 16 + tap) * KCH + kc) * CB + cb) * 64 + lane) * 8 + e] = sp[s];
}

// A-fragment loader: one coalesced 1KB segment per (cf,s) wave load.
template <int KCH, int CB>
__device__ __forceinline__ void ldaf(bf16x8 (&dst)[4][3],
    const ushort_t* __restrict__ wsp_t, int kc, int tap)
{
    #pragma unroll
    for (int cf = 0; cf < 4; ++cf)
        #pragma unroll
        for (int s = 0; s < 3; ++s)
            dst[cf][s] = *(const bf16x8*)(wsp_t +
                ((size_t)((s * 16 + tap) * KCH + kc) * CB + cf) * 512);
}

// ================= MFMA encoder conv k4 s2 p1: tap-GEMMs ===================
// v4 geometry: TWO oh rows per block (oh0, oh0+1), 32 m, 256 co, k=ci, KC=32.
// LDS: [s(3)][row(6)][ciq(4)][cpos(68)][cie(8)] ushort; col c -> cpos =
// (c>>1)+(c&1)*34. Staging identical bit pattern to round 9/10 per row.
// Weight frags double-buffered in registers, prefetched 1 tap ahead, and
// shared across both output rows (2x arithmetic intensity on the A stream).
template <int Cin, int Cout, int Hin, int Win>
__global__ __launch_bounds__(256) void mfenc(
    const float* __restrict__ x, const ushort_t* __restrict__ wsp,
    const float* __restrict__ bias, float* __restrict__ y)
{
    constexpr int Hout = Hin / 2, Wout = Win / 2;
    constexpr int MB = 32;
    constexpr int MT = Wout / MB;
    constexpr int NCOL = 66;
    constexpr int KC = 32;
    constexpr int KCH = Cin / 32;
    constexpr int CB = Cout / 16;
    constexpr int NR = 6;                          // staged input rows
    __shared__ ushort_t Xs[3 * NR * 4 * 68 * 8];   // 78336 B
    uint32* __restrict__ Xs32 = (uint32*)Xs;

    const int n  = blockIdx.z;
    const int oh0 = 2 * (blockIdx.x / MT);
    const int mt = blockIdx.x % MT;
    const int M0 = mt * MB;
    const int co_base = blockIdx.y * 256;
    const int tid = threadIdx.x;
    const int wv = tid >> 6, lane = tid & 63;
    const int q = lane >> 4, l15 = lane & 15;
    const int co_w0 = co_base + wv * 64;
    const int cb0 = (co_base >> 4) + wv * 4;
    const ushort_t* __restrict__ wsp_t = wsp + ((size_t)cb0 * 64 + lane) * 8;

    int ro[NR]; bool rv[NR];
    #pragma unroll
    for (int k = 0; k < NR; ++k) {
        int r = 2 * oh0 - 1 + k;
        rv[k] = (r >= 0) && (r < Hin);
        ro[k] = rv[k] ? r : 0;
    }

    f32x4 acc[4][2][2];                            // [cf][mf][ohh]
    #pragma unroll
    for (int a = 0; a < 4; ++a)
        #pragma unroll
        for (int b = 0; b < 2; ++b)
            #pragma unroll
            for (int h2 = 0; h2 < 2; ++h2) acc[a][b][h2] = (f32x4){0.f, 0.f, 0.f, 0.f};

    // staging ids: ci-pair + column-group
    const int p16  = tid >> 4;            // 0..15 -> ci pair (2*p16, 2*p16+1)
    const int cg   = tid & 15;            // column group
    const int sciq = p16 >> 2;            // ci octet 0..3
    const int cieP = p16 & 3;             // dword index within octet

    bf16x8 afA[4][3], afB[4][3];
    ldaf<KCH, CB>(afA, wsp_t, 0, 0);

    for (int ci0 = 0; ci0 < Cin; ci0 += KC) {
        const int kc = ci0 >> 5;
        if (ci0) __syncthreads();
        {
            const float* pl0 = x + (size_t)(n * Cin + ci0 + 2 * p16) * Hin * Win;
            const float* pl1 = pl0 + (size_t)Hin * Win;
            #pragma unroll
            for (int r = 0; r < NR; ++r) {
                const float* rp0 = pl0 + (size_t)ro[r] * Win;
                const float* rp1 = pl1 + (size_t)ro[r] * Win;
                const bool rok = rv[r];
                for (int c = cg; c < NCOL; c += 16) {
                    const int gc = 2 * M0 - 1 + c;
                    const bool ok = rok && (gc >= 0) && (gc < Win);
                    float v0 = ok ? rp0[gc] : 0.f;
                    float v1 = ok ? rp1[gc] : 0.f;
                    ushort_t s0[3], s1[3];
                    splitNS<3>(v0, s0);
                    splitNS<3>(v1, s1);
                    const int cpos = (c >> 1) + (c & 1) * 34;
                    #pragma unroll
                    for (int s = 0; s < 3; ++s)
                        Xs32[((((s * NR + r) * 4 + sciq) * 68) + cpos) * 4 + cieP] =
                            (uint32)s0[s] | ((uint32)s1[s] << 16);
                }
            }
        }
        __syncthreads();

        __builtin_amdgcn_s_setprio(1);
        #pragma unroll
        for (int tap = 0; tap < 16; ++tap) {
            bf16x8 (&cur)[4][3] = (tap & 1) ? afB : afA;
            bf16x8 (&nxt)[4][3] = (tap & 1) ? afA : afB;
            // prefetch next tap's (or next chunk's tap-0) weight fragments
            if (tap < 15) {
                ldaf<KCH, CB>(nxt, wsp_t, kc, tap + 1);
            } else if (kc + 1 < KCH) {
                ldaf<KCH, CB>(nxt, wsp_t, kc + 1, 0);
            }

            const int kh = tap >> 2, kw = tap & 3;
            bf16x8 bx[2][2][3];                     // [ohh][mf][s]
            const int cpbase = (kw >> 1) + (kw & 1) * 34;
            #pragma unroll
            for (int h2 = 0; h2 < 2; ++h2) {
                const int row = kh + 2 * h2;
                #pragma unroll
                for (int mf = 0; mf < 2; ++mf) {
                    const int cpos = (mf * 16 + l15) + cpbase;
                    #pragma unroll
                    for (int s = 0; s < 3; ++s)
                        bx[h2][mf][s] = *(const bf16x8*)(&Xs[((((s * NR + row) * 4 + q) * 68) + cpos) * 8]);
                }
            }
            #pragma unroll
            for (int sa = 0; sa < 3; ++sa)
                #pragma unroll
                for (int sb = 0; sb < 3; ++sb) {
                    if (sa + sb >= 3) continue;
                    #pragma unroll
                    for (int cf = 0; cf < 4; ++cf)
                        #pragma unroll
                        for (int mf = 0; mf < 2; ++mf)
                            #pragma unroll
                            for (int h2 = 0; h2 < 2; ++h2)
                                acc[cf][mf][h2] = __builtin_amdgcn_mfma_f32_16x16x32_bf16(
                                    cur[cf][sa], bx[h2][mf][sb], acc[cf][mf][h2], 0, 0, 0);
                }
        }
        __builtin_amdgcn_s_setprio(0);
    }

    #pragma unroll
    for (int cf = 0; cf < 4; ++cf)
        #pragma unroll
        for (int mf = 0; mf < 2; ++mf) {
            const int ow = M0 + mf * 16 + l15;
            #pragma unroll
            for (int h2 = 0; h2 < 2; ++h2) {
                const int oh = oh0 + h2;
                #pragma unroll
                for (int rg = 0; rg < 4; ++rg) {
                    const int co = co_w0 + cf * 16 + q * 4 + rg;
                    y[(((size_t)n * Cout + co) * Hout + oh) * Wout + ow] =
                        acc[cf][mf][h2][rg] + bias[co];
                }
            }
        }
}

// ============== decoder weight pre-split (round-7, NS=1) ===================
template <int Cout, int Cin, int NS>
__global__ __launch_bounds__(256) void wsplit_convt(
    const float* __restrict__ w, ushort_t* __restrict__ o)
{
    int idx = blockIdx.x * 256 + threadIdx.x;
    if (idx >= 4 * Cout * Cin * 4) return;
    int b  = idx & 1;
    int a  = (idx >> 1) & 1;
    int ci = (idx >> 2) % Cin;
    int co = ((idx >> 2) / Cin) % Cout;
    int p  = ((idx >> 2) / Cin) / Cout;
    int di = p >> 1, dj = p & 1;
    float v = w[(((size_t)co * Cin + ci) * 4 + (2 * a + di)) * 4 + (2 * b + dj)];
    ushort_t sp[NS];
    splitNS<NS>(v, sp);
    #pragma unroll
    for (int s = 0; s < NS; ++s)
        o[(((size_t)(s * 4 + p) * Cout + co) * Cin + ci) * 4 + a * 2 + b] = sp[s];
}

// ================= MFMA convT (round-7, unchanged) =========================
template <int Cin, int Cout, int Hin, int Win, int CO_WAVES, int M_WAVES, int KC, int NS>
__global__ __launch_bounds__(256) void mfconvt(
    const float* __restrict__ x, const ushort_t* __restrict__ wsp,
    const float* __restrict__ bias, float* __restrict__ y)
{
    constexpr int NDp = Win / 2 + 2;
    constexpr int CO_B = CO_WAVES * 32;
    static_assert(CO_WAVES * M_WAVES == 4, "4 waves");
    static_assert(M_WAVES * 32 == Win, "block spans full row");
    static_assert(KC % 8 == 0, "k-step = 8 ci");
    __shared__ unsigned int Xs[NS * KC * 2 * 2 * NDp];

    const int bi = blockIdx.x;
    const int i = bi >> 2;
    const int p = bi & 3;
    const int di = p >> 1, dj = p & 1;
    const int n = blockIdx.z;
    const int co_base = blockIdx.y * CO_B;
    const int tid = threadIdx.x;
    const int wv = tid >> 6, lane = tid & 63;
    const int cw = wv / M_WAVES, mw = wv % M_WAVES;
    const int co_w0 = co_base + cw * 32;
    const int m_w0 = mw * 32;
    const int q = lane >> 4, l15 = lane & 15;

    const int r0 = i - 1 + di, r1 = i + di;
    const bool v0 = (r0 >= 0), v1 = (r1 < Hin);
    const int r0c = v0 ? r0 : 0, r1c = v1 ? r1 : 0;

    f32x4 acc[2][2];
    #pragma unroll
    for (int a = 0; a < 2; ++a)
        #pragma unroll
        for (int b = 0; b < 2; ++b) acc[a][b] = (f32x4){0.f, 0.f, 0.f, 0.f};

    constexpr int SEGW = Win / 4;
    constexpr int SEGS = KC * 2 * SEGW;

    for (int ci0 = 0; ci0 < Cin; ci0 += KC) {
        if (ci0) __syncthreads();
        for (int seg = tid; seg < SEGS; seg += 256) {
            const int c0 = (seg % SEGW) * 4;
            const int rem = seg / SEGW;
            const int a = rem & 1;
            const int ci = rem >> 1;
            const bool rok = a ? v1 : v0;
            const int gr = a ? r1c : r0c;
            const float* rp = x + ((size_t)(n * Cin + ci0 + ci) * Hin + gr) * Win;
            float v[5];
            v[0] = (rok && c0 > 0) ? rp[c0 - 1] : 0.f;
            #pragma unroll
            for (int t = 1; t < 5; ++t) v[t] = rok ? rp[c0 + t - 1] : 0.f;
            ushort_t sp[5][NS];
            #pragma unroll
            for (int t = 0; t < 5; ++t) splitNS<NS>(v[t], sp[t]);
            #pragma unroll
            for (int s = 0; s < NS; ++s) {
                const int base = ((s * KC + ci) * 2 + a) * 2 * NDp;
                Xs[base + (c0 >> 1)]           = (unsigned)sp[1][s] | ((unsigned)sp[2][s] << 16);
                Xs[base + (c0 >> 1) + 1]       = (unsigned)sp[3][s] | ((unsigned)sp[4][s] << 16);
                Xs[base + NDp + (c0 >> 1)]     = (unsigned)sp[0][s] | ((unsigned)sp[1][s] << 16);
                Xs[base + NDp + (c0 >> 1) + 1] = (unsigned)sp[2][s] | ((unsigned)sp[3][s] << 16);
                if (c0 == Win - 4)
                    Xs[base + NDp + (Win >> 1)] = (unsigned)sp[4][s];
            }
        }
        __syncthreads();

        #pragma unroll
        for (int cs = 0; cs < KC; cs += 8) {
            bf16x8 af[2][NS];
            #pragma unroll
            for (int cf = 0; cf < 2; ++cf) {
                const int co = co_w0 + cf * 16 + l15;
                #pragma unroll
                for (int s = 0; s < NS; ++s) {
                    const ushort_t* ap = wsp +
                        ((size_t)(s * 4 + p) * Cout + co) * ((size_t)Cin * 4) +
                        (size_t)(ci0 + cs) * 4 + q * 8;
                    af[cf][s] = *(const bf16x8*)ap;
                }
            }
            bf16x8 bfr[2][NS];
            const int ciA = cs + q * 2;
            #pragma unroll
            for (int mf = 0; mf < 2; ++mf) {
                const int m = m_w0 + mf * 16 + l15;
                const int c = m - 1 + dj;
                const int copy = c & 1;
                const int idx = (c + 1) >> 1;
                #pragma unroll
                for (int s = 0; s < NS; ++s) {
                    u32x4 bd;
                    bd.x = Xs[((s * KC + ciA) * 2 + 0) * 2 * NDp + copy * NDp + idx];
                    bd.y = Xs[((s * KC + ciA) * 2 + 1) * 2 * NDp + copy * NDp + idx];
                    bd.z = Xs[((s * KC + ciA + 1) * 2 + 0) * 2 * NDp + copy * NDp + idx];
                    bd.w = Xs[((s * KC + ciA + 1) * 2 + 1) * 2 * NDp + copy * NDp + idx];
                    bfr[mf][s] = __builtin_bit_cast(bf16x8, bd);
                }
            }
            #pragma unroll
            for (int sa = 0; sa < NS; ++sa)
                #pragma unroll
                for (int sb = 0; sb < NS; ++sb) {
                    if (sa + sb >= NS) continue;
                    #pragma unroll
                    for (int cf = 0; cf < 2; ++cf)
                        #pragma unroll
                        for (int mf = 0; mf < 2; ++mf)
                            acc[cf][mf] = __builtin_amdgcn_mfma_f32_16x16x32_bf16(
                                af[cf][sa], bfr[mf][sb], acc[cf][mf], 0, 0, 0);
                }
        }
    }

    constexpr int Ho2 = Hin * 2, Wo2 = Win * 2;
    const int orow = 2 * i + di;
    #pragma unroll
    for (int cf = 0; cf < 2; ++cf)
        #pragma unroll
        for (int mf = 0; mf < 2; ++mf) {
            const int ocol = 2 * (m_w0 + mf * 16 + l15) + dj;
            #pragma unroll
            for (int rg = 0; rg < 4; ++rg) {
                const int co = co_w0 + cf * 16 + q * 4 + rg;
                y[(((size_t)n * Cout + co) * Ho2 + orow) * Wo2 + ocol] =
                    acc[cf][mf][rg] + bias[co];
            }
        }
}

// ============== conv k4 s2 p1 (round-3 proven fp32) — enc0 only ============
template <int Cin, int Cout, int Hin, int Win, int CO_T>
__global__ __launch_bounds__(256) void conv4s2_k(
    const float* __restrict__ x, const float* __restrict__ w,
    const float* __restrict__ bias, float* __restrict__ y)
{
    constexpr int Hout = Hin / 2, Wout = Win / 2, Wt = Wout / 4;
    const int n   = blockIdx.z;
    const int co0 = blockIdx.y * CO_T;
    const int local = blockIdx.x * 256 + threadIdx.x;
    const int wt = local & (Wt - 1);
    const int oh = local / Wt;
    const int iw0 = (wt << 3) - 1;
    const int ih0 = (oh << 1) - 1;

    const float* __restrict__ xn = x + (size_t)n * Cin * Hin * Win;
    const float* __restrict__ wb = w + (size_t)co0 * Cin * 16;

    const bool cL = (wt > 0);
    const bool cR = (wt < Wt - 1);

    float acc[CO_T][4];
    #pragma unroll
    for (int u = 0; u < CO_T; ++u)
        acc[u][0] = acc[u][1] = acc[u][2] = acc[u][3] = 0.f;

    bool rv[4]; int ro[4];
    #pragma unroll
    for (int k = 0; k < 4; ++k) {
        int r = ih0 + k;
        rv[k] = (r >= 0) && (r < Hin);
        ro[k] = rv[k] ? r : 0;
    }

    for (int ci = 0; ci < Cin; ++ci) {
        const float* xp = xn + (size_t)ci * Hin * Win;
        float xv[4][10];
        #pragma unroll
        for (int k = 0; k < 4; ++k) {
            const float* rp = xp + (size_t)ro[k] * Win;
            float4 m0 = *(const float4*)(rp + (wt << 3));
            float4 m1 = *(const float4*)(rp + (wt << 3) + 4);
            float e0 = cL ? rp[iw0] : 0.f;
            float e9 = cR ? rp[iw0 + 9] : 0.f;
            bool rk = rv[k];
            xv[k][0] = rk ? e0 : 0.f;
            xv[k][1] = rk ? m0.x : 0.f;
            xv[k][2] = rk ? m0.y : 0.f;
            xv[k][3] = rk ? m0.z : 0.f;
            xv[k][4] = rk ? m0.w : 0.f;
            xv[k][5] = rk ? m1.x : 0.f;
            xv[k][6] = rk ? m1.y : 0.f;
            xv[k][7] = rk ? m1.z : 0.f;
            xv[k][8] = rk ? m1.w : 0.f;
            xv[k][9] = rk ? e9 : 0.f;
        }
        #pragma unroll
        for (int u = 0; u < CO_T; ++u) {
            const float* wp = wb + ((size_t)u * Cin + ci) * 16;
            #pragma unroll
            for (int kh = 0; kh < 4; ++kh) {
                #pragma unroll
                for (int kw = 0; kw < 4; ++kw) {
                    float wv = wp[kh * 4 + kw];
                    acc[u][0] = fmaf(xv[kh][kw + 0], wv, acc[u][0]);
                    acc[u][1] = fmaf(xv[kh][kw + 2], wv, acc[u][1]);
                    acc[u][2] = fmaf(xv[kh][kw + 4], wv, acc[u][2]);
                    acc[u][3] = fmaf(xv[kh][kw + 6], wv, acc[u][3]);
                }
            }
        }
    }

    #pragma unroll
    for (int u = 0; u < CO_T; ++u) {
        float b = bias[co0 + u];
        float4 o;
        o.x = acc[u][0] + b; o.y = acc[u][1] + b;
        o.z = acc[u][2] + b; o.w = acc[u][3] + b;
        float* yp = y + (((size_t)(n * Cout + co0 + u)) * Hout + oh) * Wout + (wt << 2);
        *(float4*)yp = o;
    }
}

// ==================== GroupNorm 2-stage (proven) ===========================
__global__ __launch_bounds__(256) void gn_stats(
    const float* __restrict__ y, float2* __restrict__ part,
    int HWshift, int grpC, int K)
{
    const int kblk = blockIdx.x;
    const int bg = blockIdx.y;
    const int b = bg >> 5, g = bg & 31;
    const int C = grpC << 5;
    const size_t base = ((size_t)b * C + (size_t)g * grpC) << HWshift;
    const int count4 = (grpC << HWshift) >> 2;
    const int chunk4 = count4 / K;
    const int ofs4 = kblk * chunk4;
    const float4* y4 = (const float4*)(y + base);

    float s = 0.f, ss = 0.f;
    for (int i = ofs4 + threadIdx.x; i < ofs4 + chunk4; i += 256) {
        float4 v = y4[i];
        s += v.x + v.y + v.z + v.w;
        ss = fmaf(v.x, v.x, ss); ss = fmaf(v.y, v.y, ss);
        ss = fmaf(v.z, v.z, ss); ss = fmaf(v.w, v.w, ss);
    }
    __shared__ float sh0[256];
    __shared__ float sh1[256];
    sh0[threadIdx.x] = s; sh1[threadIdx.x] = ss;
    __syncthreads();
    for (int off = 128; off > 0; off >>= 1) {
        if (threadIdx.x < off) {
            sh0[threadIdx.x] += sh0[threadIdx.x + off];
            sh1[threadIdx.x] += sh1[threadIdx.x + off];
        }
        __syncthreads();
    }
    if (threadIdx.x == 0) {
        float2 pp; pp.x = sh0[0]; pp.y = sh1[0];
        part[bg * K + kblk] = pp;
    }
}

__global__ __launch_bounds__(256) void gn_apply(
    float* __restrict__ y, const float* __restrict__ gamma,
    const float* __restrict__ beta, const float2* __restrict__ part,
    int HWshift, int grpC, int K)
{
    const int kblk = blockIdx.x;
    const int bg = blockIdx.y;
    const int b = bg >> 5, g = bg & 31;
    const int C = grpC << 5;
    const size_t base = ((size_t)b * C + (size_t)g * grpC) << HWshift;
    const int count4 = (grpC << HWshift) >> 2;
    const int chunk4 = count4 / K;
    const int ofs4 = kblk * chunk4;
    float4* y4 = (float4*)(y + base);

    float s = 0.f, ss = 0.f;
    for (int k = 0; k < K; ++k) {
        float2 pp = part[bg * K + k];
        s += pp.x; ss += pp.y;
    }
    const float inv = 1.f / (float)(count4 * 4);
    const float mean = s * inv;
    const float var = ss * inv - mean * mean;
    const float rstd = rsqrtf(var + EPS);

    const int HW4shift = HWshift - 2;
    for (int i = ofs4 + threadIdx.x; i < ofs4 + chunk4; i += 256) {
        int c = g * grpC + (i >> HW4shift);
        float ga = gamma[c], be = beta[c];
        float4 v = y4[i];
        float t0 = (v.x - mean) * rstd * ga + be;
        float t1 = (v.y - mean) * rstd * ga + be;
        float t2 = (v.z - mean) * rstd * ga + be;
        float t3 = (v.w - mean) * rstd * ga + be;
        v.x = t0 / (1.f + __expf(-t0));
        v.y = t1 / (1.f + __expf(-t1));
        v.z = t2 / (1.f + __expf(-t2));
        v.w = t3 / (1.f + __expf(-t3));
        y4[i] = v;
    }
}

// ====================== 1x1 conv (proven) ==================================
template <int Cin, int Cout, int HW, int CO_T>
__global__ __launch_bounds__(256) void conv1x1_k(
    const float* __restrict__ x, const float* __restrict__ w,
    const float* __restrict__ bias, float* __restrict__ y)
{
    const int n = blockIdx.z;
    const int co0 = blockIdx.y * CO_T;
    const int s = blockIdx.x * 256 + threadIdx.x;
    const float* xp = x + (size_t)n * Cin * HW + s;

    float acc[CO_T];
    #pragma unroll
    for (int u = 0; u < CO_T; ++u) acc[u] = bias[co0 + u];

    for (int ci = 0; ci < Cin; ++ci) {
        float v = xp[(size_t)ci * HW];
        #pragma unroll
        for (int u = 0; u < CO_T; ++u)
            acc[u] = fmaf(v, w[(size_t)(co0 + u) * Cin + ci], acc[u]);
    }
    #pragma unroll
    for (int u = 0; u < CO_T; ++u)
        y[(size_t)(n * Cout + co0 + u) * HW + s] = acc[u];
}

// ============================== VQ (proven) ================================
__global__ __launch_bounds__(256) void cb_norm(
    const float* __restrict__ cb, float* __restrict__ cn)
{
    int j = blockIdx.x * 256 + threadIdx.x;
    const float* c = cb + (size_t)j * 32;
    float s = 0.f;
    #pragma unroll
    for (int k = 0; k < 32; ++k) s = fmaf(c[k], c[k], s);
    cn[j] = s;
}

__global__ __launch_bounds__(256) void vq_kernel(
    const float* __restrict__ z, const float* __restrict__ cb,
    const float* __restrict__ cn, float* __restrict__ q,
    float* __restrict__ idxf)
{
    const int row = blockIdx.x * 4 + (threadIdx.x >> 6);
    const int lane = threadIdx.x & 63;
    const float* zr = z + (size_t)row * 32;
    float zreg[32];
    #pragma unroll
    for (int k = 0; k < 32; ++k) zreg[k] = zr[k];
    float zn = 0.f;
    #pragma unroll
    for (int k = 0; k < 32; ++k) zn = fmaf(zreg[k], zreg[k], zn);

    float best = 3.4e38f;
    int bj = 0;
    for (int ii = 0; ii < 16; ++ii) {
        int j = lane * 16 + ii;
        const float* c = cb + (size_t)j * 32;
        float dot = 0.f;
        #pragma unroll
        for (int k = 0; k < 32; ++k) dot = fmaf(zreg[k], c[k], dot);
        float d = zn + cn[j] - 2.f * dot;
        if (d < best) { best = d; bj = j; }
    }
    #pragma unroll
    for (int off = 1; off < 64; off <<= 1) {
        float ob = __shfl_xor(best, off);
        int oj = __shfl_xor(bj, off);
        if (ob < best || (ob == best && oj < bj)) { best = ob; bj = oj; }
    }
    if (lane < 32) q[(size_t)row * 32 + lane] = cb[(size_t)bj * 32 + lane];
    if (lane == 0) idxf[row] = (float)bj;
}

// ======= fp32 convT (round-4 proven) — dec3 (Cout=3, tanh) =================
template <int Cin, int CO_T, int CICHUNK>
__device__ __forceinline__ void stage_weights(
    const float* __restrict__ wb, int ci0, float4* __restrict__ lds4)
{
    constexpr int W4 = CICHUNK * CO_T * 4;
    for (int g4 = threadIdx.x; g4 < W4; g4 += blockDim.x) {
        int u = g4 / (CICHUNK * 4);
        int r4 = g4 - u * (CICHUNK * 4);
        lds4[g4] = ((const float4*)(wb + (size_t)u * Cin * 16 + (size_t)ci0 * 16))[r4];
    }
}

template <int Cin, int Cout, int Hin, int Win, int CO_T, int CICHUNK, bool TANH>
__global__ __launch_bounds__(256) void convt2_lds(
    const float* __restrict__ x, const float* __restrict__ w,
    const float* __restrict__ bias, float* __restrict__ y)
{
    constexpr int Wt2 = Win / 2;
    __shared__ float4 wlds[CICHUNK * CO_T * 4];

    const int n = blockIdx.z;
    const int co0 = blockIdx.y * CO_T;
    const int local = blockIdx.x * 256 + threadIdx.x;
    const int jt = local & (Wt2 - 1);
    const int i = local / Wt2;
    const int j0 = jt << 1;

    const float* __restrict__ xn = x + (size_t)n * Cin * Hin * Win;
    const float* __restrict__ wb = w + (size_t)co0 * Cin * 16;

    const bool rm0 = (i > 0), rm2 = (i + 1 < Hin);
    const bool cmL = (jt > 0), cmR = (jt < Wt2 - 1);
    const int ro0 = rm0 ? (i - 1) : 0;
    const int ro2 = rm2 ? (i + 1) : 0;

    float acc[CO_T][2][4];
    #pragma unroll
    for (int u = 0; u < CO_T; ++u)
        #pragma unroll
        for (int p = 0; p < 2; ++p)
            acc[u][p][0] = acc[u][p][1] = acc[u][p][2] = acc[u][p][3] = 0.f;

    for (int ci0 = 0; ci0 < Cin; ci0 += CICHUNK) {
        if (ci0) __syncthreads();
        stage_weights<Cin, CO_T, CICHUNK>(wb, ci0, wlds);
        __syncthreads();

        for (int cic = 0; cic < CICHUNK; ++cic) {
            const int ci = ci0 + cic;
            const float* xp = xn + (size_t)ci * Hin * Win;
            float xr[3][4];
            {
                const int rows[3] = {ro0, i, ro2};
                const bool rvn[3] = {rm0, true, rm2};
                #pragma unroll
                for (int r = 0; r < 3; ++r) {
                    const float* rp = xp + (size_t)rows[r] * Win;
                    float2 m = *(const float2*)(rp + j0);
                    float eL = cmL ? rp[j0 - 1] : 0.f;
                    float eR = cmR ? rp[j0 + 2] : 0.f;
                    bool rk = rvn[r];
                    xr[r][0] = rk ? eL : 0.f;
                    xr[r][1] = rk ? m.x : 0.f;
                    xr[r][2] = rk ? m.y : 0.f;
                    xr[r][3] = rk ? eR : 0.f;
                }
            }
            #pragma unroll
            for (int u = 0; u < CO_T; ++u) {
                const int wbase = (cic * CO_T + u) * 4;
                float4 wq0 = wlds[wbase + 0];
                float4 wq1 = wlds[wbase + 1];
                float4 wq2 = wlds[wbase + 2];
                float4 wq3 = wlds[wbase + 3];
                #pragma unroll
                for (int p = 0; p < 2; ++p) {
                    float x00 = xr[0][p], x01 = xr[0][p + 1], x02 = xr[0][p + 2];
                    float x10 = xr[1][p], x11 = xr[1][p + 1], x12 = xr[1][p + 2];
                    float x20 = xr[2][p], x21 = xr[2][p + 1], x22 = xr[2][p + 2];
                    float* a = acc[u][p];
                    a[0] = fmaf(x00, wq0.x, a[0]); a[0] = fmaf(x01, wq0.z, a[0]);
                    a[0] = fmaf(x10, wq2.x, a[0]); a[0] = fmaf(x11, wq2.z, a[0]);
                    a[1] = fmaf(x01, wq0.y, a[1]); a[1] = fmaf(x02, wq0.w, a[1]);
                    a[1] = fmaf(x11, wq2.y, a[1]); a[1] = fmaf(x12, wq2.w, a[1]);
                    a[2] = fmaf(x10, wq1.x, a[2]); a[2] = fmaf(x11, wq1.z, a[2]);
                    a[2] = fmaf(x20, wq3.x, a[2]); a[2] = fmaf(x21, wq3.z, a[2]);
                    a[3] = fmaf(x11, wq1.y, a[3]); a[3] = fmaf(x12, wq1.w, a[3]);
                    a[3] = fmaf(x21, wq3.y, a[3]); a[3] = fmaf(x22, wq3.w, a[3]);
                }
            }
        }
    }

    constexpr int Hout = Hin * 2, Wout = Win * 2;
    #pragma unroll
    for (int u = 0; u < CO_T; ++u) {
        float b = bias[co0 + u];
        float r00 = acc[u][0][0] + b, r01 = acc[u][0][1] + b;
        float r02 = acc[u][1][0] + b, r03 = acc[u][1][1] + b;
        float r10 = acc[u][0][2] + b, r11 = acc[u][0][3] + b;
        float r12 = acc[u][1][2] + b, r13 = acc[u][1][3] + b;
        if (TANH) {
            r00 = tanhf(r00); r01 = tanhf(r01); r02 = tanhf(r02); r03 = tanhf(r03);
            r10 = tanhf(r10); r11 = tanhf(r11); r12 = tanhf(r12); r13 = tanhf(r13);
        }
        float* yp = y + (((size_t)(n * Cout + co0 + u)) * Hout + (i << 1)) * Wout + (jt << 2);
        float4 o;
        o.x = r00; o.y = r01; o.z = r02; o.w = r03; *(float4*)yp = o;
        o.x = r10; o.y = r11; o.z = r12; o.w = r13; *(float4*)(yp + Wout) = o;
    }
}

// ================================ launch ===================================
extern "C" void kernel_launch(void* const* d_in, const int* in_sizes, int n_in,
                              void* d_out, int out_size, void* d_ws, size_t ws_size,
                              hipStream_t stream)
{
    const float* x       = (const float*)d_in[0];
    const float* enc0_w  = (const float*)d_in[1];
    const float* enc0_b  = (const float*)d_in[2];
    const float* enc0_g  = (const float*)d_in[3];
    const float* enc0_bt = (const float*)d_in[4];
    const float* enc1_w  = (const float*)d_in[5];
    const float* enc1_b  = (const float*)d_in[6];
    const float* enc1_g  = (const float*)d_in[7];
    const float* enc1_bt = (const float*)d_in[8];
    const float* enc2_w  = (const float*)d_in[9];
    const float* enc2_b  = (const float*)d_in[10];
    const float* enc2_g  = (const float*)d_in[11];
    const float* enc2_bt = (const float*)d_in[12];
    const float* enc3_w  = (const float*)d_in[13];
    const float* enc3_b  = (const float*)d_in[14];
    const float* codebook= (const float*)d_in[15];
    const float* dec0_w  = (const float*)d_in[16];
    const float* dec0_b  = (const float*)d_in[17];
    const float* dec1_w  = (const float*)d_in[18];
    const float* dec1_b  = (const float*)d_in[19];
    const float* dec1_g  = (const float*)d_in[20];
    const float* dec1_bt = (const float*)d_in[21];
    const float* dec2_w  = (const float*)d_in[22];
    const float* dec2_b  = (const float*)d_in[23];
    const float* dec2_g  = (const float*)d_in[24];
    const float* dec2_bt = (const float*)d_in[25];
    const float* dec3_w  = (const float*)d_in[26];
    const float* dec3_b  = (const float*)d_in[27];

    float* ws = (float*)d_ws;
    float*  A  = ws;                       // 33,554,432 floats (134 MB)
    float*  B  = ws + 33554432;            // 16,777,216 floats (67 MB)
    float*  C  = ws + 50331648;            //  8,388,608 floats (33.6 MB)
    float*  Z  = ws + 58720256;            //    524,288 floats (2 MB)
    float*  CN = ws + 59244544;            //      1,024 floats
    float2* GP = (float2*)(ws + 59245568); //      8,192 float2 (gn partials)

    // split-weight scratch, time-multiplexed:
    ushort_t* WE1 = (ushort_t*)C;                 // enc1 (3.1 MB); C dead pre-enc2
    ushort_t* WE2 = (ushort_t*)A;                 // enc2 (12.6 MB); A dead post-enc1
    ushort_t* WD1 = (ushort_t*)C;                 // dec1 (4.2 MB); C dead post-enc3
    ushort_t* WD2 = (ushort_t*)(C + 4194304);     // dec2 (1 MB)

    float* out   = (float*)d_out;
    float* recon = out;                    // 3,145,728 floats
    float* qbuf  = out + 3145728;          //   524,288 floats
    float* idxf  = out + 3670016;          //    16,384 floats

    const dim3 blk(256);
    const int K = 16;
    const dim3 gngrid(K, 512);

    // ---------------- encoder ----------------
    wsplit_enc<256, 128><<<dim3(2048), blk, 0, stream>>>(enc1_w, WE1);

    conv4s2_k<3, 128, 256, 256, 8><<<dim3(16, 16, 16), blk, 0, stream>>>(
        x, enc0_w, enc0_b, A);
    gn_stats<<<gngrid, blk, 0, stream>>>(A, GP, 14, 4, K);
    gn_apply<<<gngrid, blk, 0, stream>>>(A, enc0_g, enc0_bt, GP, 14, 4, K);

    // enc1: 16x128x128x128 -> 16x256x64x64  (MFMA tap-GEMM, split-3, 2-oh)
    mfenc<128, 256, 128, 128><<<dim3(64, 1, 16), blk, 0, stream>>>(
        A, WE1, enc1_b, B);

    wsplit_enc<512, 256><<<dim3(8192), blk, 0, stream>>>(enc2_w, WE2);

    gn_stats<<<gngrid, blk, 0, stream>>>(B, GP, 12, 8, K);
    gn_apply<<<gngrid, blk, 0, stream>>>(B, enc1_g, enc1_bt, GP, 12, 8, K);

    // enc2: -> 16x512x32x32  (MFMA tap-GEMM, split-3, 2-oh)
    mfenc<256, 512, 64, 64><<<dim3(16, 2, 16), blk, 0, stream>>>(
        B, WE2, enc2_b, C);
    gn_stats<<<gngrid, blk, 0, stream>>>(C, GP, 10, 16, K);
    gn_apply<<<gngrid, blk, 0, stream>>>(C, enc2_g, enc2_bt, GP, 10, 16, K);

    conv1x1_k<512, 32, 1024, 8><<<dim3(4, 4, 16), blk, 0, stream>>>(
        C, enc3_w, enc3_b, Z);

    // ---------------- VQ ----------------
    cb_norm<<<dim3(4), blk, 0, stream>>>(codebook, CN);
    vq_kernel<<<dim3(16384 / 4), blk, 0, stream>>>(Z, codebook, CN, qbuf, idxf);

    // ---------------- decoder (round-7 path) ------------------------------
    wsplit_convt<256, 512, 1><<<dim3(8192), blk, 0, stream>>>(dec1_w, WD1);
    wsplit_convt<128, 256, 1><<<dim3(2048), blk, 0, stream>>>(dec2_w, WD2);

    conv1x1_k<32, 512, 1024, 8><<<dim3(4, 64, 16), blk, 0, stream>>>(
        qbuf, dec0_w, dec0_b, A);

    mfconvt<512, 256, 32, 32, 4, 1, 16, 1><<<dim3(128, 2, 16), blk, 0, stream>>>(
        A, WD1, dec1_b, B);
    gn_stats<<<gngrid, blk, 0, stream>>>(B, GP, 12, 8, K);
    gn_apply<<<gngrid, blk, 0, stream>>>(B, dec1_g, dec1_bt, GP, 12, 8, K);

    mfconvt<256, 128, 64, 64, 2, 2, 16, 1><<<dim3(256, 2, 16), blk, 0, stream>>>(
        B, WD2, dec2_b, A);
    gn_stats<<<gngrid, blk, 0, stream>>>(A, GP, 14, 4, K);
    gn_apply<<<gngrid, blk, 0, stream>>>(A, dec2_g, dec2_bt, GP, 14, 4, K);

    convt2_lds<128, 3, 128, 128, 3, 128, true><<<dim3(32, 1, 16), blk, 0, stream>>>(
        A, dec3_w, dec3_b, recon);
}

// Round 3
// 3058.196 us; speedup vs baseline: 1.1149x; 1.1149x over previous
//
#include <hip/hip_runtime.h>
#include <hip/hip_bf16.h>
#include <math.h>

// ---------------------------------------------------------------------------
// VQGAN forward, round 12.
//  - mfenc v5: round-1 geometry (1 oh/block, verified 833us) + software
//    pipeline:
//    * staging loads fully unrolled (5 predicated column steps -> all 40
//      global loads issue together, 1 latency instead of ~34 serial),
//    * LDS X-tile double-buffered (2 x 52224 B); chunk k+1's loads are
//      issued BEFORE chunk k's 16-tap MFMA phase (latency hides under
//      ~15k cyc of MFMA), splitNS+ds_write happen after, single barrier,
//    * sched_barrier(0) pins the load issue ahead of the MFMA region,
//    * weight fragment register double-buffer (round-10) unchanged.
//    Staged bits / weight bits / accumulation order identical -> z
//    bit-identical -> idx exact.
//  - 2-oh experiment (round 11) REVERTED: FETCH halved but time regressed;
//    weight stream is not the binding constraint (staging latency is).
//  - decoder: round-7/8 kernels unchanged.
// d_out = [recon 16*3*256*256 | q 16*32*32*32 | idx-as-float 16384]
// ---------------------------------------------------------------------------

#define EPS 1e-5f
typedef unsigned short ushort_t;
typedef unsigned int uint32;
typedef __attribute__((ext_vector_type(8))) short bf16x8;
typedef __attribute__((ext_vector_type(4))) float f32x4;
typedef __attribute__((ext_vector_type(4))) unsigned int u32x4;

__device__ __forceinline__ ushort_t f2bf(float x) {
    __hip_bfloat16 h = __float2bfloat16(x);
    return __builtin_bit_cast(ushort_t, h);
}
__device__ __forceinline__ float bf2f(ushort_t u) {
    __hip_bfloat16 h = __builtin_bit_cast(__hip_bfloat16, u);
    return __bfloat162float(h);
}
template <int NS>
__device__ __forceinline__ void splitNS(float x, ushort_t* p) {
    float r = x;
    #pragma unroll
    for (int s = 0; s < NS; ++s) {
        ushort_t u = f2bf(r);
        p[s] = u;
        if (s + 1 < NS) r -= bf2f(u);
    }
}

// ============ encoder weight pre-split: fragment-order layout ==============
// o[(((((s*16+tap)*KCH + kc)*CB + cb)*64 + lane)*8 + e]
//   kc = ci>>5, q = (ci>>3)&3, e = ci&7, cb = co>>4, l15 = co&15,
//   lane = q*16 + l15  (exactly the mfenc wave lane id)
template <int Cout, int Cin>
__global__ __launch_bounds__(256) void wsplit_enc(
    const float* __restrict__ w, ushort_t* __restrict__ o)
{
    constexpr int KCH = Cin / 32, CB = Cout / 16;
    int idx = blockIdx.x * 256 + threadIdx.x;
    if (idx >= Cout * Cin * 16) return;
    int tap = idx & 15;
    int ci  = (idx >> 4) % Cin;
    int co  = (idx >> 4) / Cin;
    ushort_t sp[3];
    splitNS<3>(w[idx], sp);
    const int kc = ci >> 5, q = (ci >> 3) & 3, e = ci & 7;
    const int cb = co >> 4, l15 = co & 15;
    const int lane = q * 16 + l15;
    #pragma unroll
    for (int s = 0; s < 3; ++s)
        o[((((size_t)(s * 16 + tap) * KCH + kc) * CB + cb) * 64 + lane) * 8 + e] = sp[s];
}

// A-fragment loader: one coalesced 1KB segment per (cf,s) wave load.
template <int KCH, int CB>
__device__ __forceinline__ void ldaf(bf16x8 (&dst)[4][3],
    const ushort_t* __restrict__ wsp_t, int kc, int tap)
{
    #pragma unroll
    for (int cf = 0; cf < 4; ++cf)
        #pragma unroll
        for (int s = 0; s < 3; ++s)
            dst[cf][s] = *(const bf16x8*)(wsp_t +
                ((size_t)((s * 16 + tap) * KCH + kc) * CB + cf) * 512);
}

// ================= MFMA encoder conv k4 s2 p1: tap-GEMMs ===================
// Geometry identical to round 8/9/10 (verified): one oh, 32 m, 256 co,
// k=ci, KC=32. LDS: double-buffered [s(3)][row(4)][ciq(4)][cpos(68)][cie(8)]
// ushort per buffer; col c -> cpos = (c>>1)+(c&1)*34.
// v5: chunk k+1's global loads issue before chunk k's MFMA phase; splitNS +
// ds_write into the other LDS buffer after; one barrier per chunk.
template <int Cin, int Cout, int Hin, int Win>
__global__ __launch_bounds__(256) void mfenc(
    const float* __restrict__ x, const ushort_t* __restrict__ wsp,
    const float* __restrict__ bias, float* __restrict__ y)
{
    constexpr int Hout = Hin / 2, Wout = Win / 2;
    constexpr int MB = 32;
    constexpr int MT = Wout / MB;
    constexpr int NCOL = 66;
    constexpr int KC = 32;
    constexpr int KCH = Cin / 32;
    constexpr int CB = Cout / 16;
    constexpr int BUFW = 3 * 4 * 4 * 68 * 8;       // ushorts per buffer (52224 B)
    __shared__ ushort_t Xs[2 * BUFW];              // 104448 B

    const int n  = blockIdx.z;
    const int oh = blockIdx.x / MT;
    const int mt = blockIdx.x % MT;
    const int M0 = mt * MB;
    const int co_base = blockIdx.y * 256;
    const int tid = threadIdx.x;
    const int wv = tid >> 6, lane = tid & 63;
    const int q = lane >> 4, l15 = lane & 15;
    const int co_w0 = co_base + wv * 64;
    const int cb0 = (co_base >> 4) + wv * 4;
    const ushort_t* __restrict__ wsp_t = wsp + ((size_t)cb0 * 64 + lane) * 8;

    int ro[4]; bool rv[4];
    #pragma unroll
    for (int k = 0; k < 4; ++k) {
        int r = 2 * oh - 1 + k;
        rv[k] = (r >= 0) && (r < Hin);
        ro[k] = rv[k] ? r : 0;
    }

    f32x4 acc[4][2];
    #pragma unroll
    for (int a = 0; a < 4; ++a)
        #pragma unroll
        for (int b = 0; b < 2; ++b) acc[a][b] = (f32x4){0.f, 0.f, 0.f, 0.f};

    // staging ids: ci-pair + column-group
    const int p16  = tid >> 4;            // 0..15 -> ci pair (2*p16, 2*p16+1)
    const int cg   = tid & 15;            // column group
    const int sciq = p16 >> 2;            // ci octet 0..3
    const int cieP = p16 & 3;             // dword index within octet

    float a0[4][5], a1[4][5];             // staged values in flight

    // all 40 loads issue together (fully unrolled, predicated)
    auto stage_load = [&](int ci0) {
        const float* b0 = x + (size_t)(n * Cin + ci0 + 2 * p16) * Hin * Win;
        const float* b1 = b0 + (size_t)Hin * Win;
        #pragma unroll
        for (int r = 0; r < 4; ++r) {
            const float* rp0 = b0 + (size_t)ro[r] * Win;
            const float* rp1 = b1 + (size_t)ro[r] * Win;
            #pragma unroll
            for (int t = 0; t < 5; ++t) {
                const int c = cg + 16 * t;
                const int gc = 2 * M0 - 1 + c;
                const bool ok = rv[r] && (c < NCOL) && (gc >= 0) && (gc < Win);
                a0[r][t] = ok ? rp0[gc] : 0.f;
                a1[r][t] = ok ? rp1[gc] : 0.f;
            }
        }
    };
    // splitNS + ds_write (same bits / same LDS slots as round 9/10)
    auto stage_write = [&](int buf) {
        uint32* __restrict__ dst32 = (uint32*)(Xs + buf * BUFW);
        #pragma unroll
        for (int r = 0; r < 4; ++r)
            #pragma unroll
            for (int t = 0; t < 5; ++t) {
                const int c = cg + 16 * t;
                if (c < NCOL) {
                    ushort_t s0[3], s1[3];
                    splitNS<3>(a0[r][t], s0);
                    splitNS<3>(a1[r][t], s1);
                    const int cpos = (c >> 1) + (c & 1) * 34;
                    #pragma unroll
                    for (int s = 0; s < 3; ++s)
                        dst32[((((s * 4 + r) * 4 + sciq) * 68) + cpos) * 4 + cieP] =
                            (uint32)s0[s] | ((uint32)s1[s] << 16);
                }
            }
    };

    bf16x8 afA[4][3], afB[4][3];
    ldaf<KCH, CB>(afA, wsp_t, 0, 0);

    // prologue: stage chunk 0
    stage_load(0);
    stage_write(0);
    __syncthreads();

    for (int kc = 0; kc < KCH; ++kc) {
        const int cur = kc & 1;
        const ushort_t* __restrict__ Xr = Xs + cur * BUFW;

        // issue next chunk's global loads now; latency hides under MFMA
        if (kc + 1 < KCH) stage_load((kc + 1) * KC);
        __builtin_amdgcn_sched_barrier(0);   // pin load issue ahead of MFMA

        __builtin_amdgcn_s_setprio(1);
        #pragma unroll
        for (int tap = 0; tap < 16; ++tap) {
            bf16x8 (&cw)[4][3] = (tap & 1) ? afB : afA;
            bf16x8 (&nw)[4][3] = (tap & 1) ? afA : afB;
            // prefetch next tap's (or next chunk's tap-0) weight fragments
            if (tap < 15) {
                ldaf<KCH, CB>(nw, wsp_t, kc, tap + 1);
            } else if (kc + 1 < KCH) {
                ldaf<KCH, CB>(nw, wsp_t, kc + 1, 0);
            }

            const int kh = tap >> 2, kw = tap & 3;
            bf16x8 bx[2][3];
            const int cpbase = (kw >> 1) + (kw & 1) * 34;
            #pragma unroll
            for (int mf = 0; mf < 2; ++mf) {
                const int cpos = (mf * 16 + l15) + cpbase;
                #pragma unroll
                for (int s = 0; s < 3; ++s)
                    bx[mf][s] = *(const bf16x8*)(&Xr[((((s * 4 + kh) * 4 + q) * 68) + cpos) * 8]);
            }
            #pragma unroll
            for (int sa = 0; sa < 3; ++sa)
                #pragma unroll
                for (int sb = 0; sb < 3; ++sb) {
                    if (sa + sb >= 3) continue;
                    #pragma unroll
                    for (int cf = 0; cf < 4; ++cf)
                        #pragma unroll
                        for (int mf = 0; mf < 2; ++mf)
                            acc[cf][mf] = __builtin_amdgcn_mfma_f32_16x16x32_bf16(
                                cw[cf][sa], bx[mf][sb], acc[cf][mf], 0, 0, 0);
                }
        }
        __builtin_amdgcn_s_setprio(0);

        if (kc + 1 < KCH) {
            stage_write(cur ^ 1);
            __syncthreads();
        }
    }

    #pragma unroll
    for (int cf = 0; cf < 4; ++cf)
        #pragma unroll
        for (int mf = 0; mf < 2; ++mf) {
            const int ow = M0 + mf * 16 + l15;
            #pragma unroll
            for (int rg = 0; rg < 4; ++rg) {
                const int co = co_w0 + cf * 16 + q * 4 + rg;
                y[(((size_t)n * Cout + co) * Hout + oh) * Wout + ow] =
                    acc[cf][mf][rg] + bias[co];
            }
        }
}

// ============== decoder weight pre-split (round-7, NS=1) ===================
template <int Cout, int Cin, int NS>
__global__ __launch_bounds__(256) void wsplit_convt(
    const float* __restrict__ w, ushort_t* __restrict__ o)
{
    int idx = blockIdx.x * 256 + threadIdx.x;
    if (idx >= 4 * Cout * Cin * 4) return;
    int b  = idx & 1;
    int a  = (idx >> 1) & 1;
    int ci = (idx >> 2) % Cin;
    int co = ((idx >> 2) / Cin) % Cout;
    int p  = ((idx >> 2) / Cin) / Cout;
    int di = p >> 1, dj = p & 1;
    float v = w[(((size_t)co * Cin + ci) * 4 + (2 * a + di)) * 4 + (2 * b + dj)];
    ushort_t sp[NS];
    splitNS<NS>(v, sp);
    #pragma unroll
    for (int s = 0; s < NS; ++s)
        o[(((size_t)(s * 4 + p) * Cout + co) * Cin + ci) * 4 + a * 2 + b] = sp[s];
}

// ================= MFMA convT (round-7, unchanged) =========================
template <int Cin, int Cout, int Hin, int Win, int CO_WAVES, int M_WAVES, int KC, int NS>
__global__ __launch_bounds__(256) void mfconvt(
    const float* __restrict__ x, const ushort_t* __restrict__ wsp,
    const float* __restrict__ bias, float* __restrict__ y)
{
    constexpr int NDp = Win / 2 + 2;
    constexpr int CO_B = CO_WAVES * 32;
    static_assert(CO_WAVES * M_WAVES == 4, "4 waves");
    static_assert(M_WAVES * 32 == Win, "block spans full row");
    static_assert(KC % 8 == 0, "k-step = 8 ci");
    __shared__ unsigned int Xs[NS * KC * 2 * 2 * NDp];

    const int bi = blockIdx.x;
    const int i = bi >> 2;
    const int p = bi & 3;
    const int di = p >> 1, dj = p & 1;
    const int n = blockIdx.z;
    const int co_base = blockIdx.y * CO_B;
    const int tid = threadIdx.x;
    const int wv = tid >> 6, lane = tid & 63;
    const int cw = wv / M_WAVES, mw = wv % M_WAVES;
    const int co_w0 = co_base + cw * 32;
    const int m_w0 = mw * 32;
    const int q = lane >> 4, l15 = lane & 15;

    const int r0 = i - 1 + di, r1 = i + di;
    const bool v0 = (r0 >= 0), v1 = (r1 < Hin);
    const int r0c = v0 ? r0 : 0, r1c = v1 ? r1 : 0;

    f32x4 acc[2][2];
    #pragma unroll
    for (int a = 0; a < 2; ++a)
        #pragma unroll
        for (int b = 0; b < 2; ++b) acc[a][b] = (f32x4){0.f, 0.f, 0.f, 0.f};

    constexpr int SEGW = Win / 4;
    constexpr int SEGS = KC * 2 * SEGW;

    for (int ci0 = 0; ci0 < Cin; ci0 += KC) {
        if (ci0) __syncthreads();
        for (int seg = tid; seg < SEGS; seg += 256) {
            const int c0 = (seg % SEGW) * 4;
            const int rem = seg / SEGW;
            const int a = rem & 1;
            const int ci = rem >> 1;
            const bool rok = a ? v1 : v0;
            const int gr = a ? r1c : r0c;
            const float* rp = x + ((size_t)(n * Cin + ci0 + ci) * Hin + gr) * Win;
            float v[5];
            v[0] = (rok && c0 > 0) ? rp[c0 - 1] : 0.f;
            #pragma unroll
            for (int t = 1; t < 5; ++t) v[t] = rok ? rp[c0 + t - 1] : 0.f;
            ushort_t sp[5][NS];
            #pragma unroll
            for (int t = 0; t < 5; ++t) splitNS<NS>(v[t], sp[t]);
            #pragma unroll
            for (int s = 0; s < NS; ++s) {
                const int base = ((s * KC + ci) * 2 + a) * 2 * NDp;
                Xs[base + (c0 >> 1)]           = (unsigned)sp[1][s] | ((unsigned)sp[2][s] << 16);
                Xs[base + (c0 >> 1) + 1]       = (unsigned)sp[3][s] | ((unsigned)sp[4][s] << 16);
                Xs[base + NDp + (c0 >> 1)]     = (unsigned)sp[0][s] | ((unsigned)sp[1][s] << 16);
                Xs[base + NDp + (c0 >> 1) + 1] = (unsigned)sp[2][s] | ((unsigned)sp[3][s] << 16);
                if (c0 == Win - 4)
                    Xs[base + NDp + (Win >> 1)] = (unsigned)sp[4][s];
            }
        }
        __syncthreads();

        #pragma unroll
        for (int cs = 0; cs < KC; cs += 8) {
            bf16x8 af[2][NS];
            #pragma unroll
            for (int cf = 0; cf < 2; ++cf) {
                const int co = co_w0 + cf * 16 + l15;
                #pragma unroll
                for (int s = 0; s < NS; ++s) {
                    const ushort_t* ap = wsp +
                        ((size_t)(s * 4 + p) * Cout + co) * ((size_t)Cin * 4) +
                        (size_t)(ci0 + cs) * 4 + q * 8;
                    af[cf][s] = *(const bf16x8*)ap;
                }
            }
            bf16x8 bfr[2][NS];
            const int ciA = cs + q * 2;
            #pragma unroll
            for (int mf = 0; mf < 2; ++mf) {
                const int m = m_w0 + mf * 16 + l15;
                const int c = m - 1 + dj;
                const int copy = c & 1;
                const int idx = (c + 1) >> 1;
                #pragma unroll
                for (int s = 0; s < NS; ++s) {
                    u32x4 bd;
                    bd.x = Xs[((s * KC + ciA) * 2 + 0) * 2 * NDp + copy * NDp + idx];
                    bd.y = Xs[((s * KC + ciA) * 2 + 1) * 2 * NDp + copy * NDp + idx];
                    bd.z = Xs[((s * KC + ciA + 1) * 2 + 0) * 2 * NDp + copy * NDp + idx];
                    bd.w = Xs[((s * KC + ciA + 1) * 2 + 1) * 2 * NDp + copy * NDp + idx];
                    bfr[mf][s] = __builtin_bit_cast(bf16x8, bd);
                }
            }
            #pragma unroll
            for (int sa = 0; sa < NS; ++sa)
                #pragma unroll
                for (int sb = 0; sb < NS; ++sb) {
                    if (sa + sb >= NS) continue;
                    #pragma unroll
                    for (int cf = 0; cf < 2; ++cf)
                        #pragma unroll
                        for (int mf = 0; mf < 2; ++mf)
                            acc[cf][mf] = __builtin_amdgcn_mfma_f32_16x16x32_bf16(
                                af[cf][sa], bfr[mf][sb], acc[cf][mf], 0, 0, 0);
                }
        }
    }

    constexpr int Ho2 = Hin * 2, Wo2 = Win * 2;
    const int orow = 2 * i + di;
    #pragma unroll
    for (int cf = 0; cf < 2; ++cf)
        #pragma unroll
        for (int mf = 0; mf < 2; ++mf) {
            const int ocol = 2 * (m_w0 + mf * 16 + l15) + dj;
            #pragma unroll
            for (int rg = 0; rg < 4; ++rg) {
                const int co = co_w0 + cf * 16 + q * 4 + rg;
                y[(((size_t)n * Cout + co) * Ho2 + orow) * Wo2 + ocol] =
                    acc[cf][mf][rg] + bias[co];
            }
        }
}

// ============== conv k4 s2 p1 (round-3 proven fp32) — enc0 only ============
template <int Cin, int Cout, int Hin, int Win, int CO_T>
__global__ __launch_bounds__(256) void conv4s2_k(
    const float* __restrict__ x, const float* __restrict__ w,
    const float* __restrict__ bias, float* __restrict__ y)
{
    constexpr int Hout = Hin / 2, Wout = Win / 2, Wt = Wout / 4;
    const int n   = blockIdx.z;
    const int co0 = blockIdx.y * CO_T;
    const int local = blockIdx.x * 256 + threadIdx.x;
    const int wt = local & (Wt - 1);
    const int oh = local / Wt;
    const int iw0 = (wt << 3) - 1;
    const int ih0 = (oh << 1) - 1;

    const float* __restrict__ xn = x + (size_t)n * Cin * Hin * Win;
    const float* __restrict__ wb = w + (size_t)co0 * Cin * 16;

    const bool cL = (wt > 0);
    const bool cR = (wt < Wt - 1);

    float acc[CO_T][4];
    #pragma unroll
    for (int u = 0; u < CO_T; ++u)
        acc[u][0] = acc[u][1] = acc[u][2] = acc[u][3] = 0.f;

    bool rv[4]; int ro[4];
    #pragma unroll
    for (int k = 0; k < 4; ++k) {
        int r = ih0 + k;
        rv[k] = (r >= 0) && (r < Hin);
        ro[k] = rv[k] ? r : 0;
    }

    for (int ci = 0; ci < Cin; ++ci) {
        const float* xp = xn + (size_t)ci * Hin * Win;
        float xv[4][10];
        #pragma unroll
        for (int k = 0; k < 4; ++k) {
            const float* rp = xp + (size_t)ro[k] * Win;
            float4 m0 = *(const float4*)(rp + (wt << 3));
            float4 m1 = *(const float4*)(rp + (wt << 3) + 4);
            float e0 = cL ? rp[iw0] : 0.f;
            float e9 = cR ? rp[iw0 + 9] : 0.f;
            bool rk = rv[k];
            xv[k][0] = rk ? e0 : 0.f;
            xv[k][1] = rk ? m0.x : 0.f;
            xv[k][2] = rk ? m0.y : 0.f;
            xv[k][3] = rk ? m0.z : 0.f;
            xv[k][4] = rk ? m0.w : 0.f;
            xv[k][5] = rk ? m1.x : 0.f;
            xv[k][6] = rk ? m1.y : 0.f;
            xv[k][7] = rk ? m1.z : 0.f;
            xv[k][8] = rk ? m1.w : 0.f;
            xv[k][9] = rk ? e9 : 0.f;
        }
        #pragma unroll
        for (int u = 0; u < CO_T; ++u) {
            const float* wp = wb + ((size_t)u * Cin + ci) * 16;
            #pragma unroll
            for (int kh = 0; kh < 4; ++kh) {
                #pragma unroll
                for (int kw = 0; kw < 4; ++kw) {
                    float wv = wp[kh * 4 + kw];
                    acc[u][0] = fmaf(xv[kh][kw + 0], wv, acc[u][0]);
                    acc[u][1] = fmaf(xv[kh][kw + 2], wv, acc[u][1]);
                    acc[u][2] = fmaf(xv[kh][kw + 4], wv, acc[u][2]);
                    acc[u][3] = fmaf(xv[kh][kw + 6], wv, acc[u][3]);
                }
            }
        }
    }

    #pragma unroll
    for (int u = 0; u < CO_T; ++u) {
        float b = bias[co0 + u];
        float4 o;
        o.x = acc[u][0] + b; o.y = acc[u][1] + b;
        o.z = acc[u][2] + b; o.w = acc[u][3] + b;
        float* yp = y + (((size_t)(n * Cout + co0 + u)) * Hout + oh) * Wout + (wt << 2);
        *(float4*)yp = o;
    }
}

// ==================== GroupNorm 2-stage (proven) ===========================
__global__ __launch_bounds__(256) void gn_stats(
    const float* __restrict__ y, float2* __restrict__ part,
    int HWshift, int grpC, int K)
{
    const int kblk = blockIdx.x;
    const int bg = blockIdx.y;
    const int b = bg >> 5, g = bg & 31;
    const int C = grpC << 5;
    const size_t base = ((size_t)b * C + (size_t)g * grpC) << HWshift;
    const int count4 = (grpC << HWshift) >> 2;
    const int chunk4 = count4 / K;
    const int ofs4 = kblk * chunk4;
    const float4* y4 = (const float4*)(y + base);

    float s = 0.f, ss = 0.f;
    for (int i = ofs4 + threadIdx.x; i < ofs4 + chunk4; i += 256) {
        float4 v = y4[i];
        s += v.x + v.y + v.z + v.w;
        ss = fmaf(v.x, v.x, ss); ss = fmaf(v.y, v.y, ss);
        ss = fmaf(v.z, v.z, ss); ss = fmaf(v.w, v.w, ss);
    }
    __shared__ float sh0[256];
    __shared__ float sh1[256];
    sh0[threadIdx.x] = s; sh1[threadIdx.x] = ss;
    __syncthreads();
    for (int off = 128; off > 0; off >>= 1) {
        if (threadIdx.x < off) {
            sh0[threadIdx.x] += sh0[threadIdx.x + off];
            sh1[threadIdx.x] += sh1[threadIdx.x + off];
        }
        __syncthreads();
    }
    if (threadIdx.x == 0) {
        float2 pp; pp.x = sh0[0]; pp.y = sh1[0];
        part[bg * K + kblk] = pp;
    }
}

__global__ __launch_bounds__(256) void gn_apply(
    float* __restrict__ y, const float* __restrict__ gamma,
    const float* __restrict__ beta, const float2* __restrict__ part,
    int HWshift, int grpC, int K)
{
    const int kblk = blockIdx.x;
    const int bg = blockIdx.y;
    const int b = bg >> 5, g = bg & 31;
    const int C = grpC << 5;
    const size_t base = ((size_t)b * C + (size_t)g * grpC) << HWshift;
    const int count4 = (grpC << HWshift) >> 2;
    const int chunk4 = count4 / K;
    const int ofs4 = kblk * chunk4;
    float4* y4 = (float4*)(y + base);

    float s = 0.f, ss = 0.f;
    for (int k = 0; k < K; ++k) {
        float2 pp = part[bg * K + k];
        s += pp.x; ss += pp.y;
    }
    const float inv = 1.f / (float)(count4 * 4);
    const float mean = s * inv;
    const float var = ss * inv - mean * mean;
    const float rstd = rsqrtf(var + EPS);

    const int HW4shift = HWshift - 2;
    for (int i = ofs4 + threadIdx.x; i < ofs4 + chunk4; i += 256) {
        int c = g * grpC + (i >> HW4shift);
        float ga = gamma[c], be = beta[c];
        float4 v = y4[i];
        float t0 = (v.x - mean) * rstd * ga + be;
        float t1 = (v.y - mean) * rstd * ga + be;
        float t2 = (v.z - mean) * rstd * ga + be;
        float t3 = (v.w - mean) * rstd * ga + be;
        v.x = t0 / (1.f + __expf(-t0));
        v.y = t1 / (1.f + __expf(-t1));
        v.z = t2 / (1.f + __expf(-t2));
        v.w = t3 / (1.f + __expf(-t3));
        y4[i] = v;
    }
}

// ====================== 1x1 conv (proven) ==================================
template <int Cin, int Cout, int HW, int CO_T>
__global__ __launch_bounds__(256) void conv1x1_k(
    const float* __restrict__ x, const float* __restrict__ w,
    const float* __restrict__ bias, float* __restrict__ y)
{
    const int n = blockIdx.z;
    const int co0 = blockIdx.y * CO_T;
    const int s = blockIdx.x * 256 + threadIdx.x;
    const float* xp = x + (size_t)n * Cin * HW + s;

    float acc[CO_T];
    #pragma unroll
    for (int u = 0; u < CO_T; ++u) acc[u] = bias[co0 + u];

    for (int ci = 0; ci < Cin; ++ci) {
        float v = xp[(size_t)ci * HW];
        #pragma unroll
        for (int u = 0; u < CO_T; ++u)
            acc[u] = fmaf(v, w[(size_t)(co0 + u) * Cin + ci], acc[u]);
    }
    #pragma unroll
    for (int u = 0; u < CO_T; ++u)
        y[(size_t)(n * Cout + co0 + u) * HW + s] = acc[u];
}

// ============================== VQ (proven) ================================
__global__ __launch_bounds__(256) void cb_norm(
    const float* __restrict__ cb, float* __restrict__ cn)
{
    int j = blockIdx.x * 256 + threadIdx.x;
    const float* c = cb + (size_t)j * 32;
    float s = 0.f;
    #pragma unroll
    for (int k = 0; k < 32; ++k) s = fmaf(c[k], c[k], s);
    cn[j] = s;
}

__global__ __launch_bounds__(256) void vq_kernel(
    const float* __restrict__ z, const float* __restrict__ cb,
    const float* __restrict__ cn, float* __restrict__ q,
    float* __restrict__ idxf)
{
    const int row = blockIdx.x * 4 + (threadIdx.x >> 6);
    const int lane = threadIdx.x & 63;
    const float* zr = z + (size_t)row * 32;
    float zreg[32];
    #pragma unroll
    for (int k = 0; k < 32; ++k) zreg[k] = zr[k];
    float zn = 0.f;
    #pragma unroll
    for (int k = 0; k < 32; ++k) zn = fmaf(zreg[k], zreg[k], zn);

    float best = 3.4e38f;
    int bj = 0;
    for (int ii = 0; ii < 16; ++ii) {
        int j = lane * 16 + ii;
        const float* c = cb + (size_t)j * 32;
        float dot = 0.f;
        #pragma unroll
        for (int k = 0; k < 32; ++k) dot = fmaf(zreg[k], c[k], dot);
        float d = zn + cn[j] - 2.f * dot;
        if (d < best) { best = d; bj = j; }
    }
    #pragma unroll
    for (int off = 1; off < 64; off <<= 1) {
        float ob = __shfl_xor(best, off);
        int oj = __shfl_xor(bj, off);
        if (ob < best || (ob == best && oj < bj)) { best = ob; bj = oj; }
    }
    if (lane < 32) q[(size_t)row * 32 + lane] = cb[(size_t)bj * 32 + lane];
    if (lane == 0) idxf[row] = (float)bj;
}

// ======= fp32 convT (round-4 proven) — dec3 (Cout=3, tanh) =================
template <int Cin, int CO_T, int CICHUNK>
__device__ __forceinline__ void stage_weights(
    const float* __restrict__ wb, int ci0, float4* __restrict__ lds4)
{
    constexpr int W4 = CICHUNK * CO_T * 4;
    for (int g4 = threadIdx.x; g4 < W4; g4 += blockDim.x) {
        int u = g4 / (CICHUNK * 4);
        int r4 = g4 - u * (CICHUNK * 4);
        lds4[g4] = ((const float4*)(wb + (size_t)u * Cin * 16 + (size_t)ci0 * 16))[r4];
    }
}

template <int Cin, int Cout, int Hin, int Win, int CO_T, int CICHUNK, bool TANH>
__global__ __launch_bounds__(256) void convt2_lds(
    const float* __restrict__ x, const float* __restrict__ w,
    const float* __restrict__ bias, float* __restrict__ y)
{
    constexpr int Wt2 = Win / 2;
    __shared__ float4 wlds[CICHUNK * CO_T * 4];

    const int n = blockIdx.z;
    const int co0 = blockIdx.y * CO_T;
    const int local = blockIdx.x * 256 + threadIdx.x;
    const int jt = local & (Wt2 - 1);
    const int i = local / Wt2;
    const int j0 = jt << 1;

    const float* __restrict__ xn = x + (size_t)n * Cin * Hin * Win;
    const float* __restrict__ wb = w + (size_t)co0 * Cin * 16;

    const bool rm0 = (i > 0), rm2 = (i + 1 < Hin);
    const bool cmL = (jt > 0), cmR = (jt < Wt2 - 1);
    const int ro0 = rm0 ? (i - 1) : 0;
    const int ro2 = rm2 ? (i + 1) : 0;

    float acc[CO_T][2][4];
    #pragma unroll
    for (int u = 0; u < CO_T; ++u)
        #pragma unroll
        for (int p = 0; p < 2; ++p)
            acc[u][p][0] = acc[u][p][1] = acc[u][p][2] = acc[u][p][3] = 0.f;

    for (int ci0 = 0; ci0 < Cin; ci0 += CICHUNK) {
        if (ci0) __syncthreads();
        stage_weights<Cin, CO_T, CICHUNK>(wb, ci0, wlds);
        __syncthreads();

        for (int cic = 0; cic < CICHUNK; ++cic) {
            const int ci = ci0 + cic;
            const float* xp = xn + (size_t)ci * Hin * Win;
            float xr[3][4];
            {
                const int rows[3] = {ro0, i, ro2};
                const bool rvn[3] = {rm0, true, rm2};
                #pragma unroll
                for (int r = 0; r < 3; ++r) {
                    const float* rp = xp + (size_t)rows[r] * Win;
                    float2 m = *(const float2*)(rp + j0);
                    float eL = cmL ? rp[j0 - 1] : 0.f;
                    float eR = cmR ? rp[j0 + 2] : 0.f;
                    bool rk = rvn[r];
                    xr[r][0] = rk ? eL : 0.f;
                    xr[r][1] = rk ? m.x : 0.f;
                    xr[r][2] = rk ? m.y : 0.f;
                    xr[r][3] = rk ? eR : 0.f;
                }
            }
            #pragma unroll
            for (int u = 0; u < CO_T; ++u) {
                const int wbase = (cic * CO_T + u) * 4;
                float4 wq0 = wlds[wbase + 0];
                float4 wq1 = wlds[wbase + 1];
                float4 wq2 = wlds[wbase + 2];
                float4 wq3 = wlds[wbase + 3];
                #pragma unroll
                for (int p = 0; p < 2; ++p) {
                    float x00 = xr[0][p], x01 = xr[0][p + 1], x02 = xr[0][p + 2];
                    float x10 = xr[1][p], x11 = xr[1][p + 1], x12 = xr[1][p + 2];
                    float x20 = xr[2][p], x21 = xr[2][p + 1], x22 = xr[2][p + 2];
                    float* a = acc[u][p];
                    a[0] = fmaf(x00, wq0.x, a[0]); a[0] = fmaf(x01, wq0.z, a[0]);
                    a[0] = fmaf(x10, wq2.x, a[0]); a[0] = fmaf(x11, wq2.z, a[0]);
                    a[1] = fmaf(x01, wq0.y, a[1]); a[1] = fmaf(x02, wq0.w, a[1]);
                    a[1] = fmaf(x11, wq2.y, a[1]); a[1] = fmaf(x12, wq2.w, a[1]);
                    a[2] = fmaf(x10, wq1.x, a[2]); a[2] = fmaf(x11, wq1.z, a[2]);
                    a[2] = fmaf(x20, wq3.x, a[2]); a[2] = fmaf(x21, wq3.z, a[2]);
                    a[3] = fmaf(x11, wq1.y, a[3]); a[3] = fmaf(x12, wq1.w, a[3]);
                    a[3] = fmaf(x21, wq3.y, a[3]); a[3] = fmaf(x22, wq3.w, a[3]);
                }
            }
        }
    }

    constexpr int Hout = Hin * 2, Wout = Win * 2;
    #pragma unroll
    for (int u = 0; u < CO_T; ++u) {
        float b = bias[co0 + u];
        float r00 = acc[u][0][0] + b, r01 = acc[u][0][1] + b;
        float r02 = acc[u][1][0] + b, r03 = acc[u][1][1] + b;
        float r10 = acc[u][0][2] + b, r11 = acc[u][0][3] + b;
        float r12 = acc[u][1][2] + b, r13 = acc[u][1][3] + b;
        if (TANH) {
            r00 = tanhf(r00); r01 = tanhf(r01); r02 = tanhf(r02); r03 = tanhf(r03);
            r10 = tanhf(r10); r11 = tanhf(r11); r12 = tanhf(r12); r13 = tanhf(r13);
        }
        float* yp = y + (((size_t)(n * Cout + co0 + u)) * Hout + (i << 1)) * Wout + (jt << 2);
        float4 o;
        o.x = r00; o.y = r01; o.z = r02; o.w = r03; *(float4*)yp = o;
        o.x = r10; o.y = r11; o.z = r12; o.w = r13; *(float4*)(yp + Wout) = o;
    }
}

// ================================ launch ===================================
extern "C" void kernel_launch(void* const* d_in, const int* in_sizes, int n_in,
                              void* d_out, int out_size, void* d_ws, size_t ws_size,
                              hipStream_t stream)
{
    const float* x       = (const float*)d_in[0];
    const float* enc0_w  = (const float*)d_in[1];
    const float* enc0_b  = (const float*)d_in[2];
    const float* enc0_g  = (const float*)d_in[3];
    const float* enc0_bt = (const float*)d_in[4];
    const float* enc1_w  = (const float*)d_in[5];
    const float* enc1_b  = (const float*)d_in[6];
    const float* enc1_g  = (const float*)d_in[7];
    const float* enc1_bt = (const float*)d_in[8];
    const float* enc2_w  = (const float*)d_in[9];
    const float* enc2_b  = (const float*)d_in[10];
    const float* enc2_g  = (const float*)d_in[11];
    const float* enc2_bt = (const float*)d_in[12];
    const float* enc3_w  = (const float*)d_in[13];
    const float* enc3_b  = (const float*)d_in[14];
    const float* codebook= (const float*)d_in[15];
    const float* dec0_w  = (const float*)d_in[16];
    const float* dec0_b  = (const float*)d_in[17];
    const float* dec1_w  = (const float*)d_in[18];
    const float* dec1_b  = (const float*)d_in[19];
    const float* dec1_g  = (const float*)d_in[20];
    const float* dec1_bt = (const float*)d_in[21];
    const float* dec2_w  = (const float*)d_in[22];
    const float* dec2_b  = (const float*)d_in[23];
    const float* dec2_g  = (const float*)d_in[24];
    const float* dec2_bt = (const float*)d_in[25];
    const float* dec3_w  = (const float*)d_in[26];
    const float* dec3_b  = (const float*)d_in[27];

    float* ws = (float*)d_ws;
    float*  A  = ws;                       // 33,554,432 floats (134 MB)
    float*  B  = ws + 33554432;            // 16,777,216 floats (67 MB)
    float*  C  = ws + 50331648;            //  8,388,608 floats (33.6 MB)
    float*  Z  = ws + 58720256;            //    524,288 floats (2 MB)
    float*  CN = ws + 59244544;            //      1,024 floats
    float2* GP = (float2*)(ws + 59245568); //      8,192 float2 (gn partials)

    // split-weight scratch, time-multiplexed:
    ushort_t* WE1 = (ushort_t*)C;                 // enc1 (3.1 MB); C dead pre-enc2
    ushort_t* WE2 = (ushort_t*)A;                 // enc2 (12.6 MB); A dead post-enc1
    ushort_t* WD1 = (ushort_t*)C;                 // dec1 (4.2 MB); C dead post-enc3
    ushort_t* WD2 = (ushort_t*)(C + 4194304);     // dec2 (1 MB)

    float* out   = (float*)d_out;
    float* recon = out;                    // 3,145,728 floats
    float* qbuf  = out + 3145728;          //   524,288 floats
    float* idxf  = out + 3670016;          //    16,384 floats

    const dim3 blk(256);
    const int K = 16;
    const dim3 gngrid(K, 512);

    // ---------------- encoder ----------------
    wsplit_enc<256, 128><<<dim3(2048), blk, 0, stream>>>(enc1_w, WE1);

    conv4s2_k<3, 128, 256, 256, 8><<<dim3(16, 16, 16), blk, 0, stream>>>(
        x, enc0_w, enc0_b, A);
    gn_stats<<<gngrid, blk, 0, stream>>>(A, GP, 14, 4, K);
    gn_apply<<<gngrid, blk, 0, stream>>>(A, enc0_g, enc0_bt, GP, 14, 4, K);

    // enc1: 16x128x128x128 -> 16x256x64x64  (MFMA tap-GEMM, split-3, pipelined)
    mfenc<128, 256, 128, 128><<<dim3(128, 1, 16), blk, 0, stream>>>(
        A, WE1, enc1_b, B);

    wsplit_enc<512, 256><<<dim3(8192), blk, 0, stream>>>(enc2_w, WE2);

    gn_stats<<<gngrid, blk, 0, stream>>>(B, GP, 12, 8, K);
    gn_apply<<<gngrid, blk, 0, stream>>>(B, enc1_g, enc1_bt, GP, 12, 8, K);

    // enc2: -> 16x512x32x32  (MFMA tap-GEMM, split-3, pipelined)
    mfenc<256, 512, 64, 64><<<dim3(32, 2, 16), blk, 0, stream>>>(
        B, WE2, enc2_b, C);
    gn_stats<<<gngrid, blk, 0, stream>>>(C, GP, 10, 16, K);
    gn_apply<<<gngrid, blk, 0, stream>>>(C, enc2_g, enc2_bt, GP, 10, 16, K);

    conv1x1_k<512, 32, 1024, 8><<<dim3(4, 4, 16), blk, 0, stream>>>(
        C, enc3_w, enc3_b, Z);

    // ---------------- VQ ----------------
    cb_norm<<<dim3(4), blk, 0, stream>>>(codebook, CN);
    vq_kernel<<<dim3(16384 / 4), blk, 0, stream>>>(Z, codebook, CN, qbuf, idxf);

    // ---------------- decoder (round-7 path) ------------------------------
    wsplit_convt<256, 512, 1><<<dim3(8192), blk, 0, stream>>>(dec1_w, WD1);
    wsplit_convt<128, 256, 1><<<dim3(2048), blk, 0, stream>>>(dec2_w, WD2);

    conv1x1_k<32, 512, 1024, 8><<<dim3(4, 64, 16), blk, 0, stream>>>(
        qbuf, dec0_w, dec0_b, A);

    mfconvt<512, 256, 32, 32, 4, 1, 16, 1><<<dim3(128, 2, 16), blk, 0, stream>>>(
        A, WD1, dec1_b, B);
    gn_stats<<<gngrid, blk, 0, stream>>>(B, GP, 12, 8, K);
    gn_apply<<<gngrid, blk, 0, stream>>>(B, dec1_g, dec1_bt, GP, 12, 8, K);

    mfconvt<256, 128, 64, 64, 2, 2, 16, 1><<<dim3(256, 2, 16), blk, 0, stream>>>(
        B, WD2, dec2_b, A);
    gn_stats<<<gngrid, blk, 0, stream>>>(A, GP, 14, 4, K);
    gn_apply<<<gngrid, blk, 0, stream>>>(A, dec2_g, dec2_bt, GP, 14, 4, K);

    convt2_lds<128, 3, 128, 128, 3, 128, true><<<dim3(32, 1, 16), blk, 0, stream>>>(
        A, dec3_w, dec3_b, recon);
}

// Round 4
// 2744.394 us; speedup vs baseline: 1.2423x; 1.1143x over previous
//
#include <hip/hip_runtime.h>
#include <hip/hip_bf16.h>
#include <math.h>

// ---------------------------------------------------------------------------
// VQGAN forward, round 13.
//  - mfenc v6: round-12 pipeline (dbuf LDS + early stage_load, verified
//    685us) + 512-thread blocks for TLP:
//    * 8 waves/block, each wave owns 2 co-blocks (32 co) instead of 4 ->
//      same per-CU MFMA, half per-wave -> 2 waves/SIMD (was 1) hides the
//      ds_read->MFMA chains, splitNS VALU and barrier drain that a single
//      wave/SIMD exposed (round-12: wall 86us/block vs 12us MFMA busy).
//    * staging executed by threads 0-255 with the EXACT round-12 mapping
//      (same loads, same splitNS bits, same LDS slots, 2-way-conflict
//      ds_write) -> staged bits identical; waves 4-7 are pure compute.
//    * weight bits + per-acc-element accumulation order unchanged ->
//      z bit-identical -> idx exact.
//  - decoder: round-7/8 kernels unchanged.
// d_out = [recon 16*3*256*256 | q 16*32*32*32 | idx-as-float 16384]
// ---------------------------------------------------------------------------

#define EPS 1e-5f
typedef unsigned short ushort_t;
typedef unsigned int uint32;
typedef __attribute__((ext_vector_type(8))) short bf16x8;
typedef __attribute__((ext_vector_type(4))) float f32x4;
typedef __attribute__((ext_vector_type(4))) unsigned int u32x4;

__device__ __forceinline__ ushort_t f2bf(float x) {
    __hip_bfloat16 h = __float2bfloat16(x);
    return __builtin_bit_cast(ushort_t, h);
}
__device__ __forceinline__ float bf2f(ushort_t u) {
    __hip_bfloat16 h = __builtin_bit_cast(__hip_bfloat16, u);
    return __bfloat162float(h);
}
template <int NS>
__device__ __forceinline__ void splitNS(float x, ushort_t* p) {
    float r = x;
    #pragma unroll
    for (int s = 0; s < NS; ++s) {
        ushort_t u = f2bf(r);
        p[s] = u;
        if (s + 1 < NS) r -= bf2f(u);
    }
}

// ============ encoder weight pre-split: fragment-order layout ==============
// o[(((((s*16+tap)*KCH + kc)*CB + cb)*64 + lane)*8 + e]
//   kc = ci>>5, q = (ci>>3)&3, e = ci&7, cb = co>>4, l15 = co&15,
//   lane = q*16 + l15  (exactly the mfenc wave lane id)
template <int Cout, int Cin>
__global__ __launch_bounds__(256) void wsplit_enc(
    const float* __restrict__ w, ushort_t* __restrict__ o)
{
    constexpr int KCH = Cin / 32, CB = Cout / 16;
    int idx = blockIdx.x * 256 + threadIdx.x;
    if (idx >= Cout * Cin * 16) return;
    int tap = idx & 15;
    int ci  = (idx >> 4) % Cin;
    int co  = (idx >> 4) / Cin;
    ushort_t sp[3];
    splitNS<3>(w[idx], sp);
    const int kc = ci >> 5, q = (ci >> 3) & 3, e = ci & 7;
    const int cb = co >> 4, l15 = co & 15;
    const int lane = q * 16 + l15;
    #pragma unroll
    for (int s = 0; s < 3; ++s)
        o[((((size_t)(s * 16 + tap) * KCH + kc) * CB + cb) * 64 + lane) * 8 + e] = sp[s];
}

// A-fragment loader: one coalesced 1KB segment per (cf,s) wave load.
template <int KCH, int CB>
__device__ __forceinline__ void ldaf2(bf16x8 (&dst)[2][3],
    const ushort_t* __restrict__ wsp_t, int kc, int tap)
{
    #pragma unroll
    for (int cf = 0; cf < 2; ++cf)
        #pragma unroll
        for (int s = 0; s < 3; ++s)
            dst[cf][s] = *(const bf16x8*)(wsp_t +
                ((size_t)((s * 16 + tap) * KCH + kc) * CB + cf) * 512);
}

// ================= MFMA encoder conv k4 s2 p1: tap-GEMMs ===================
// Geometry: one oh, 32 m, 256 co per block; k=ci, KC=32. 512 threads =
// 8 waves x 2 co-blocks. LDS double-buffered
// [s(3)][row(4)][ciq(4)][cpos(68)][cie(8)] ushort; col c -> cpos =
// (c>>1)+(c&1)*34. Staging (threads 0-255) identical bits to round 12.
template <int Cin, int Cout, int Hin, int Win>
__global__ __launch_bounds__(512) void mfenc(
    const float* __restrict__ x, const ushort_t* __restrict__ wsp,
    const float* __restrict__ bias, float* __restrict__ y)
{
    constexpr int Hout = Hin / 2, Wout = Win / 2;
    constexpr int MB = 32;
    constexpr int MT = Wout / MB;
    constexpr int NCOL = 66;
    constexpr int KC = 32;
    constexpr int KCH = Cin / 32;
    constexpr int CB = Cout / 16;
    constexpr int BUFW = 3 * 4 * 4 * 68 * 8;       // ushorts per buffer (52224 B)
    __shared__ ushort_t Xs[2 * BUFW];              // 104448 B

    const int n  = blockIdx.z;
    const int oh = blockIdx.x / MT;
    const int mt = blockIdx.x % MT;
    const int M0 = mt * MB;
    const int co_base = blockIdx.y * 256;
    const int tid = threadIdx.x;
    const int wv = tid >> 6, lane = tid & 63;
    const int q = lane >> 4, l15 = lane & 15;
    const int co_w0 = co_base + wv * 32;           // 2 co-blocks per wave
    const int cb0 = (co_base >> 4) + wv * 2;
    const ushort_t* __restrict__ wsp_t = wsp + ((size_t)cb0 * 64 + lane) * 8;

    int ro[4]; bool rv[4];
    #pragma unroll
    for (int k = 0; k < 4; ++k) {
        int r = 2 * oh - 1 + k;
        rv[k] = (r >= 0) && (r < Hin);
        ro[k] = rv[k] ? r : 0;
    }

    f32x4 acc[2][2];
    #pragma unroll
    for (int a = 0; a < 2; ++a)
        #pragma unroll
        for (int b = 0; b < 2; ++b) acc[a][b] = (f32x4){0.f, 0.f, 0.f, 0.f};

    // staging ids (threads 0-255 only; mapping identical to round 12)
    const bool stg = (tid < 256);
    const int p16  = (tid >> 4) & 15;     // ci pair (2*p16, 2*p16+1)
    const int cg   = tid & 15;            // column group
    const int sciq = p16 >> 2;            // ci octet 0..3
    const int cieP = p16 & 3;             // dword index within octet

    float a0[4][5], a1[4][5];             // staged values in flight

    // all 40 loads issue together (fully unrolled, predicated)
    auto stage_load = [&](int ci0) {
        const float* b0 = x + (size_t)(n * Cin + ci0 + 2 * p16) * Hin * Win;
        const float* b1 = b0 + (size_t)Hin * Win;
        #pragma unroll
        for (int r = 0; r < 4; ++r) {
            const float* rp0 = b0 + (size_t)ro[r] * Win;
            const float* rp1 = b1 + (size_t)ro[r] * Win;
            #pragma unroll
            for (int t = 0; t < 5; ++t) {
                const int c = cg + 16 * t;
                const int gc = 2 * M0 - 1 + c;
                const bool ok = rv[r] && (c < NCOL) && (gc >= 0) && (gc < Win);
                a0[r][t] = ok ? rp0[gc] : 0.f;
                a1[r][t] = ok ? rp1[gc] : 0.f;
            }
        }
    };
    // splitNS + ds_write (same bits / same LDS slots as round 12)
    auto stage_write = [&](int buf) {
        uint32* __restrict__ dst32 = (uint32*)(Xs + buf * BUFW);
        #pragma unroll
        for (int r = 0; r < 4; ++r)
            #pragma unroll
            for (int t = 0; t < 5; ++t) {
                const int c = cg + 16 * t;
                if (c < NCOL) {
                    ushort_t s0[3], s1[3];
                    splitNS<3>(a0[r][t], s0);
                    splitNS<3>(a1[r][t], s1);
                    const int cpos = (c >> 1) + (c & 1) * 34;
                    #pragma unroll
                    for (int s = 0; s < 3; ++s)
                        dst32[((((s * 4 + r) * 4 + sciq) * 68) + cpos) * 4 + cieP] =
                            (uint32)s0[s] | ((uint32)s1[s] << 16);
                }
            }
    };

    bf16x8 afA[2][3], afB[2][3];
    ldaf2<KCH, CB>(afA, wsp_t, 0, 0);

    // prologue: stage chunk 0
    if (stg) {
        stage_load(0);
        stage_write(0);
    }
    __syncthreads();

    for (int kc = 0; kc < KCH; ++kc) {
        const int cur = kc & 1;
        const ushort_t* __restrict__ Xr = Xs + cur * BUFW;

        // issue next chunk's global loads now; latency hides under MFMA
        if (stg && kc + 1 < KCH) stage_load((kc + 1) * KC);
        __builtin_amdgcn_sched_barrier(0);   // pin load issue ahead of MFMA

        __builtin_amdgcn_s_setprio(1);
        #pragma unroll
        for (int tap = 0; tap < 16; ++tap) {
            bf16x8 (&cw)[2][3] = (tap & 1) ? afB : afA;
            bf16x8 (&nw)[2][3] = (tap & 1) ? afA : afB;
            // prefetch next tap's (or next chunk's tap-0) weight fragments
            if (tap < 15) {
                ldaf2<KCH, CB>(nw, wsp_t, kc, tap + 1);
            } else if (kc + 1 < KCH) {
                ldaf2<KCH, CB>(nw, wsp_t, kc + 1, 0);
            }

            const int kh = tap >> 2, kw = tap & 3;
            bf16x8 bx[2][3];
            const int cpbase = (kw >> 1) + (kw & 1) * 34;
            #pragma unroll
            for (int mf = 0; mf < 2; ++mf) {
                const int cpos = (mf * 16 + l15) + cpbase;
                #pragma unroll
                for (int s = 0; s < 3; ++s)
                    bx[mf][s] = *(const bf16x8*)(&Xr[((((s * 4 + kh) * 4 + q) * 68) + cpos) * 8]);
            }
            #pragma unroll
            for (int sa = 0; sa < 3; ++sa)
                #pragma unroll
                for (int sb = 0; sb < 3; ++sb) {
                    if (sa + sb >= 3) continue;
                    #pragma unroll
                    for (int cf = 0; cf < 2; ++cf)
                        #pragma unroll
                        for (int mf = 0; mf < 2; ++mf)
                            acc[cf][mf] = __builtin_amdgcn_mfma_f32_16x16x32_bf16(
                                cw[cf][sa], bx[mf][sb], acc[cf][mf], 0, 0, 0);
                }
        }
        __builtin_amdgcn_s_setprio(0);

        if (kc + 1 < KCH) {
            if (stg) stage_write(cur ^ 1);
            __syncthreads();
        }
    }

    #pragma unroll
    for (int cf = 0; cf < 2; ++cf)
        #pragma unroll
        for (int mf = 0; mf < 2; ++mf) {
            const int ow = M0 + mf * 16 + l15;
            #pragma unroll
            for (int rg = 0; rg < 4; ++rg) {
                const int co = co_w0 + cf * 16 + q * 4 + rg;
                y[(((size_t)n * Cout + co) * Hout + oh) * Wout + ow] =
                    acc[cf][mf][rg] + bias[co];
            }
        }
}

// ============== decoder weight pre-split (round-7, NS=1) ===================
template <int Cout, int Cin, int NS>
__global__ __launch_bounds__(256) void wsplit_convt(
    const float* __restrict__ w, ushort_t* __restrict__ o)
{
    int idx = blockIdx.x * 256 + threadIdx.x;
    if (idx >= 4 * Cout * Cin * 4) return;
    int b  = idx & 1;
    int a  = (idx >> 1) & 1;
    int ci = (idx >> 2) % Cin;
    int co = ((idx >> 2) / Cin) % Cout;
    int p  = ((idx >> 2) / Cin) / Cout;
    int di = p >> 1, dj = p & 1;
    float v = w[(((size_t)co * Cin + ci) * 4 + (2 * a + di)) * 4 + (2 * b + dj)];
    ushort_t sp[NS];
    splitNS<NS>(v, sp);
    #pragma unroll
    for (int s = 0; s < NS; ++s)
        o[(((size_t)(s * 4 + p) * Cout + co) * Cin + ci) * 4 + a * 2 + b] = sp[s];
}

// ================= MFMA convT (round-7, unchanged) =========================
template <int Cin, int Cout, int Hin, int Win, int CO_WAVES, int M_WAVES, int KC, int NS>
__global__ __launch_bounds__(256) void mfconvt(
    const float* __restrict__ x, const ushort_t* __restrict__ wsp,
    const float* __restrict__ bias, float* __restrict__ y)
{
    constexpr int NDp = Win / 2 + 2;
    constexpr int CO_B = CO_WAVES * 32;
    static_assert(CO_WAVES * M_WAVES == 4, "4 waves");
    static_assert(M_WAVES * 32 == Win, "block spans full row");
    static_assert(KC % 8 == 0, "k-step = 8 ci");
    __shared__ unsigned int Xs[NS * KC * 2 * 2 * NDp];

    const int bi = blockIdx.x;
    const int i = bi >> 2;
    const int p = bi & 3;
    const int di = p >> 1, dj = p & 1;
    const int n = blockIdx.z;
    const int co_base = blockIdx.y * CO_B;
    const int tid = threadIdx.x;
    const int wv = tid >> 6, lane = tid & 63;
    const int cw = wv / M_WAVES, mw = wv % M_WAVES;
    const int co_w0 = co_base + cw * 32;
    const int m_w0 = mw * 32;
    const int q = lane >> 4, l15 = lane & 15;

    const int r0 = i - 1 + di, r1 = i + di;
    const bool v0 = (r0 >= 0), v1 = (r1 < Hin);
    const int r0c = v0 ? r0 : 0, r1c = v1 ? r1 : 0;

    f32x4 acc[2][2];
    #pragma unroll
    for (int a = 0; a < 2; ++a)
        #pragma unroll
        for (int b = 0; b < 2; ++b) acc[a][b] = (f32x4){0.f, 0.f, 0.f, 0.f};

    constexpr int SEGW = Win / 4;
    constexpr int SEGS = KC * 2 * SEGW;

    for (int ci0 = 0; ci0 < Cin; ci0 += KC) {
        if (ci0) __syncthreads();
        for (int seg = tid; seg < SEGS; seg += 256) {
            const int c0 = (seg % SEGW) * 4;
            const int rem = seg / SEGW;
            const int a = rem & 1;
            const int ci = rem >> 1;
            const bool rok = a ? v1 : v0;
            const int gr = a ? r1c : r0c;
            const float* rp = x + ((size_t)(n * Cin + ci0 + ci) * Hin + gr) * Win;
            float v[5];
            v[0] = (rok && c0 > 0) ? rp[c0 - 1] : 0.f;
            #pragma unroll
            for (int t = 1; t < 5; ++t) v[t] = rok ? rp[c0 + t - 1] : 0.f;
            ushort_t sp[5][NS];
            #pragma unroll
            for (int t = 0; t < 5; ++t) splitNS<NS>(v[t], sp[t]);
            #pragma unroll
            for (int s = 0; s < NS; ++s) {
                const int base = ((s * KC + ci) * 2 + a) * 2 * NDp;
                Xs[base + (c0 >> 1)]           = (unsigned)sp[1][s] | ((unsigned)sp[2][s] << 16);
                Xs[base + (c0 >> 1) + 1]       = (unsigned)sp[3][s] | ((unsigned)sp[4][s] << 16);
                Xs[base + NDp + (c0 >> 1)]     = (unsigned)sp[0][s] | ((unsigned)sp[1][s] << 16);
                Xs[base + NDp + (c0 >> 1) + 1] = (unsigned)sp[2][s] | ((unsigned)sp[3][s] << 16);
                if (c0 == Win - 4)
                    Xs[base + NDp + (Win >> 1)] = (unsigned)sp[4][s];
            }
        }
        __syncthreads();

        #pragma unroll
        for (int cs = 0; cs < KC; cs += 8) {
            bf16x8 af[2][NS];
            #pragma unroll
            for (int cf = 0; cf < 2; ++cf) {
                const int co = co_w0 + cf * 16 + l15;
                #pragma unroll
                for (int s = 0; s < NS; ++s) {
                    const ushort_t* ap = wsp +
                        ((size_t)(s * 4 + p) * Cout + co) * ((size_t)Cin * 4) +
                        (size_t)(ci0 + cs) * 4 + q * 8;
                    af[cf][s] = *(const bf16x8*)ap;
                }
            }
            bf16x8 bfr[2][NS];
            const int ciA = cs + q * 2;
            #pragma unroll
            for (int mf = 0; mf < 2; ++mf) {
                const int m = m_w0 + mf * 16 + l15;
                const int c = m - 1 + dj;
                const int copy = c & 1;
                const int idx = (c + 1) >> 1;
                #pragma unroll
                for (int s = 0; s < NS; ++s) {
                    u32x4 bd;
                    bd.x = Xs[((s * KC + ciA) * 2 + 0) * 2 * NDp + copy * NDp + idx];
                    bd.y = Xs[((s * KC + ciA) * 2 + 1) * 2 * NDp + copy * NDp + idx];
                    bd.z = Xs[((s * KC + ciA + 1) * 2 + 0) * 2 * NDp + copy * NDp + idx];
                    bd.w = Xs[((s * KC + ciA + 1) * 2 + 1) * 2 * NDp + copy * NDp + idx];
                    bfr[mf][s] = __builtin_bit_cast(bf16x8, bd);
                }
            }
            #pragma unroll
            for (int sa = 0; sa < NS; ++sa)
                #pragma unroll
                for (int sb = 0; sb < NS; ++sb) {
                    if (sa + sb >= NS) continue;
                    #pragma unroll
                    for (int cf = 0; cf < 2; ++cf)
                        #pragma unroll
                        for (int mf = 0; mf < 2; ++mf)
                            acc[cf][mf] = __builtin_amdgcn_mfma_f32_16x16x32_bf16(
                                af[cf][sa], bfr[mf][sb], acc[cf][mf], 0, 0, 0);
                }
        }
    }

    constexpr int Ho2 = Hin * 2, Wo2 = Win * 2;
    const int orow = 2 * i + di;
    #pragma unroll
    for (int cf = 0; cf < 2; ++cf)
        #pragma unroll
        for (int mf = 0; mf < 2; ++mf) {
            const int ocol = 2 * (m_w0 + mf * 16 + l15) + dj;
            #pragma unroll
            for (int rg = 0; rg < 4; ++rg) {
                const int co = co_w0 + cf * 16 + q * 4 + rg;
                y[(((size_t)n * Cout + co) * Ho2 + orow) * Wo2 + ocol] =
                    acc[cf][mf][rg] + bias[co];
            }
        }
}

// ============== conv k4 s2 p1 (round-3 proven fp32) — enc0 only ============
template <int Cin, int Cout, int Hin, int Win, int CO_T>
__global__ __launch_bounds__(256) void conv4s2_k(
    const float* __restrict__ x, const float* __restrict__ w,
    const float* __restrict__ bias, float* __restrict__ y)
{
    constexpr int Hout = Hin / 2, Wout = Win / 2, Wt = Wout / 4;
    const int n   = blockIdx.z;
    const int co0 = blockIdx.y * CO_T;
    const int local = blockIdx.x * 256 + threadIdx.x;
    const int wt = local & (Wt - 1);
    const int oh = local / Wt;
    const int iw0 = (wt << 3) - 1;
    const int ih0 = (oh << 1) - 1;

    const float* __restrict__ xn = x + (size_t)n * Cin * Hin * Win;
    const float* __restrict__ wb = w + (size_t)co0 * Cin * 16;

    const bool cL = (wt > 0);
    const bool cR = (wt < Wt - 1);

    float acc[CO_T][4];
    #pragma unroll
    for (int u = 0; u < CO_T; ++u)
        acc[u][0] = acc[u][1] = acc[u][2] = acc[u][3] = 0.f;

    bool rv[4]; int ro[4];
    #pragma unroll
    for (int k = 0; k < 4; ++k) {
        int r = ih0 + k;
        rv[k] = (r >= 0) && (r < Hin);
        ro[k] = rv[k] ? r : 0;
    }

    for (int ci = 0; ci < Cin; ++ci) {
        const float* xp = xn + (size_t)ci * Hin * Win;
        float xv[4][10];
        #pragma unroll
        for (int k = 0; k < 4; ++k) {
            const float* rp = xp + (size_t)ro[k] * Win;
            float4 m0 = *(const float4*)(rp + (wt << 3));
            float4 m1 = *(const float4*)(rp + (wt << 3) + 4);
            float e0 = cL ? rp[iw0] : 0.f;
            float e9 = cR ? rp[iw0 + 9] : 0.f;
            bool rk = rv[k];
            xv[k][0] = rk ? e0 : 0.f;
            xv[k][1] = rk ? m0.x : 0.f;
            xv[k][2] = rk ? m0.y : 0.f;
            xv[k][3] = rk ? m0.z : 0.f;
            xv[k][4] = rk ? m0.w : 0.f;
            xv[k][5] = rk ? m1.x : 0.f;
            xv[k][6] = rk ? m1.y : 0.f;
            xv[k][7] = rk ? m1.z : 0.f;
            xv[k][8] = rk ? m1.w : 0.f;
            xv[k][9] = rk ? e9 : 0.f;
        }
        #pragma unroll
        for (int u = 0; u < CO_T; ++u) {
            const float* wp = wb + ((size_t)u * Cin + ci) * 16;
            #pragma unroll
            for (int kh = 0; kh < 4; ++kh) {
                #pragma unroll
                for (int kw = 0; kw < 4; ++kw) {
                    float wv = wp[kh * 4 + kw];
                    acc[u][0] = fmaf(xv[kh][kw + 0], wv, acc[u][0]);
                    acc[u][1] = fmaf(xv[kh][kw + 2], wv, acc[u][1]);
                    acc[u][2] = fmaf(xv[kh][kw + 4], wv, acc[u][2]);
                    acc[u][3] = fmaf(xv[kh][kw + 6], wv, acc[u][3]);
                }
            }
        }
    }

    #pragma unroll
    for (int u = 0; u < CO_T; ++u) {
        float b = bias[co0 + u];
        float4 o;
        o.x = acc[u][0] + b; o.y = acc[u][1] + b;
        o.z = acc[u][2] + b; o.w = acc[u][3] + b;
        float* yp = y + (((size_t)(n * Cout + co0 + u)) * Hout + oh) * Wout + (wt << 2);
        *(float4*)yp = o;
    }
}

// ==================== GroupNorm 2-stage (proven) ===========================
__global__ __launch_bounds__(256) void gn_stats(
    const float* __restrict__ y, float2* __restrict__ part,
    int HWshift, int grpC, int K)
{
    const int kblk = blockIdx.x;
    const int bg = blockIdx.y;
    const int b = bg >> 5, g = bg & 31;
    const int C = grpC << 5;
    const size_t base = ((size_t)b * C + (size_t)g * grpC) << HWshift;
    const int count4 = (grpC << HWshift) >> 2;
    const int chunk4 = count4 / K;
    const int ofs4 = kblk * chunk4;
    const float4* y4 = (const float4*)(y + base);

    float s = 0.f, ss = 0.f;
    for (int i = ofs4 + threadIdx.x; i < ofs4 + chunk4; i += 256) {
        float4 v = y4[i];
        s += v.x + v.y + v.z + v.w;
        ss = fmaf(v.x, v.x, ss); ss = fmaf(v.y, v.y, ss);
        ss = fmaf(v.z, v.z, ss); ss = fmaf(v.w, v.w, ss);
    }
    __shared__ float sh0[256];
    __shared__ float sh1[256];
    sh0[threadIdx.x] = s; sh1[threadIdx.x] = ss;
    __syncthreads();
    for (int off = 128; off > 0; off >>= 1) {
        if (threadIdx.x < off) {
            sh0[threadIdx.x] += sh0[threadIdx.x + off];
            sh1[threadIdx.x] += sh1[threadIdx.x + off];
        }
        __syncthreads();
    }
    if (threadIdx.x == 0) {
        float2 pp; pp.x = sh0[0]; pp.y = sh1[0];
        part[bg * K + kblk] = pp;
    }
}

__global__ __launch_bounds__(256) void gn_apply(
    float* __restrict__ y, const float* __restrict__ gamma,
    const float* __restrict__ beta, const float2* __restrict__ part,
    int HWshift, int grpC, int K)
{
    const int kblk = blockIdx.x;
    const int bg = blockIdx.y;
    const int b = bg >> 5, g = bg & 31;
    const int C = grpC << 5;
    const size_t base = ((size_t)b * C + (size_t)g * grpC) << HWshift;
    const int count4 = (grpC << HWshift) >> 2;
    const int chunk4 = count4 / K;
    const int ofs4 = kblk * chunk4;
    float4* y4 = (float4*)(y + base);

    float s = 0.f, ss = 0.f;
    for (int k = 0; k < K; ++k) {
        float2 pp = part[bg * K + k];
        s += pp.x; ss += pp.y;
    }
    const float inv = 1.f / (float)(count4 * 4);
    const float mean = s * inv;
    const float var = ss * inv - mean * mean;
    const float rstd = rsqrtf(var + EPS);

    const int HW4shift = HWshift - 2;
    for (int i = ofs4 + threadIdx.x; i < ofs4 + chunk4; i += 256) {
        int c = g * grpC + (i >> HW4shift);
        float ga = gamma[c], be = beta[c];
        float4 v = y4[i];
        float t0 = (v.x - mean) * rstd * ga + be;
        float t1 = (v.y - mean) * rstd * ga + be;
        float t2 = (v.z - mean) * rstd * ga + be;
        float t3 = (v.w - mean) * rstd * ga + be;
        v.x = t0 / (1.f + __expf(-t0));
        v.y = t1 / (1.f + __expf(-t1));
        v.z = t2 / (1.f + __expf(-t2));
        v.w = t3 / (1.f + __expf(-t3));
        y4[i] = v;
    }
}

// ====================== 1x1 conv (proven) ==================================
template <int Cin, int Cout, int HW, int CO_T>
__global__ __launch_bounds__(256) void conv1x1_k(
    const float* __restrict__ x, const float* __restrict__ w,
    const float* __restrict__ bias, float* __restrict__ y)
{
    const int n = blockIdx.z;
    const int co0 = blockIdx.y * CO_T;
    const int s = blockIdx.x * 256 + threadIdx.x;
    const float* xp = x + (size_t)n * Cin * HW + s;

    float acc[CO_T];
    #pragma unroll
    for (int u = 0; u < CO_T; ++u) acc[u] = bias[co0 + u];

    for (int ci = 0; ci < Cin; ++ci) {
        float v = xp[(size_t)ci * HW];
        #pragma unroll
        for (int u = 0; u < CO_T; ++u)
            acc[u] = fmaf(v, w[(size_t)(co0 + u) * Cin + ci], acc[u]);
    }
    #pragma unroll
    for (int u = 0; u < CO_T; ++u)
        y[(size_t)(n * Cout + co0 + u) * HW + s] = acc[u];
}

// ============================== VQ (proven) ================================
__global__ __launch_bounds__(256) void cb_norm(
    const float* __restrict__ cb, float* __restrict__ cn)
{
    int j = blockIdx.x * 256 + threadIdx.x;
    const float* c = cb + (size_t)j * 32;
    float s = 0.f;
    #pragma unroll
    for (int k = 0; k < 32; ++k) s = fmaf(c[k], c[k], s);
    cn[j] = s;
}

__global__ __launch_bounds__(256) void vq_kernel(
    const float* __restrict__ z, const float* __restrict__ cb,
    const float* __restrict__ cn, float* __restrict__ q,
    float* __restrict__ idxf)
{
    const int row = blockIdx.x * 4 + (threadIdx.x >> 6);
    const int lane = threadIdx.x & 63;
    const float* zr = z + (size_t)row * 32;
    float zreg[32];
    #pragma unroll
    for (int k = 0; k < 32; ++k) zreg[k] = zr[k];
    float zn = 0.f;
    #pragma unroll
    for (int k = 0; k < 32; ++k) zn = fmaf(zreg[k], zreg[k], zn);

    float best = 3.4e38f;
    int bj = 0;
    for (int ii = 0; ii < 16; ++ii) {
        int j = lane * 16 + ii;
        const float* c = cb + (size_t)j * 32;
        float dot = 0.f;
        #pragma unroll
        for (int k = 0; k < 32; ++k) dot = fmaf(zreg[k], c[k], dot);
        float d = zn + cn[j] - 2.f * dot;
        if (d < best) { best = d; bj = j; }
    }
    #pragma unroll
    for (int off = 1; off < 64; off <<= 1) {
        float ob = __shfl_xor(best, off);
        int oj = __shfl_xor(bj, off);
        if (ob < best || (ob == best && oj < bj)) { best = ob; bj = oj; }
    }
    if (lane < 32) q[(size_t)row * 32 + lane] = cb[(size_t)bj * 32 + lane];
    if (lane == 0) idxf[row] = (float)bj;
}

// ======= fp32 convT (round-4 proven) — dec3 (Cout=3, tanh) =================
template <int Cin, int CO_T, int CICHUNK>
__device__ __forceinline__ void stage_weights(
    const float* __restrict__ wb, int ci0, float4* __restrict__ lds4)
{
    constexpr int W4 = CICHUNK * CO_T * 4;
    for (int g4 = threadIdx.x; g4 < W4; g4 += blockDim.x) {
        int u = g4 / (CICHUNK * 4);
        int r4 = g4 - u * (CICHUNK * 4);
        lds4[g4] = ((const float4*)(wb + (size_t)u * Cin * 16 + (size_t)ci0 * 16))[r4];
    }
}

template <int Cin, int Cout, int Hin, int Win, int CO_T, int CICHUNK, bool TANH>
__global__ __launch_bounds__(256) void convt2_lds(
    const float* __restrict__ x, const float* __restrict__ w,
    const float* __restrict__ bias, float* __restrict__ y)
{
    constexpr int Wt2 = Win / 2;
    __shared__ float4 wlds[CICHUNK * CO_T * 4];

    const int n = blockIdx.z;
    const int co0 = blockIdx.y * CO_T;
    const int local = blockIdx.x * 256 + threadIdx.x;
    const int jt = local & (Wt2 - 1);
    const int i = local / Wt2;
    const int j0 = jt << 1;

    const float* __restrict__ xn = x + (size_t)n * Cin * Hin * Win;
    const float* __restrict__ wb = w + (size_t)co0 * Cin * 16;

    const bool rm0 = (i > 0), rm2 = (i + 1 < Hin);
    const bool cmL = (jt > 0), cmR = (jt < Wt2 - 1);
    const int ro0 = rm0 ? (i - 1) : 0;
    const int ro2 = rm2 ? (i + 1) : 0;

    float acc[CO_T][2][4];
    #pragma unroll
    for (int u = 0; u < CO_T; ++u)
        #pragma unroll
        for (int p = 0; p < 2; ++p)
            acc[u][p][0] = acc[u][p][1] = acc[u][p][2] = acc[u][p][3] = 0.f;

    for (int ci0 = 0; ci0 < Cin; ci0 += CICHUNK) {
        if (ci0) __syncthreads();
        stage_weights<Cin, CO_T, CICHUNK>(wb, ci0, wlds);
        __syncthreads();

        for (int cic = 0; cic < CICHUNK; ++cic) {
            const int ci = ci0 + cic;
            const float* xp = xn + (size_t)ci * Hin * Win;
            float xr[3][4];
            {
                const int rows[3] = {ro0, i, ro2};
                const bool rvn[3] = {rm0, true, rm2};
                #pragma unroll
                for (int r = 0; r < 3; ++r) {
                    const float* rp = xp + (size_t)rows[r] * Win;
                    float2 m = *(const float2*)(rp + j0);
                    float eL = cmL ? rp[j0 - 1] : 0.f;
                    float eR = cmR ? rp[j0 + 2] : 0.f;
                    bool rk = rvn[r];
                    xr[r][0] = rk ? eL : 0.f;
                    xr[r][1] = rk ? m.x : 0.f;
                    xr[r][2] = rk ? m.y : 0.f;
                    xr[r][3] = rk ? eR : 0.f;
                }
            }
            #pragma unroll
            for (int u = 0; u < CO_T; ++u) {
                const int wbase = (cic * CO_T + u) * 4;
                float4 wq0 = wlds[wbase + 0];
                float4 wq1 = wlds[wbase + 1];
                float4 wq2 = wlds[wbase + 2];
                float4 wq3 = wlds[wbase + 3];
                #pragma unroll
                for (int p = 0; p < 2; ++p) {
                    float x00 = xr[0][p], x01 = xr[0][p + 1], x02 = xr[0][p + 2];
                    float x10 = xr[1][p], x11 = xr[1][p + 1], x12 = xr[1][p + 2];
                    float x20 = xr[2][p], x21 = xr[2][p + 1], x22 = xr[2][p + 2];
                    float* a = acc[u][p];
                    a[0] = fmaf(x00, wq0.x, a[0]); a[0] = fmaf(x01, wq0.z, a[0]);
                    a[0] = fmaf(x10, wq2.x, a[0]); a[0] = fmaf(x11, wq2.z, a[0]);
                    a[1] = fmaf(x01, wq0.y, a[1]); a[1] = fmaf(x02, wq0.w, a[1]);
                    a[1] = fmaf(x11, wq2.y, a[1]); a[1] = fmaf(x12, wq2.w, a[1]);
                    a[2] = fmaf(x10, wq1.x, a[2]); a[2] = fmaf(x11, wq1.z, a[2]);
                    a[2] = fmaf(x20, wq3.x, a[2]); a[2] = fmaf(x21, wq3.z, a[2]);
                    a[3] = fmaf(x11, wq1.y, a[3]); a[3] = fmaf(x12, wq1.w, a[3]);
                    a[3] = fmaf(x21, wq3.y, a[3]); a[3] = fmaf(x22, wq3.w, a[3]);
                }
            }
        }
    }

    constexpr int Hout = Hin * 2, Wout = Win * 2;
    #pragma unroll
    for (int u = 0; u < CO_T; ++u) {
        float b = bias[co0 + u];
        float r00 = acc[u][0][0] + b, r01 = acc[u][0][1] + b;
        float r02 = acc[u][1][0] + b, r03 = acc[u][1][1] + b;
        float r10 = acc[u][0][2] + b, r11 = acc[u][0][3] + b;
        float r12 = acc[u][1][2] + b, r13 = acc[u][1][3] + b;
        if (TANH) {
            r00 = tanhf(r00); r01 = tanhf(r01); r02 = tanhf(r02); r03 = tanhf(r03);
            r10 = tanhf(r10); r11 = tanhf(r11); r12 = tanhf(r12); r13 = tanhf(r13);
        }
        float* yp = y + (((size_t)(n * Cout + co0 + u)) * Hout + (i << 1)) * Wout + (jt << 2);
        float4 o;
        o.x = r00; o.y = r01; o.z = r02; o.w = r03; *(float4*)yp = o;
        o.x = r10; o.y = r11; o.z = r12; o.w = r13; *(float4*)(yp + Wout) = o;
    }
}

// ================================ launch ===================================
extern "C" void kernel_launch(void* const* d_in, const int* in_sizes, int n_in,
                              void* d_out, int out_size, void* d_ws, size_t ws_size,
                              hipStream_t stream)
{
    const float* x       = (const float*)d_in[0];
    const float* enc0_w  = (const float*)d_in[1];
    const float* enc0_b  = (const float*)d_in[2];
    const float* enc0_g  = (const float*)d_in[3];
    const float* enc0_bt = (const float*)d_in[4];
    const float* enc1_w  = (const float*)d_in[5];
    const float* enc1_b  = (const float*)d_in[6];
    const float* enc1_g  = (const float*)d_in[7];
    const float* enc1_bt = (const float*)d_in[8];
    const float* enc2_w  = (const float*)d_in[9];
    const float* enc2_b  = (const float*)d_in[10];
    const float* enc2_g  = (const float*)d_in[11];
    const float* enc2_bt = (const float*)d_in[12];
    const float* enc3_w  = (const float*)d_in[13];
    const float* enc3_b  = (const float*)d_in[14];
    const float* codebook= (const float*)d_in[15];
    const float* dec0_w  = (const float*)d_in[16];
    const float* dec0_b  = (const float*)d_in[17];
    const float* dec1_w  = (const float*)d_in[18];
    const float* dec1_b  = (const float*)d_in[19];
    const float* dec1_g  = (const float*)d_in[20];
    const float* dec1_bt = (const float*)d_in[21];
    const float* dec2_w  = (const float*)d_in[22];
    const float* dec2_b  = (const float*)d_in[23];
    const float* dec2_g  = (const float*)d_in[24];
    const float* dec2_bt = (const float*)d_in[25];
    const float* dec3_w  = (const float*)d_in[26];
    const float* dec3_b  = (const float*)d_in[27];

    float* ws = (float*)d_ws;
    float*  A  = ws;                       // 33,554,432 floats (134 MB)
    float*  B  = ws + 33554432;            // 16,777,216 floats (67 MB)
    float*  C  = ws + 50331648;            //  8,388,608 floats (33.6 MB)
    float*  Z  = ws + 58720256;            //    524,288 floats (2 MB)
    float*  CN = ws + 59244544;            //      1,024 floats
    float2* GP = (float2*)(ws + 59245568); //      8,192 float2 (gn partials)

    // split-weight scratch, time-multiplexed:
    ushort_t* WE1 = (ushort_t*)C;                 // enc1 (3.1 MB); C dead pre-enc2
    ushort_t* WE2 = (ushort_t*)A;                 // enc2 (12.6 MB); A dead post-enc1
    ushort_t* WD1 = (ushort_t*)C;                 // dec1 (4.2 MB); C dead post-enc3
    ushort_t* WD2 = (ushort_t*)(C + 4194304);     // dec2 (1 MB)

    float* out   = (float*)d_out;
    float* recon = out;                    // 3,145,728 floats
    float* qbuf  = out + 3145728;          //   524,288 floats
    float* idxf  = out + 3670016;          //    16,384 floats

    const dim3 blk(256);
    const dim3 blk512(512);
    const int K = 16;
    const dim3 gngrid(K, 512);

    // ---------------- encoder ----------------
    wsplit_enc<256, 128><<<dim3(2048), blk, 0, stream>>>(enc1_w, WE1);

    conv4s2_k<3, 128, 256, 256, 8><<<dim3(16, 16, 16), blk, 0, stream>>>(
        x, enc0_w, enc0_b, A);
    gn_stats<<<gngrid, blk, 0, stream>>>(A, GP, 14, 4, K);
    gn_apply<<<gngrid, blk, 0, stream>>>(A, enc0_g, enc0_bt, GP, 14, 4, K);

    // enc1: 16x128x128x128 -> 16x256x64x64  (MFMA tap-GEMM, 8-wave pipelined)
    mfenc<128, 256, 128, 128><<<dim3(128, 1, 16), blk512, 0, stream>>>(
        A, WE1, enc1_b, B);

    wsplit_enc<512, 256><<<dim3(8192), blk, 0, stream>>>(enc2_w, WE2);

    gn_stats<<<gngrid, blk, 0, stream>>>(B, GP, 12, 8, K);
    gn_apply<<<gngrid, blk, 0, stream>>>(B, enc1_g, enc1_bt, GP, 12, 8, K);

    // enc2: -> 16x512x32x32  (MFMA tap-GEMM, 8-wave pipelined)
    mfenc<256, 512, 64, 64><<<dim3(32, 2, 16), blk512, 0, stream>>>(
        B, WE2, enc2_b, C);
    gn_stats<<<gngrid, blk, 0, stream>>>(C, GP, 10, 16, K);
    gn_apply<<<gngrid, blk, 0, stream>>>(C, enc2_g, enc2_bt, GP, 10, 16, K);

    conv1x1_k<512, 32, 1024, 8><<<dim3(4, 4, 16), blk, 0, stream>>>(
        C, enc3_w, enc3_b, Z);

    // ---------------- VQ ----------------
    cb_norm<<<dim3(4), blk, 0, stream>>>(codebook, CN);
    vq_kernel<<<dim3(16384 / 4), blk, 0, stream>>>(Z, codebook, CN, qbuf, idxf);

    // ---------------- decoder (round-7 path) ------------------------------
    wsplit_convt<256, 512, 1><<<dim3(8192), blk, 0, stream>>>(dec1_w, WD1);
    wsplit_convt<128, 256, 1><<<dim3(2048), blk, 0, stream>>>(dec2_w, WD2);

    conv1x1_k<32, 512, 1024, 8><<<dim3(4, 64, 16), blk, 0, stream>>>(
        qbuf, dec0_w, dec0_b, A);

    mfconvt<512, 256, 32, 32, 4, 1, 16, 1><<<dim3(128, 2, 16), blk, 0, stream>>>(
        A, WD1, dec1_b, B);
    gn_stats<<<gngrid, blk, 0, stream>>>(B, GP, 12, 8, K);
    gn_apply<<<gngrid, blk, 0, stream>>>(B, dec1_g, dec1_bt, GP, 12, 8, K);

    mfconvt<256, 128, 64, 64, 2, 2, 16, 1><<<dim3(256, 2, 16), blk, 0, stream>>>(
        B, WD2, dec2_b, A);
    gn_stats<<<gngrid, blk, 0, stream>>>(A, GP, 14, 4, K);
    gn_apply<<<gngrid, blk, 0, stream>>>(A, dec2_g, dec2_bt, GP, 14, 4, K);

    convt2_lds<128, 3, 128, 128, 3, 128, true><<<dim3(32, 1, 16), blk, 0, stream>>>(
        A, dec3_w, dec3_b, recon);
}

// Round 5
// 2127.823 us; speedup vs baseline: 1.6023x; 1.2898x over previous
//
#include <hip/hip_runtime.h>
#include <hip/hip_bf16.h>
#include <math.h>

// ---------------------------------------------------------------------------
// VQGAN forward, round 14.
//  - mfconvt v2 (decoder convT): ports the proven mfenc recipe.
//    * dj-merge: one block computes BOTH column parities (they share staged
//      input rows) -> write full cachelines via float2 (WRITE_SIZE 262->134MB),
//      staging per output halved, 2x arithmetic intensity.
//    * fragment-order weight layout (new wsplit_convt): af load = one
//      coalesced 1KB wave segment, register double-buffered 1 k-step ahead.
//    * KC 16->32, LDS double-buffered, pipelined stage_load (regs, issued
//      before compute) / stage_write (after), one barrier per chunk.
//    * accumulation sequence per output element unchanged (same staged bits,
//      weight bits, chunk/cs-ascending MFMA order) -> recon bit-identical;
//      encoder untouched -> idx exact.
//  - mfenc v6 (round-13, 512-thread pipelined) unchanged.
// d_out = [recon 16*3*256*256 | q 16*32*32*32 | idx-as-float 16384]
// ---------------------------------------------------------------------------

#define EPS 1e-5f
typedef unsigned short ushort_t;
typedef unsigned int uint32;
typedef __attribute__((ext_vector_type(8))) short bf16x8;
typedef __attribute__((ext_vector_type(4))) float f32x4;
typedef __attribute__((ext_vector_type(4))) unsigned int u32x4;

__device__ __forceinline__ ushort_t f2bf(float x) {
    __hip_bfloat16 h = __float2bfloat16(x);
    return __builtin_bit_cast(ushort_t, h);
}
__device__ __forceinline__ float bf2f(ushort_t u) {
    __hip_bfloat16 h = __builtin_bit_cast(__hip_bfloat16, u);
    return __bfloat162float(h);
}
template <int NS>
__device__ __forceinline__ void splitNS(float x, ushort_t* p) {
    float r = x;
    #pragma unroll
    for (int s = 0; s < NS; ++s) {
        ushort_t u = f2bf(r);
        p[s] = u;
        if (s + 1 < NS) r -= bf2f(u);
    }
}

// ============ encoder weight pre-split: fragment-order layout ==============
template <int Cout, int Cin>
__global__ __launch_bounds__(256) void wsplit_enc(
    const float* __restrict__ w, ushort_t* __restrict__ o)
{
    constexpr int KCH = Cin / 32, CB = Cout / 16;
    int idx = blockIdx.x * 256 + threadIdx.x;
    if (idx >= Cout * Cin * 16) return;
    int tap = idx & 15;
    int ci  = (idx >> 4) % Cin;
    int co  = (idx >> 4) / Cin;
    ushort_t sp[3];
    splitNS<3>(w[idx], sp);
    const int kc = ci >> 5, q = (ci >> 3) & 3, e = ci & 7;
    const int cb = co >> 4, l15 = co & 15;
    const int lane = q * 16 + l15;
    #pragma unroll
    for (int s = 0; s < 3; ++s)
        o[((((size_t)(s * 16 + tap) * KCH + kc) * CB + cb) * 64 + lane) * 8 + e] = sp[s];
}

// A-fragment loader: one coalesced 1KB segment per (cf,s) wave load.
template <int KCH, int CB>
__device__ __forceinline__ void ldaf2(bf16x8 (&dst)[2][3],
    const ushort_t* __restrict__ wsp_t, int kc, int tap)
{
    #pragma unroll
    for (int cf = 0; cf < 2; ++cf)
        #pragma unroll
        for (int s = 0; s < 3; ++s)
            dst[cf][s] = *(const bf16x8*)(wsp_t +
                ((size_t)((s * 16 + tap) * KCH + kc) * CB + cf) * 512);
}

// ================= MFMA encoder conv k4 s2 p1 (round-13, proven) ===========
template <int Cin, int Cout, int Hin, int Win>
__global__ __launch_bounds__(512) void mfenc(
    const float* __restrict__ x, const ushort_t* __restrict__ wsp,
    const float* __restrict__ bias, float* __restrict__ y)
{
    constexpr int Hout = Hin / 2, Wout = Win / 2;
    constexpr int MB = 32;
    constexpr int MT = Wout / MB;
    constexpr int NCOL = 66;
    constexpr int KC = 32;
    constexpr int KCH = Cin / 32;
    constexpr int CB = Cout / 16;
    constexpr int BUFW = 3 * 4 * 4 * 68 * 8;       // ushorts per buffer (52224 B)
    __shared__ ushort_t Xs[2 * BUFW];              // 104448 B

    const int n  = blockIdx.z;
    const int oh = blockIdx.x / MT;
    const int mt = blockIdx.x % MT;
    const int M0 = mt * MB;
    const int co_base = blockIdx.y * 256;
    const int tid = threadIdx.x;
    const int wv = tid >> 6, lane = tid & 63;
    const int q = lane >> 4, l15 = lane & 15;
    const int co_w0 = co_base + wv * 32;           // 2 co-blocks per wave
    const int cb0 = (co_base >> 4) + wv * 2;
    const ushort_t* __restrict__ wsp_t = wsp + ((size_t)cb0 * 64 + lane) * 8;

    int ro[4]; bool rv[4];
    #pragma unroll
    for (int k = 0; k < 4; ++k) {
        int r = 2 * oh - 1 + k;
        rv[k] = (r >= 0) && (r < Hin);
        ro[k] = rv[k] ? r : 0;
    }

    f32x4 acc[2][2];
    #pragma unroll
    for (int a = 0; a < 2; ++a)
        #pragma unroll
        for (int b = 0; b < 2; ++b) acc[a][b] = (f32x4){0.f, 0.f, 0.f, 0.f};

    const bool stg = (tid < 256);
    const int p16  = (tid >> 4) & 15;
    const int cg   = tid & 15;
    const int sciq = p16 >> 2;
    const int cieP = p16 & 3;

    float a0[4][5], a1[4][5];

    auto stage_load = [&](int ci0) {
        const float* b0 = x + (size_t)(n * Cin + ci0 + 2 * p16) * Hin * Win;
        const float* b1 = b0 + (size_t)Hin * Win;
        #pragma unroll
        for (int r = 0; r < 4; ++r) {
            const float* rp0 = b0 + (size_t)ro[r] * Win;
            const float* rp1 = b1 + (size_t)ro[r] * Win;
            #pragma unroll
            for (int t = 0; t < 5; ++t) {
                const int c = cg + 16 * t;
                const int gc = 2 * M0 - 1 + c;
                const bool ok = rv[r] && (c < NCOL) && (gc >= 0) && (gc < Win);
                a0[r][t] = ok ? rp0[gc] : 0.f;
                a1[r][t] = ok ? rp1[gc] : 0.f;
            }
        }
    };
    auto stage_write = [&](int buf) {
        uint32* __restrict__ dst32 = (uint32*)(Xs + buf * BUFW);
        #pragma unroll
        for (int r = 0; r < 4; ++r)
            #pragma unroll
            for (int t = 0; t < 5; ++t) {
                const int c = cg + 16 * t;
                if (c < NCOL) {
                    ushort_t s0[3], s1[3];
                    splitNS<3>(a0[r][t], s0);
                    splitNS<3>(a1[r][t], s1);
                    const int cpos = (c >> 1) + (c & 1) * 34;
                    #pragma unroll
                    for (int s = 0; s < 3; ++s)
                        dst32[((((s * 4 + r) * 4 + sciq) * 68) + cpos) * 4 + cieP] =
                            (uint32)s0[s] | ((uint32)s1[s] << 16);
                }
            }
    };

    bf16x8 afA[2][3], afB[2][3];
    ldaf2<KCH, CB>(afA, wsp_t, 0, 0);

    if (stg) {
        stage_load(0);
        stage_write(0);
    }
    __syncthreads();

    for (int kc = 0; kc < KCH; ++kc) {
        const int cur = kc & 1;
        const ushort_t* __restrict__ Xr = Xs + cur * BUFW;

        if (stg && kc + 1 < KCH) stage_load((kc + 1) * KC);
        __builtin_amdgcn_sched_barrier(0);

        __builtin_amdgcn_s_setprio(1);
        #pragma unroll
        for (int tap = 0; tap < 16; ++tap) {
            bf16x8 (&cw)[2][3] = (tap & 1) ? afB : afA;
            bf16x8 (&nw)[2][3] = (tap & 1) ? afA : afB;
            if (tap < 15) {
                ldaf2<KCH, CB>(nw, wsp_t, kc, tap + 1);
            } else if (kc + 1 < KCH) {
                ldaf2<KCH, CB>(nw, wsp_t, kc + 1, 0);
            }

            const int kh = tap >> 2, kw = tap & 3;
            bf16x8 bx[2][3];
            const int cpbase = (kw >> 1) + (kw & 1) * 34;
            #pragma unroll
            for (int mf = 0; mf < 2; ++mf) {
                const int cpos = (mf * 16 + l15) + cpbase;
                #pragma unroll
                for (int s = 0; s < 3; ++s)
                    bx[mf][s] = *(const bf16x8*)(&Xr[((((s * 4 + kh) * 4 + q) * 68) + cpos) * 8]);
            }
            #pragma unroll
            for (int sa = 0; sa < 3; ++sa)
                #pragma unroll
                for (int sb = 0; sb < 3; ++sb) {
                    if (sa + sb >= 3) continue;
                    #pragma unroll
                    for (int cf = 0; cf < 2; ++cf)
                        #pragma unroll
                        for (int mf = 0; mf < 2; ++mf)
                            acc[cf][mf] = __builtin_amdgcn_mfma_f32_16x16x32_bf16(
                                cw[cf][sa], bx[mf][sb], acc[cf][mf], 0, 0, 0);
                }
        }
        __builtin_amdgcn_s_setprio(0);

        if (kc + 1 < KCH) {
            if (stg) stage_write(cur ^ 1);
            __syncthreads();
        }
    }

    #pragma unroll
    for (int cf = 0; cf < 2; ++cf)
        #pragma unroll
        for (int mf = 0; mf < 2; ++mf) {
            const int ow = M0 + mf * 16 + l15;
            #pragma unroll
            for (int rg = 0; rg < 4; ++rg) {
                const int co = co_w0 + cf * 16 + q * 4 + rg;
                y[(((size_t)n * Cout + co) * Hout + oh) * Wout + ow] =
                    acc[cf][mf][rg] + bias[co];
            }
        }
}

// ========= decoder weight pre-split v2: fragment-order layout ==============
// o[(((p*KST + kst)*CB + cb)*64 + lane)*8 + e]; lane = q*16+l15;
// k_flat = kst*32 + q*8 + e = ci*4 + a*2 + b; co = cb*16 + l15.
// value = w[((co*Cin + ci)*4 + (2a+di))*4 + (2b+dj)], p = 2*di+dj. NS=1.
template <int Cout, int Cin>
__global__ __launch_bounds__(256) void wsplit_convt(
    const float* __restrict__ w, ushort_t* __restrict__ o)
{
    constexpr int KST = Cin / 8;
    constexpr int CB = Cout / 16;
    int idx = blockIdx.x * 256 + threadIdx.x;
    if (idx >= 4 * KST * CB * 512) return;
    const int e = idx & 7;
    const int lane = (idx >> 3) & 63;
    int rest = idx >> 9;
    const int cb = rest % CB; rest /= CB;
    const int kst = rest % KST;
    const int p = rest / KST;
    const int q = lane >> 4, l15 = lane & 15;
    const int co = cb * 16 + l15;
    const int kf = kst * 32 + q * 8 + e;
    const int ci = kf >> 2, a = (kf >> 1) & 1, b = kf & 1;
    const int di = p >> 1, dj = p & 1;
    const float v = w[(((size_t)co * Cin + ci) * 4 + (2 * a + di)) * 4 + (2 * b + dj)];
    o[idx] = f2bf(v);
}

// ================= MFMA convT v2: dj-merged, pipelined =====================
template <int Cin, int Cout, int Hin, int Win, int CO_WAVES, int M_WAVES, int KC>
__global__ __launch_bounds__(256) void mfconvt(
    const float* __restrict__ x, const ushort_t* __restrict__ wsp,
    const float* __restrict__ bias, float* __restrict__ y)
{
    constexpr int NDp = Win / 2 + 2;
    constexpr int CO_B = CO_WAVES * 32;
    constexpr int KST = Cin / 8;
    constexpr int CB = Cout / 16;
    constexpr int KCH = Cin / KC;
    constexpr int SEGW = Win / 4;
    constexpr int SEGS = KC * 2 * SEGW;
    constexpr int NSEG = SEGS / 256;
    constexpr int BUFD = KC * 2 * 2 * NDp;         // dwords per LDS buffer
    static_assert(CO_WAVES * M_WAVES == 4, "4 waves");
    static_assert(M_WAVES * 32 == Win, "block spans full row");
    static_assert(KC % 8 == 0 && SEGS % 256 == 0, "seg mapping");
    static_assert((KC / 8) % 2 == 0, "even steps per chunk for wdbuf parity");
    __shared__ unsigned int Xs[2 * BUFD];

    const int bi = blockIdx.x;
    const int i  = bi >> 1;
    const int di = bi & 1;
    const int n = blockIdx.z;
    const int co_base = blockIdx.y * CO_B;
    const int tid = threadIdx.x;
    const int wv = tid >> 6, lane = tid & 63;
    const int cw = wv / M_WAVES, mw = wv % M_WAVES;
    const int co_w0 = co_base + cw * 32;
    const int cbw = (co_base >> 4) + cw * 2;
    const int m_w0 = mw * 32;
    const int q = lane >> 4, l15 = lane & 15;
    const ushort_t* __restrict__ wspL = wsp + (size_t)lane * 8;

    const int r0 = i - 1 + di, r1 = i + di;
    const bool v0 = (r0 >= 0), v1 = (r1 < Hin);
    const int r0c = v0 ? r0 : 0, r1c = v1 ? r1 : 0;

    f32x4 acc[2][2][2];                            // [cf][mf][dj]
    #pragma unroll
    for (int a = 0; a < 2; ++a)
        #pragma unroll
        for (int b = 0; b < 2; ++b)
            #pragma unroll
            for (int d = 0; d < 2; ++d) acc[a][b][d] = (f32x4){0.f, 0.f, 0.f, 0.f};

    // per-thread staging segments (mapping identical to round-4 kernel)
    int sc0[NSEG], sci[NSEG], sA[NSEG], sgr[NSEG]; bool sok[NSEG];
    #pragma unroll
    for (int j = 0; j < NSEG; ++j) {
        const int seg = tid + 256 * j;
        sc0[j] = (seg % SEGW) * 4;
        const int rem = seg / SEGW;
        sA[j] = rem & 1;
        sci[j] = rem >> 1;
        sok[j] = sA[j] ? v1 : v0;
        sgr[j] = sA[j] ? r1c : r0c;
    }

    float sv[NSEG][5];

    auto stage_load = [&](int ci0) {
        #pragma unroll
        for (int j = 0; j < NSEG; ++j) {
            const float* rp = x + ((size_t)(n * Cin + ci0 + sci[j]) * Hin + sgr[j]) * Win;
            const int c0 = sc0[j];
            sv[j][0] = (sok[j] && c0 > 0) ? rp[c0 - 1] : 0.f;
            #pragma unroll
            for (int t = 1; t < 5; ++t) sv[j][t] = sok[j] ? rp[c0 + t - 1] : 0.f;
        }
    };
    auto stage_write = [&](int buf) {
        unsigned int* __restrict__ dst = (unsigned int*)Xs + buf * BUFD;
        #pragma unroll
        for (int j = 0; j < NSEG; ++j) {
            ushort_t sp[5];
            #pragma unroll
            for (int t = 0; t < 5; ++t) sp[t] = f2bf(sv[j][t]);
            const int c0 = sc0[j];
            const int base = (sci[j] * 2 + sA[j]) * 2 * NDp;
            dst[base + (c0 >> 1)]           = (unsigned)sp[1] | ((unsigned)sp[2] << 16);
            dst[base + (c0 >> 1) + 1]       = (unsigned)sp[3] | ((unsigned)sp[4] << 16);
            dst[base + NDp + (c0 >> 1)]     = (unsigned)sp[0] | ((unsigned)sp[1] << 16);
            dst[base + NDp + (c0 >> 1) + 1] = (unsigned)sp[2] | ((unsigned)sp[3] << 16);
            if (c0 == Win - 4)
                dst[base + NDp + (Win >> 1)] = (unsigned)sp[4];
        }
    };

    // weight fragment loader: [dj][cf], one coalesced 1KB segment each
    auto ldw = [&](bf16x8 (&dst)[2][2], int g) {
        #pragma unroll
        for (int dj = 0; dj < 2; ++dj)
            #pragma unroll
            for (int cf = 0; cf < 2; ++cf)
                dst[dj][cf] = *(const bf16x8*)(wspL +
                    (((size_t)(2 * di + dj) * KST + g) * CB + cbw + cf) * 512);
    };

    bf16x8 afA[2][2], afB[2][2];
    ldw(afA, 0);

    stage_load(0);
    stage_write(0);
    __syncthreads();

    for (int kcI = 0; kcI < KCH; ++kcI) {
        const int cur = kcI & 1;
        const unsigned int* __restrict__ Xr = (unsigned int*)Xs + cur * BUFD;

        if (kcI + 1 < KCH) stage_load((kcI + 1) * KC);
        __builtin_amdgcn_sched_barrier(0);

        __builtin_amdgcn_s_setprio(1);
        #pragma unroll
        for (int csi = 0; csi < KC / 8; ++csi) {
            bf16x8 (&cw_)[2][2] = (csi & 1) ? afB : afA;
            bf16x8 (&nw_)[2][2] = (csi & 1) ? afA : afB;
            const int g = kcI * (KC / 8) + csi;
            if (g + 1 < KST) ldw(nw_, g + 1);

            const int ciA = csi * 8 + q * 2;
            bf16x8 bfr[2][2];                      // [dj][mf]
            #pragma unroll
            for (int dj = 0; dj < 2; ++dj)
                #pragma unroll
                for (int mf = 0; mf < 2; ++mf) {
                    const int m = m_w0 + mf * 16 + l15;
                    const int c = m - 1 + dj;
                    const int copy = c & 1;
                    const int idx = (c + 1) >> 1;
                    u32x4 bd;
                    bd.x = Xr[((ciA)     * 2 + 0) * 2 * NDp + copy * NDp + idx];
                    bd.y = Xr[((ciA)     * 2 + 1) * 2 * NDp + copy * NDp + idx];
                    bd.z = Xr[((ciA + 1) * 2 + 0) * 2 * NDp + copy * NDp + idx];
                    bd.w = Xr[((ciA + 1) * 2 + 1) * 2 * NDp + copy * NDp + idx];
                    bfr[dj][mf] = __builtin_bit_cast(bf16x8, bd);
                }
            #pragma unroll
            for (int cf = 0; cf < 2; ++cf)
                #pragma unroll
                for (int mf = 0; mf < 2; ++mf)
                    #pragma unroll
                    for (int dj = 0; dj < 2; ++dj)
                        acc[cf][mf][dj] = __builtin_amdgcn_mfma_f32_16x16x32_bf16(
                            cw_[dj][cf], bfr[dj][mf], acc[cf][mf][dj], 0, 0, 0);
        }
        __builtin_amdgcn_s_setprio(0);

        if (kcI + 1 < KCH) {
            stage_write(cur ^ 1);
            __syncthreads();
        }
    }

    constexpr int Ho2 = Hin * 2, Wo2 = Win * 2;
    const int orow = 2 * i + di;
    #pragma unroll
    for (int cf = 0; cf < 2; ++cf)
        #pragma unroll
        for (int mf = 0; mf < 2; ++mf) {
            const int ocol0 = 2 * (m_w0 + mf * 16 + l15);
            #pragma unroll
            for (int rg = 0; rg < 4; ++rg) {
                const int co = co_w0 + cf * 16 + q * 4 + rg;
                const float b = bias[co];
                float2 o2;
                o2.x = acc[cf][mf][0][rg] + b;
                o2.y = acc[cf][mf][1][rg] + b;
                *(float2*)&y[(((size_t)n * Cout + co) * Ho2 + orow) * Wo2 + ocol0] = o2;
            }
        }
}

// ============== conv k4 s2 p1 (round-3 proven fp32) — enc0 only ============
template <int Cin, int Cout, int Hin, int Win, int CO_T>
__global__ __launch_bounds__(256) void conv4s2_k(
    const float* __restrict__ x, const float* __restrict__ w,
    const float* __restrict__ bias, float* __restrict__ y)
{
    constexpr int Hout = Hin / 2, Wout = Win / 2, Wt = Wout / 4;
    const int n   = blockIdx.z;
    const int co0 = blockIdx.y * CO_T;
    const int local = blockIdx.x * 256 + threadIdx.x;
    const int wt = local & (Wt - 1);
    const int oh = local / Wt;
    const int iw0 = (wt << 3) - 1;
    const int ih0 = (oh << 1) - 1;

    const float* __restrict__ xn = x + (size_t)n * Cin * Hin * Win;
    const float* __restrict__ wb = w + (size_t)co0 * Cin * 16;

    const bool cL = (wt > 0);
    const bool cR = (wt < Wt - 1);

    float acc[CO_T][4];
    #pragma unroll
    for (int u = 0; u < CO_T; ++u)
        acc[u][0] = acc[u][1] = acc[u][2] = acc[u][3] = 0.f;

    bool rv[4]; int ro[4];
    #pragma unroll
    for (int k = 0; k < 4; ++k) {
        int r = ih0 + k;
        rv[k] = (r >= 0) && (r < Hin);
        ro[k] = rv[k] ? r : 0;
    }

    for (int ci = 0; ci < Cin; ++ci) {
        const float* xp = xn + (size_t)ci * Hin * Win;
        float xv[4][10];
        #pragma unroll
        for (int k = 0; k < 4; ++k) {
            const float* rp = xp + (size_t)ro[k] * Win;
            float4 m0 = *(const float4*)(rp + (wt << 3));
            float4 m1 = *(const float4*)(rp + (wt << 3) + 4);
            float e0 = cL ? rp[iw0] : 0.f;
            float e9 = cR ? rp[iw0 + 9] : 0.f;
            bool rk = rv[k];
            xv[k][0] = rk ? e0 : 0.f;
            xv[k][1] = rk ? m0.x : 0.f;
            xv[k][2] = rk ? m0.y : 0.f;
            xv[k][3] = rk ? m0.z : 0.f;
            xv[k][4] = rk ? m0.w : 0.f;
            xv[k][5] = rk ? m1.x : 0.f;
            xv[k][6] = rk ? m1.y : 0.f;
            xv[k][7] = rk ? m1.z : 0.f;
            xv[k][8] = rk ? m1.w : 0.f;
            xv[k][9] = rk ? e9 : 0.f;
        }
        #pragma unroll
        for (int u = 0; u < CO_T; ++u) {
            const float* wp = wb + ((size_t)u * Cin + ci) * 16;
            #pragma unroll
            for (int kh = 0; kh < 4; ++kh) {
                #pragma unroll
                for (int kw = 0; kw < 4; ++kw) {
                    float wv = wp[kh * 4 + kw];
                    acc[u][0] = fmaf(xv[kh][kw + 0], wv, acc[u][0]);
                    acc[u][1] = fmaf(xv[kh][kw + 2], wv, acc[u][1]);
                    acc[u][2] = fmaf(xv[kh][kw + 4], wv, acc[u][2]);
                    acc[u][3] = fmaf(xv[kh][kw + 6], wv, acc[u][3]);
                }
            }
        }
    }

    #pragma unroll
    for (int u = 0; u < CO_T; ++u) {
        float b = bias[co0 + u];
        float4 o;
        o.x = acc[u][0] + b; o.y = acc[u][1] + b;
        o.z = acc[u][2] + b; o.w = acc[u][3] + b;
        float* yp = y + (((size_t)(n * Cout + co0 + u)) * Hout + oh) * Wout + (wt << 2);
        *(float4*)yp = o;
    }
}

// ==================== GroupNorm 2-stage (proven) ===========================
__global__ __launch_bounds__(256) void gn_stats(
    const float* __restrict__ y, float2* __restrict__ part,
    int HWshift, int grpC, int K)
{
    const int kblk = blockIdx.x;
    const int bg = blockIdx.y;
    const int b = bg >> 5, g = bg & 31;
    const int C = grpC << 5;
    const size_t base = ((size_t)b * C + (size_t)g * grpC) << HWshift;
    const int count4 = (grpC << HWshift) >> 2;
    const int chunk4 = count4 / K;
    const int ofs4 = kblk * chunk4;
    const float4* y4 = (const float4*)(y + base);

    float s = 0.f, ss = 0.f;
    for (int i = ofs4 + threadIdx.x; i < ofs4 + chunk4; i += 256) {
        float4 v = y4[i];
        s += v.x + v.y + v.z + v.w;
        ss = fmaf(v.x, v.x, ss); ss = fmaf(v.y, v.y, ss);
        ss = fmaf(v.z, v.z, ss); ss = fmaf(v.w, v.w, ss);
    }
    __shared__ float sh0[256];
    __shared__ float sh1[256];
    sh0[threadIdx.x] = s; sh1[threadIdx.x] = ss;
    __syncthreads();
    for (int off = 128; off > 0; off >>= 1) {
        if (threadIdx.x < off) {
            sh0[threadIdx.x] += sh0[threadIdx.x + off];
            sh1[threadIdx.x] += sh1[threadIdx.x + off];
        }
        __syncthreads();
    }
    if (threadIdx.x == 0) {
        float2 pp; pp.x = sh0[0]; pp.y = sh1[0];
        part[bg * K + kblk] = pp;
    }
}

__global__ __launch_bounds__(256) void gn_apply(
    float* __restrict__ y, const float* __restrict__ gamma,
    const float* __restrict__ beta, const float2* __restrict__ part,
    int HWshift, int grpC, int K)
{
    const int kblk = blockIdx.x;
    const int bg = blockIdx.y;
    const int b = bg >> 5, g = bg & 31;
    const int C = grpC << 5;
    const size_t base = ((size_t)b * C + (size_t)g * grpC) << HWshift;
    const int count4 = (grpC << HWshift) >> 2;
    const int chunk4 = count4 / K;
    const int ofs4 = kblk * chunk4;
    float4* y4 = (float4*)(y + base);

    float s = 0.f, ss = 0.f;
    for (int k = 0; k < K; ++k) {
        float2 pp = part[bg * K + k];
        s += pp.x; ss += pp.y;
    }
    const float inv = 1.f / (float)(count4 * 4);
    const float mean = s * inv;
    const float var = ss * inv - mean * mean;
    const float rstd = rsqrtf(var + EPS);

    const int HW4shift = HWshift - 2;
    for (int i = ofs4 + threadIdx.x; i < ofs4 + chunk4; i += 256) {
        int c = g * grpC + (i >> HW4shift);
        float ga = gamma[c], be = beta[c];
        float4 v = y4[i];
        float t0 = (v.x - mean) * rstd * ga + be;
        float t1 = (v.y - mean) * rstd * ga + be;
        float t2 = (v.z - mean) * rstd * ga + be;
        float t3 = (v.w - mean) * rstd * ga + be;
        v.x = t0 / (1.f + __expf(-t0));
        v.y = t1 / (1.f + __expf(-t1));
        v.z = t2 / (1.f + __expf(-t2));
        v.w = t3 / (1.f + __expf(-t3));
        y4[i] = v;
    }
}

// ====================== 1x1 conv (proven) ==================================
template <int Cin, int Cout, int HW, int CO_T>
__global__ __launch_bounds__(256) void conv1x1_k(
    const float* __restrict__ x, const float* __restrict__ w,
    const float* __restrict__ bias, float* __restrict__ y)
{
    const int n = blockIdx.z;
    const int co0 = blockIdx.y * CO_T;
    const int s = blockIdx.x * 256 + threadIdx.x;
    const float* xp = x + (size_t)n * Cin * HW + s;

    float acc[CO_T];
    #pragma unroll
    for (int u = 0; u < CO_T; ++u) acc[u] = bias[co0 + u];

    for (int ci = 0; ci < Cin; ++ci) {
        float v = xp[(size_t)ci * HW];
        #pragma unroll
        for (int u = 0; u < CO_T; ++u)
            acc[u] = fmaf(v, w[(size_t)(co0 + u) * Cin + ci], acc[u]);
    }
    #pragma unroll
    for (int u = 0; u < CO_T; ++u)
        y[(size_t)(n * Cout + co0 + u) * HW + s] = acc[u];
}

// ============================== VQ (proven) ================================
__global__ __launch_bounds__(256) void cb_norm(
    const float* __restrict__ cb, float* __restrict__ cn)
{
    int j = blockIdx.x * 256 + threadIdx.x;
    const float* c = cb + (size_t)j * 32;
    float s = 0.f;
    #pragma unroll
    for (int k = 0; k < 32; ++k) s = fmaf(c[k], c[k], s);
    cn[j] = s;
}

__global__ __launch_bounds__(256) void vq_kernel(
    const float* __restrict__ z, const float* __restrict__ cb,
    const float* __restrict__ cn, float* __restrict__ q,
    float* __restrict__ idxf)
{
    const int row = blockIdx.x * 4 + (threadIdx.x >> 6);
    const int lane = threadIdx.x & 63;
    const float* zr = z + (size_t)row * 32;
    float zreg[32];
    #pragma unroll
    for (int k = 0; k < 32; ++k) zreg[k] = zr[k];
    float zn = 0.f;
    #pragma unroll
    for (int k = 0; k < 32; ++k) zn = fmaf(zreg[k], zreg[k], zn);

    float best = 3.4e38f;
    int bj = 0;
    for (int ii = 0; ii < 16; ++ii) {
        int j = lane * 16 + ii;
        const float* c = cb + (size_t)j * 32;
        float dot = 0.f;
        #pragma unroll
        for (int k = 0; k < 32; ++k) dot = fmaf(zreg[k], c[k], dot);
        float d = zn + cn[j] - 2.f * dot;
        if (d < best) { best = d; bj = j; }
    }
    #pragma unroll
    for (int off = 1; off < 64; off <<= 1) {
        float ob = __shfl_xor(best, off);
        int oj = __shfl_xor(bj, off);
        if (ob < best || (ob == best && oj < bj)) { best = ob; bj = oj; }
    }
    if (lane < 32) q[(size_t)row * 32 + lane] = cb[(size_t)bj * 32 + lane];
    if (lane == 0) idxf[row] = (float)bj;
}

// ======= fp32 convT (round-4 proven) — dec3 (Cout=3, tanh) =================
template <int Cin, int CO_T, int CICHUNK>
__device__ __forceinline__ void stage_weights(
    const float* __restrict__ wb, int ci0, float4* __restrict__ lds4)
{
    constexpr int W4 = CICHUNK * CO_T * 4;
    for (int g4 = threadIdx.x; g4 < W4; g4 += blockDim.x) {
        int u = g4 / (CICHUNK * 4);
        int r4 = g4 - u * (CICHUNK * 4);
        lds4[g4] = ((const float4*)(wb + (size_t)u * Cin * 16 + (size_t)ci0 * 16))[r4];
    }
}

template <int Cin, int Cout, int Hin, int Win, int CO_T, int CICHUNK, bool TANH>
__global__ __launch_bounds__(256) void convt2_lds(
    const float* __restrict__ x, const float* __restrict__ w,
    const float* __restrict__ bias, float* __restrict__ y)
{
    constexpr int Wt2 = Win / 2;
    __shared__ float4 wlds[CICHUNK * CO_T * 4];

    const int n = blockIdx.z;
    const int co0 = blockIdx.y * CO_T;
    const int local = blockIdx.x * 256 + threadIdx.x;
    const int jt = local & (Wt2 - 1);
    const int i = local / Wt2;
    const int j0 = jt << 1;

    const float* __restrict__ xn = x + (size_t)n * Cin * Hin * Win;
    const float* __restrict__ wb = w + (size_t)co0 * Cin * 16;

    const bool rm0 = (i > 0), rm2 = (i + 1 < Hin);
    const bool cmL = (jt > 0), cmR = (jt < Wt2 - 1);
    const int ro0 = rm0 ? (i - 1) : 0;
    const int ro2 = rm2 ? (i + 1) : 0;

    float acc[CO_T][2][4];
    #pragma unroll
    for (int u = 0; u < CO_T; ++u)
        #pragma unroll
        for (int p = 0; p < 2; ++p)
            acc[u][p][0] = acc[u][p][1] = acc[u][p][2] = acc[u][p][3] = 0.f;

    for (int ci0 = 0; ci0 < Cin; ci0 += CICHUNK) {
        if (ci0) __syncthreads();
        stage_weights<Cin, CO_T, CICHUNK>(wb, ci0, wlds);
        __syncthreads();

        for (int cic = 0; cic < CICHUNK; ++cic) {
            const int ci = ci0 + cic;
            const float* xp = xn + (size_t)ci * Hin * Win;
            float xr[3][4];
            {
                const int rows[3] = {ro0, i, ro2};
                const bool rvn[3] = {rm0, true, rm2};
                #pragma unroll
                for (int r = 0; r < 3; ++r) {
                    const float* rp = xp + (size_t)rows[r] * Win;
                    float2 m = *(const float2*)(rp + j0);
                    float eL = cmL ? rp[j0 - 1] : 0.f;
                    float eR = cmR ? rp[j0 + 2] : 0.f;
                    bool rk = rvn[r];
                    xr[r][0] = rk ? eL : 0.f;
                    xr[r][1] = rk ? m.x : 0.f;
                    xr[r][2] = rk ? m.y : 0.f;
                    xr[r][3] = rk ? eR : 0.f;
                }
            }
            #pragma unroll
            for (int u = 0; u < CO_T; ++u) {
                const int wbase = (cic * CO_T + u) * 4;
                float4 wq0 = wlds[wbase + 0];
                float4 wq1 = wlds[wbase + 1];
                float4 wq2 = wlds[wbase + 2];
                float4 wq3 = wlds[wbase + 3];
                #pragma unroll
                for (int p = 0; p < 2; ++p) {
                    float x00 = xr[0][p], x01 = xr[0][p + 1], x02 = xr[0][p + 2];
                    float x10 = xr[1][p], x11 = xr[1][p + 1], x12 = xr[1][p + 2];
                    float x20 = xr[2][p], x21 = xr[2][p + 1], x22 = xr[2][p + 2];
                    float* a = acc[u][p];
                    a[0] = fmaf(x00, wq0.x, a[0]); a[0] = fmaf(x01, wq0.z, a[0]);
                    a[0] = fmaf(x10, wq2.x, a[0]); a[0] = fmaf(x11, wq2.z, a[0]);
                    a[1] = fmaf(x01, wq0.y, a[1]); a[1] = fmaf(x02, wq0.w, a[1]);
                    a[1] = fmaf(x11, wq2.y, a[1]); a[1] = fmaf(x12, wq2.w, a[1]);
                    a[2] = fmaf(x10, wq1.x, a[2]); a[2] = fmaf(x11, wq1.z, a[2]);
                    a[2] = fmaf(x20, wq3.x, a[2]); a[2] = fmaf(x21, wq3.z, a[2]);
                    a[3] = fmaf(x11, wq1.y, a[3]); a[3] = fmaf(x12, wq1.w, a[3]);
                    a[3] = fmaf(x21, wq3.y, a[3]); a[3] = fmaf(x22, wq3.w, a[3]);
                }
            }
        }
    }

    constexpr int Hout = Hin * 2, Wout = Win * 2;
    #pragma unroll
    for (int u = 0; u < CO_T; ++u) {
        float b = bias[co0 + u];
        float r00 = acc[u][0][0] + b, r01 = acc[u][0][1] + b;
        float r02 = acc[u][1][0] + b, r03 = acc[u][1][1] + b;
        float r10 = acc[u][0][2] + b, r11 = acc[u][0][3] + b;
        float r12 = acc[u][1][2] + b, r13 = acc[u][1][3] + b;
        if (TANH) {
            r00 = tanhf(r00); r01 = tanhf(r01); r02 = tanhf(r02); r03 = tanhf(r03);
            r10 = tanhf(r10); r11 = tanhf(r11); r12 = tanhf(r12); r13 = tanhf(r13);
        }
        float* yp = y + (((size_t)(n * Cout + co0 + u)) * Hout + (i << 1)) * Wout + (jt << 2);
        float4 o;
        o.x = r00; o.y = r01; o.z = r02; o.w = r03; *(float4*)yp = o;
        o.x = r10; o.y = r11; o.z = r12; o.w = r13; *(float4*)(yp + Wout) = o;
    }
}

// ================================ launch ===================================
extern "C" void kernel_launch(void* const* d_in, const int* in_sizes, int n_in,
                              void* d_out, int out_size, void* d_ws, size_t ws_size,
                              hipStream_t stream)
{
    const float* x       = (const float*)d_in[0];
    const float* enc0_w  = (const float*)d_in[1];
    const float* enc0_b  = (const float*)d_in[2];
    const float* enc0_g  = (const float*)d_in[3];
    const float* enc0_bt = (const float*)d_in[4];
    const float* enc1_w  = (const float*)d_in[5];
    const float* enc1_b  = (const float*)d_in[6];
    const float* enc1_g  = (const float*)d_in[7];
    const float* enc1_bt = (const float*)d_in[8];
    const float* enc2_w  = (const float*)d_in[9];
    const float* enc2_b  = (const float*)d_in[10];
    const float* enc2_g  = (const float*)d_in[11];
    const float* enc2_bt = (const float*)d_in[12];
    const float* enc3_w  = (const float*)d_in[13];
    const float* enc3_b  = (const float*)d_in[14];
    const float* codebook= (const float*)d_in[15];
    const float* dec0_w  = (const float*)d_in[16];
    const float* dec0_b  = (const float*)d_in[17];
    const float* dec1_w  = (const float*)d_in[18];
    const float* dec1_b  = (const float*)d_in[19];
    const float* dec1_g  = (const float*)d_in[20];
    const float* dec1_bt = (const float*)d_in[21];
    const float* dec2_w  = (const float*)d_in[22];
    const float* dec2_b  = (const float*)d_in[23];
    const float* dec2_g  = (const float*)d_in[24];
    const float* dec2_bt = (const float*)d_in[25];
    const float* dec3_w  = (const float*)d_in[26];
    const float* dec3_b  = (const float*)d_in[27];

    float* ws = (float*)d_ws;
    float*  A  = ws;                       // 33,554,432 floats (134 MB)
    float*  B  = ws + 33554432;            // 16,777,216 floats (67 MB)
    float*  C  = ws + 50331648;            //  8,388,608 floats (33.6 MB)
    float*  Z  = ws + 58720256;            //    524,288 floats (2 MB)
    float*  CN = ws + 59244544;            //      1,024 floats
    float2* GP = (float2*)(ws + 59245568); //      8,192 float2 (gn partials)

    // split-weight scratch, time-multiplexed:
    ushort_t* WE1 = (ushort_t*)C;                 // enc1 (3.1 MB); C dead pre-enc2
    ushort_t* WE2 = (ushort_t*)A;                 // enc2 (12.6 MB); A dead post-enc1
    ushort_t* WD1 = (ushort_t*)C;                 // dec1 (4.2 MB); C dead post-enc3
    ushort_t* WD2 = (ushort_t*)(C + 4194304);     // dec2 (1 MB)

    float* out   = (float*)d_out;
    float* recon = out;                    // 3,145,728 floats
    float* qbuf  = out + 3145728;          //   524,288 floats
    float* idxf  = out + 3670016;          //    16,384 floats

    const dim3 blk(256);
    const dim3 blk512(512);
    const int K = 16;
    const dim3 gngrid(K, 512);

    // ---------------- encoder ----------------
    wsplit_enc<256, 128><<<dim3(2048), blk, 0, stream>>>(enc1_w, WE1);

    conv4s2_k<3, 128, 256, 256, 8><<<dim3(16, 16, 16), blk, 0, stream>>>(
        x, enc0_w, enc0_b, A);
    gn_stats<<<gngrid, blk, 0, stream>>>(A, GP, 14, 4, K);
    gn_apply<<<gngrid, blk, 0, stream>>>(A, enc0_g, enc0_bt, GP, 14, 4, K);

    // enc1: 16x128x128x128 -> 16x256x64x64  (MFMA tap-GEMM, 8-wave pipelined)
    mfenc<128, 256, 128, 128><<<dim3(128, 1, 16), blk512, 0, stream>>>(
        A, WE1, enc1_b, B);

    wsplit_enc<512, 256><<<dim3(8192), blk, 0, stream>>>(enc2_w, WE2);

    gn_stats<<<gngrid, blk, 0, stream>>>(B, GP, 12, 8, K);
    gn_apply<<<gngrid, blk, 0, stream>>>(B, enc1_g, enc1_bt, GP, 12, 8, K);

    // enc2: -> 16x512x32x32  (MFMA tap-GEMM, 8-wave pipelined)
    mfenc<256, 512, 64, 64><<<dim3(32, 2, 16), blk512, 0, stream>>>(
        B, WE2, enc2_b, C);
    gn_stats<<<gngrid, blk, 0, stream>>>(C, GP, 10, 16, K);
    gn_apply<<<gngrid, blk, 0, stream>>>(C, enc2_g, enc2_bt, GP, 10, 16, K);

    conv1x1_k<512, 32, 1024, 8><<<dim3(4, 4, 16), blk, 0, stream>>>(
        C, enc3_w, enc3_b, Z);

    // ---------------- VQ ----------------
    cb_norm<<<dim3(4), blk, 0, stream>>>(codebook, CN);
    vq_kernel<<<dim3(16384 / 4), blk, 0, stream>>>(Z, codebook, CN, qbuf, idxf);

    // ---------------- decoder ---------------------------------------------
    wsplit_convt<256, 512><<<dim3(8192), blk, 0, stream>>>(dec1_w, WD1);
    wsplit_convt<128, 256><<<dim3(2048), blk, 0, stream>>>(dec2_w, WD2);

    conv1x1_k<32, 512, 1024, 8><<<dim3(4, 64, 16), blk, 0, stream>>>(
        qbuf, dec0_w, dec0_b, A);

    // dec1: 16x512x32x32 -> 16x256x64x64  (dj-merged, pipelined)
    mfconvt<512, 256, 32, 32, 4, 1, 32><<<dim3(64, 2, 16), blk, 0, stream>>>(
        A, WD1, dec1_b, B);
    gn_stats<<<gngrid, blk, 0, stream>>>(B, GP, 12, 8, K);
    gn_apply<<<gngrid, blk, 0, stream>>>(B, dec1_g, dec1_bt, GP, 12, 8, K);

    // dec2: 16x256x64x64 -> 16x128x128x128  (dj-merged, pipelined)
    mfconvt<256, 128, 64, 64, 2, 2, 32><<<dim3(128, 2, 16), blk, 0, stream>>>(
        B, WD2, dec2_b, A);
    gn_stats<<<gngrid, blk, 0, stream>>>(A, GP, 14, 4, K);
    gn_apply<<<gngrid, blk, 0, stream>>>(A, dec2_g, dec2_bt, GP, 14, 4, K);

    convt2_lds<128, 3, 128, 128, 3, 128, true><<<dim3(32, 1, 16), blk, 0, stream>>>(
        A, dec3_w, dec3_b, recon);
}

// Round 6
// 2123.213 us; speedup vs baseline: 1.6058x; 1.0022x over previous
//
#include <hip/hip_runtime.h>
#include <hip/hip_bf16.h>
#include <math.h>

// ---------------------------------------------------------------------------
// VQGAN forward, round 15.
//  - mfenc v7: trade intra-block LDS double-buffer for inter-block overlap.
//    * single 52224 B LDS buffer -> 3 blocks/CU (24 waves, 6/SIMD), was
//      1 block/CU (104 KB dbuf, 2 waves/SIMD). Round-5 counters: wall
//      ~41k cyc/chunk vs ~12-15k busy -> stalls dominate; co-resident
//      blocks fill them.
//    * keeps: 512 threads, register pipeline (chunk k+1's 40 loads issued
//      before chunk k's MFMA phase), fragment-order weight register dbuf.
//    * cost: 2 barriers/chunk (reads drain before in-place stage_write) —
//      hidden by cross-block TLP.
//    * staged values/slots, weight bits, accumulation order unchanged ->
//      z bit-identical -> idx exact.
//  - mfconvt v2 (round-14, dj-merged pipelined) unchanged.
// d_out = [recon 16*3*256*256 | q 16*32*32*32 | idx-as-float 16384]
// ---------------------------------------------------------------------------

#define EPS 1e-5f
typedef unsigned short ushort_t;
typedef unsigned int uint32;
typedef __attribute__((ext_vector_type(8))) short bf16x8;
typedef __attribute__((ext_vector_type(4))) float f32x4;
typedef __attribute__((ext_vector_type(4))) unsigned int u32x4;

__device__ __forceinline__ ushort_t f2bf(float x) {
    __hip_bfloat16 h = __float2bfloat16(x);
    return __builtin_bit_cast(ushort_t, h);
}
__device__ __forceinline__ float bf2f(ushort_t u) {
    __hip_bfloat16 h = __builtin_bit_cast(__hip_bfloat16, u);
    return __bfloat162float(h);
}
template <int NS>
__device__ __forceinline__ void splitNS(float x, ushort_t* p) {
    float r = x;
    #pragma unroll
    for (int s = 0; s < NS; ++s) {
        ushort_t u = f2bf(r);
        p[s] = u;
        if (s + 1 < NS) r -= bf2f(u);
    }
}

// ============ encoder weight pre-split: fragment-order layout ==============
template <int Cout, int Cin>
__global__ __launch_bounds__(256) void wsplit_enc(
    const float* __restrict__ w, ushort_t* __restrict__ o)
{
    constexpr int KCH = Cin / 32, CB = Cout / 16;
    int idx = blockIdx.x * 256 + threadIdx.x;
    if (idx >= Cout * Cin * 16) return;
    int tap = idx & 15;
    int ci  = (idx >> 4) % Cin;
    int co  = (idx >> 4) / Cin;
    ushort_t sp[3];
    splitNS<3>(w[idx], sp);
    const int kc = ci >> 5, q = (ci >> 3) & 3, e = ci & 7;
    const int cb = co >> 4, l15 = co & 15;
    const int lane = q * 16 + l15;
    #pragma unroll
    for (int s = 0; s < 3; ++s)
        o[((((size_t)(s * 16 + tap) * KCH + kc) * CB + cb) * 64 + lane) * 8 + e] = sp[s];
}

// A-fragment loader: one coalesced 1KB segment per (cf,s) wave load.
template <int KCH, int CB>
__device__ __forceinline__ void ldaf2(bf16x8 (&dst)[2][3],
    const ushort_t* __restrict__ wsp_t, int kc, int tap)
{
    #pragma unroll
    for (int cf = 0; cf < 2; ++cf)
        #pragma unroll
        for (int s = 0; s < 3; ++s)
            dst[cf][s] = *(const bf16x8*)(wsp_t +
                ((size_t)((s * 16 + tap) * KCH + kc) * CB + cf) * 512);
}

// ================= MFMA encoder conv k4 s2 p1: tap-GEMMs ===================
// v7: 512 threads, single LDS buffer, reg-pipelined staging, 2 barriers/chunk.
template <int Cin, int Cout, int Hin, int Win>
__global__ __launch_bounds__(512) void mfenc(
    const float* __restrict__ x, const ushort_t* __restrict__ wsp,
    const float* __restrict__ bias, float* __restrict__ y)
{
    constexpr int Hout = Hin / 2, Wout = Win / 2;
    constexpr int MB = 32;
    constexpr int MT = Wout / MB;
    constexpr int NCOL = 66;
    constexpr int KC = 32;
    constexpr int KCH = Cin / 32;
    constexpr int CB = Cout / 16;
    constexpr int BUFW = 3 * 4 * 4 * 68 * 8;       // ushorts (52224 B)
    __shared__ ushort_t Xs[BUFW];

    const int n  = blockIdx.z;
    const int oh = blockIdx.x / MT;
    const int mt = blockIdx.x % MT;
    const int M0 = mt * MB;
    const int co_base = blockIdx.y * 256;
    const int tid = threadIdx.x;
    const int wv = tid >> 6, lane = tid & 63;
    const int q = lane >> 4, l15 = lane & 15;
    const int co_w0 = co_base + wv * 32;           // 2 co-blocks per wave
    const int cb0 = (co_base >> 4) + wv * 2;
    const ushort_t* __restrict__ wsp_t = wsp + ((size_t)cb0 * 64 + lane) * 8;

    int ro[4]; bool rv[4];
    #pragma unroll
    for (int k = 0; k < 4; ++k) {
        int r = 2 * oh - 1 + k;
        rv[k] = (r >= 0) && (r < Hin);
        ro[k] = rv[k] ? r : 0;
    }

    f32x4 acc[2][2];
    #pragma unroll
    for (int a = 0; a < 2; ++a)
        #pragma unroll
        for (int b = 0; b < 2; ++b) acc[a][b] = (f32x4){0.f, 0.f, 0.f, 0.f};

    const bool stg = (tid < 256);
    const int p16  = (tid >> 4) & 15;
    const int cg   = tid & 15;
    const int sciq = p16 >> 2;
    const int cieP = p16 & 3;

    float a0[4][5], a1[4][5];

    auto stage_load = [&](int ci0) {
        const float* b0 = x + (size_t)(n * Cin + ci0 + 2 * p16) * Hin * Win;
        const float* b1 = b0 + (size_t)Hin * Win;
        #pragma unroll
        for (int r = 0; r < 4; ++r) {
            const float* rp0 = b0 + (size_t)ro[r] * Win;
            const float* rp1 = b1 + (size_t)ro[r] * Win;
            #pragma unroll
            for (int t = 0; t < 5; ++t) {
                const int c = cg + 16 * t;
                const int gc = 2 * M0 - 1 + c;
                const bool ok = rv[r] && (c < NCOL) && (gc >= 0) && (gc < Win);
                a0[r][t] = ok ? rp0[gc] : 0.f;
                a1[r][t] = ok ? rp1[gc] : 0.f;
            }
        }
    };
    auto stage_write = [&]() {
        uint32* __restrict__ dst32 = (uint32*)Xs;
        #pragma unroll
        for (int r = 0; r < 4; ++r)
            #pragma unroll
            for (int t = 0; t < 5; ++t) {
                const int c = cg + 16 * t;
                if (c < NCOL) {
                    ushort_t s0[3], s1[3];
                    splitNS<3>(a0[r][t], s0);
                    splitNS<3>(a1[r][t], s1);
                    const int cpos = (c >> 1) + (c & 1) * 34;
                    #pragma unroll
                    for (int s = 0; s < 3; ++s)
                        dst32[((((s * 4 + r) * 4 + sciq) * 68) + cpos) * 4 + cieP] =
                            (uint32)s0[s] | ((uint32)s1[s] << 16);
                }
            }
    };

    bf16x8 afA[2][3], afB[2][3];
    ldaf2<KCH, CB>(afA, wsp_t, 0, 0);

    if (stg) {
        stage_load(0);
        stage_write();
    }
    __syncthreads();

    for (int kc = 0; kc < KCH; ++kc) {
        // issue next chunk's global loads now; latency hides under MFMA
        if (stg && kc + 1 < KCH) stage_load((kc + 1) * KC);
        __builtin_amdgcn_sched_barrier(0);   // pin load issue ahead of MFMA

        __builtin_amdgcn_s_setprio(1);
        #pragma unroll
        for (int tap = 0; tap < 16; ++tap) {
            bf16x8 (&cw)[2][3] = (tap & 1) ? afB : afA;
            bf16x8 (&nw)[2][3] = (tap & 1) ? afA : afB;
            if (tap < 15) {
                ldaf2<KCH, CB>(nw, wsp_t, kc, tap + 1);
            } else if (kc + 1 < KCH) {
                ldaf2<KCH, CB>(nw, wsp_t, kc + 1, 0);
            }

            const int kh = tap >> 2, kw = tap & 3;
            bf16x8 bx[2][3];
            const int cpbase = (kw >> 1) + (kw & 1) * 34;
            #pragma unroll
            for (int mf = 0; mf < 2; ++mf) {
                const int cpos = (mf * 16 + l15) + cpbase;
                #pragma unroll
                for (int s = 0; s < 3; ++s)
                    bx[mf][s] = *(const bf16x8*)(&Xs[((((s * 4 + kh) * 4 + q) * 68) + cpos) * 8]);
            }
            #pragma unroll
            for (int sa = 0; sa < 3; ++sa)
                #pragma unroll
                for (int sb = 0; sb < 3; ++sb) {
                    if (sa + sb >= 3) continue;
                    #pragma unroll
                    for (int cf = 0; cf < 2; ++cf)
                        #pragma unroll
                        for (int mf = 0; mf < 2; ++mf)
                            acc[cf][mf] = __builtin_amdgcn_mfma_f32_16x16x32_bf16(
                                cw[cf][sa], bx[mf][sb], acc[cf][mf], 0, 0, 0);
                }
        }
        __builtin_amdgcn_s_setprio(0);

        if (kc + 1 < KCH) {
            __syncthreads();                 // all reads of Xs done
            if (stg) stage_write();          // in-place refill
            __syncthreads();                 // writes visible
        }
    }

    #pragma unroll
    for (int cf = 0; cf < 2; ++cf)
        #pragma unroll
        for (int mf = 0; mf < 2; ++mf) {
            const int ow = M0 + mf * 16 + l15;
            #pragma unroll
            for (int rg = 0; rg < 4; ++rg) {
                const int co = co_w0 + cf * 16 + q * 4 + rg;
                y[(((size_t)n * Cout + co) * Hout + oh) * Wout + ow] =
                    acc[cf][mf][rg] + bias[co];
            }
        }
}

// ========= decoder weight pre-split v2: fragment-order layout ==============
template <int Cout, int Cin>
__global__ __launch_bounds__(256) void wsplit_convt(
    const float* __restrict__ w, ushort_t* __restrict__ o)
{
    constexpr int KST = Cin / 8;
    constexpr int CB = Cout / 16;
    int idx = blockIdx.x * 256 + threadIdx.x;
    if (idx >= 4 * KST * CB * 512) return;
    const int e = idx & 7;
    const int lane = (idx >> 3) & 63;
    int rest = idx >> 9;
    const int cb = rest % CB; rest /= CB;
    const int kst = rest % KST;
    const int p = rest / KST;
    const int q = lane >> 4, l15 = lane & 15;
    const int co = cb * 16 + l15;
    const int kf = kst * 32 + q * 8 + e;
    const int ci = kf >> 2, a = (kf >> 1) & 1, b = kf & 1;
    const int di = p >> 1, dj = p & 1;
    const float v = w[(((size_t)co * Cin + ci) * 4 + (2 * a + di)) * 4 + (2 * b + dj)];
    o[idx] = f2bf(v);
}

// ================= MFMA convT v2: dj-merged, pipelined =====================
template <int Cin, int Cout, int Hin, int Win, int CO_WAVES, int M_WAVES, int KC>
__global__ __launch_bounds__(256) void mfconvt(
    const float* __restrict__ x, const ushort_t* __restrict__ wsp,
    const float* __restrict__ bias, float* __restrict__ y)
{
    constexpr int NDp = Win / 2 + 2;
    constexpr int CO_B = CO_WAVES * 32;
    constexpr int KST = Cin / 8;
    constexpr int CB = Cout / 16;
    constexpr int KCH = Cin / KC;
    constexpr int SEGW = Win / 4;
    constexpr int SEGS = KC * 2 * SEGW;
    constexpr int NSEG = SEGS / 256;
    constexpr int BUFD = KC * 2 * 2 * NDp;         // dwords per LDS buffer
    static_assert(CO_WAVES * M_WAVES == 4, "4 waves");
    static_assert(M_WAVES * 32 == Win, "block spans full row");
    static_assert(KC % 8 == 0 && SEGS % 256 == 0, "seg mapping");
    static_assert((KC / 8) % 2 == 0, "even steps per chunk for wdbuf parity");
    __shared__ unsigned int Xs[2 * BUFD];

    const int bi = blockIdx.x;
    const int i  = bi >> 1;
    const int di = bi & 1;
    const int n = blockIdx.z;
    const int co_base = blockIdx.y * CO_B;
    const int tid = threadIdx.x;
    const int wv = tid >> 6, lane = tid & 63;
    const int cw = wv / M_WAVES, mw = wv % M_WAVES;
    const int co_w0 = co_base + cw * 32;
    const int cbw = (co_base >> 4) + cw * 2;
    const int m_w0 = mw * 32;
    const int q = lane >> 4, l15 = lane & 15;
    const ushort_t* __restrict__ wspL = wsp + (size_t)lane * 8;

    const int r0 = i - 1 + di, r1 = i + di;
    const bool v0 = (r0 >= 0), v1 = (r1 < Hin);
    const int r0c = v0 ? r0 : 0, r1c = v1 ? r1 : 0;

    f32x4 acc[2][2][2];                            // [cf][mf][dj]
    #pragma unroll
    for (int a = 0; a < 2; ++a)
        #pragma unroll
        for (int b = 0; b < 2; ++b)
            #pragma unroll
            for (int d = 0; d < 2; ++d) acc[a][b][d] = (f32x4){0.f, 0.f, 0.f, 0.f};

    int sc0[NSEG], sci[NSEG], sA[NSEG], sgr[NSEG]; bool sok[NSEG];
    #pragma unroll
    for (int j = 0; j < NSEG; ++j) {
        const int seg = tid + 256 * j;
        sc0[j] = (seg % SEGW) * 4;
        const int rem = seg / SEGW;
        sA[j] = rem & 1;
        sci[j] = rem >> 1;
        sok[j] = sA[j] ? v1 : v0;
        sgr[j] = sA[j] ? r1c : r0c;
    }

    float sv[NSEG][5];

    auto stage_load = [&](int ci0) {
        #pragma unroll
        for (int j = 0; j < NSEG; ++j) {
            const float* rp = x + ((size_t)(n * Cin + ci0 + sci[j]) * Hin + sgr[j]) * Win;
            const int c0 = sc0[j];
            sv[j][0] = (sok[j] && c0 > 0) ? rp[c0 - 1] : 0.f;
            #pragma unroll
            for (int t = 1; t < 5; ++t) sv[j][t] = sok[j] ? rp[c0 + t - 1] : 0.f;
        }
    };
    auto stage_write = [&](int buf) {
        unsigned int* __restrict__ dst = (unsigned int*)Xs + buf * BUFD;
        #pragma unroll
        for (int j = 0; j < NSEG; ++j) {
            ushort_t sp[5];
            #pragma unroll
            for (int t = 0; t < 5; ++t) sp[t] = f2bf(sv[j][t]);
            const int c0 = sc0[j];
            const int base = (sci[j] * 2 + sA[j]) * 2 * NDp;
            dst[base + (c0 >> 1)]           = (unsigned)sp[1] | ((unsigned)sp[2] << 16);
            dst[base + (c0 >> 1) + 1]       = (unsigned)sp[3] | ((unsigned)sp[4] << 16);
            dst[base + NDp + (c0 >> 1)]     = (unsigned)sp[0] | ((unsigned)sp[1] << 16);
            dst[base + NDp + (c0 >> 1) + 1] = (unsigned)sp[2] | ((unsigned)sp[3] << 16);
            if (c0 == Win - 4)
                dst[base + NDp + (Win >> 1)] = (unsigned)sp[4];
        }
    };

    auto ldw = [&](bf16x8 (&dst)[2][2], int g) {
        #pragma unroll
        for (int dj = 0; dj < 2; ++dj)
            #pragma unroll
            for (int cf = 0; cf < 2; ++cf)
                dst[dj][cf] = *(const bf16x8*)(wspL +
                    (((size_t)(2 * di + dj) * KST + g) * CB + cbw + cf) * 512);
    };

    bf16x8 afA[2][2], afB[2][2];
    ldw(afA, 0);

    stage_load(0);
    stage_write(0);
    __syncthreads();

    for (int kcI = 0; kcI < KCH; ++kcI) {
        const int cur = kcI & 1;
        const unsigned int* __restrict__ Xr = (unsigned int*)Xs + cur * BUFD;

        if (kcI + 1 < KCH) stage_load((kcI + 1) * KC);
        __builtin_amdgcn_sched_barrier(0);

        __builtin_amdgcn_s_setprio(1);
        #pragma unroll
        for (int csi = 0; csi < KC / 8; ++csi) {
            bf16x8 (&cw_)[2][2] = (csi & 1) ? afB : afA;
            bf16x8 (&nw_)[2][2] = (csi & 1) ? afA : afB;
            const int g = kcI * (KC / 8) + csi;
            if (g + 1 < KST) ldw(nw_, g + 1);

            const int ciA = csi * 8 + q * 2;
            bf16x8 bfr[2][2];                      // [dj][mf]
            #pragma unroll
            for (int dj = 0; dj < 2; ++dj)
                #pragma unroll
                for (int mf = 0; mf < 2; ++mf) {
                    const int m = m_w0 + mf * 16 + l15;
                    const int c = m - 1 + dj;
                    const int copy = c & 1;
                    const int idx = (c + 1) >> 1;
                    u32x4 bd;
                    bd.x = Xr[((ciA)     * 2 + 0) * 2 * NDp + copy * NDp + idx];
                    bd.y = Xr[((ciA)     * 2 + 1) * 2 * NDp + copy * NDp + idx];
                    bd.z = Xr[((ciA + 1) * 2 + 0) * 2 * NDp + copy * NDp + idx];
                    bd.w = Xr[((ciA + 1) * 2 + 1) * 2 * NDp + copy * NDp + idx];
                    bfr[dj][mf] = __builtin_bit_cast(bf16x8, bd);
                }
            #pragma unroll
            for (int cf = 0; cf < 2; ++cf)
                #pragma unroll
                for (int mf = 0; mf < 2; ++mf)
                    #pragma unroll
                    for (int dj = 0; dj < 2; ++dj)
                        acc[cf][mf][dj] = __builtin_amdgcn_mfma_f32_16x16x32_bf16(
                            cw_[dj][cf], bfr[dj][mf], acc[cf][mf][dj], 0, 0, 0);
        }
        __builtin_amdgcn_s_setprio(0);

        if (kcI + 1 < KCH) {
            stage_write(cur ^ 1);
            __syncthreads();
        }
    }

    constexpr int Ho2 = Hin * 2, Wo2 = Win * 2;
    const int orow = 2 * i + di;
    #pragma unroll
    for (int cf = 0; cf < 2; ++cf)
        #pragma unroll
        for (int mf = 0; mf < 2; ++mf) {
            const int ocol0 = 2 * (m_w0 + mf * 16 + l15);
            #pragma unroll
            for (int rg = 0; rg < 4; ++rg) {
                const int co = co_w0 + cf * 16 + q * 4 + rg;
                const float b = bias[co];
                float2 o2;
                o2.x = acc[cf][mf][0][rg] + b;
                o2.y = acc[cf][mf][1][rg] + b;
                *(float2*)&y[(((size_t)n * Cout + co) * Ho2 + orow) * Wo2 + ocol0] = o2;
            }
        }
}

// ============== conv k4 s2 p1 (round-3 proven fp32) — enc0 only ============
template <int Cin, int Cout, int Hin, int Win, int CO_T>
__global__ __launch_bounds__(256) void conv4s2_k(
    const float* __restrict__ x, const float* __restrict__ w,
    const float* __restrict__ bias, float* __restrict__ y)
{
    constexpr int Hout = Hin / 2, Wout = Win / 2, Wt = Wout / 4;
    const int n   = blockIdx.z;
    const int co0 = blockIdx.y * CO_T;
    const int local = blockIdx.x * 256 + threadIdx.x;
    const int wt = local & (Wt - 1);
    const int oh = local / Wt;
    const int iw0 = (wt << 3) - 1;
    const int ih0 = (oh << 1) - 1;

    const float* __restrict__ xn = x + (size_t)n * Cin * Hin * Win;
    const float* __restrict__ wb = w + (size_t)co0 * Cin * 16;

    const bool cL = (wt > 0);
    const bool cR = (wt < Wt - 1);

    float acc[CO_T][4];
    #pragma unroll
    for (int u = 0; u < CO_T; ++u)
        acc[u][0] = acc[u][1] = acc[u][2] = acc[u][3] = 0.f;

    bool rv[4]; int ro[4];
    #pragma unroll
    for (int k = 0; k < 4; ++k) {
        int r = ih0 + k;
        rv[k] = (r >= 0) && (r < Hin);
        ro[k] = rv[k] ? r : 0;
    }

    for (int ci = 0; ci < Cin; ++ci) {
        const float* xp = xn + (size_t)ci * Hin * Win;
        float xv[4][10];
        #pragma unroll
        for (int k = 0; k < 4; ++k) {
            const float* rp = xp + (size_t)ro[k] * Win;
            float4 m0 = *(const float4*)(rp + (wt << 3));
            float4 m1 = *(const float4*)(rp + (wt << 3) + 4);
            float e0 = cL ? rp[iw0] : 0.f;
            float e9 = cR ? rp[iw0 + 9] : 0.f;
            bool rk = rv[k];
            xv[k][0] = rk ? e0 : 0.f;
            xv[k][1] = rk ? m0.x : 0.f;
            xv[k][2] = rk ? m0.y : 0.f;
            xv[k][3] = rk ? m0.z : 0.f;
            xv[k][4] = rk ? m0.w : 0.f;
            xv[k][5] = rk ? m1.x : 0.f;
            xv[k][6] = rk ? m1.y : 0.f;
            xv[k][7] = rk ? m1.z : 0.f;
            xv[k][8] = rk ? m1.w : 0.f;
            xv[k][9] = rk ? e9 : 0.f;
        }
        #pragma unroll
        for (int u = 0; u < CO_T; ++u) {
            const float* wp = wb + ((size_t)u * Cin + ci) * 16;
            #pragma unroll
            for (int kh = 0; kh < 4; ++kh) {
                #pragma unroll
                for (int kw = 0; kw < 4; ++kw) {
                    float wv = wp[kh * 4 + kw];
                    acc[u][0] = fmaf(xv[kh][kw + 0], wv, acc[u][0]);
                    acc[u][1] = fmaf(xv[kh][kw + 2], wv, acc[u][1]);
                    acc[u][2] = fmaf(xv[kh][kw + 4], wv, acc[u][2]);
                    acc[u][3] = fmaf(xv[kh][kw + 6], wv, acc[u][3]);
                }
            }
        }
    }

    #pragma unroll
    for (int u = 0; u < CO_T; ++u) {
        float b = bias[co0 + u];
        float4 o;
        o.x = acc[u][0] + b; o.y = acc[u][1] + b;
        o.z = acc[u][2] + b; o.w = acc[u][3] + b;
        float* yp = y + (((size_t)(n * Cout + co0 + u)) * Hout + oh) * Wout + (wt << 2);
        *(float4*)yp = o;
    }
}

// ==================== GroupNorm 2-stage (proven) ===========================
__global__ __launch_bounds__(256) void gn_stats(
    const float* __restrict__ y, float2* __restrict__ part,
    int HWshift, int grpC, int K)
{
    const int kblk = blockIdx.x;
    const int bg = blockIdx.y;
    const int b = bg >> 5, g = bg & 31;
    const int C = grpC << 5;
    const size_t base = ((size_t)b * C + (size_t)g * grpC) << HWshift;
    const int count4 = (grpC << HWshift) >> 2;
    const int chunk4 = count4 / K;
    const int ofs4 = kblk * chunk4;
    const float4* y4 = (const float4*)(y + base);

    float s = 0.f, ss = 0.f;
    for (int i = ofs4 + threadIdx.x; i < ofs4 + chunk4; i += 256) {
        float4 v = y4[i];
        s += v.x + v.y + v.z + v.w;
        ss = fmaf(v.x, v.x, ss); ss = fmaf(v.y, v.y, ss);
        ss = fmaf(v.z, v.z, ss); ss = fmaf(v.w, v.w, ss);
    }
    __shared__ float sh0[256];
    __shared__ float sh1[256];
    sh0[threadIdx.x] = s; sh1[threadIdx.x] = ss;
    __syncthreads();
    for (int off = 128; off > 0; off >>= 1) {
        if (threadIdx.x < off) {
            sh0[threadIdx.x] += sh0[threadIdx.x + off];
            sh1[threadIdx.x] += sh1[threadIdx.x + off];
        }
        __syncthreads();
    }
    if (threadIdx.x == 0) {
        float2 pp; pp.x = sh0[0]; pp.y = sh1[0];
        part[bg * K + kblk] = pp;
    }
}

__global__ __launch_bounds__(256) void gn_apply(
    float* __restrict__ y, const float* __restrict__ gamma,
    const float* __restrict__ beta, const float2* __restrict__ part,
    int HWshift, int grpC, int K)
{
    const int kblk = blockIdx.x;
    const int bg = blockIdx.y;
    const int b = bg >> 5, g = bg & 31;
    const int C = grpC << 5;
    const size_t base = ((size_t)b * C + (size_t)g * grpC) << HWshift;
    const int count4 = (grpC << HWshift) >> 2;
    const int chunk4 = count4 / K;
    const int ofs4 = kblk * chunk4;
    float4* y4 = (float4*)(y + base);

    float s = 0.f, ss = 0.f;
    for (int k = 0; k < K; ++k) {
        float2 pp = part[bg * K + k];
        s += pp.x; ss += pp.y;
    }
    const float inv = 1.f / (float)(count4 * 4);
    const float mean = s * inv;
    const float var = ss * inv - mean * mean;
    const float rstd = rsqrtf(var + EPS);

    const int HW4shift = HWshift - 2;
    for (int i = ofs4 + threadIdx.x; i < ofs4 + chunk4; i += 256) {
        int c = g * grpC + (i >> HW4shift);
        float ga = gamma[c], be = beta[c];
        float4 v = y4[i];
        float t0 = (v.x - mean) * rstd * ga + be;
        float t1 = (v.y - mean) * rstd * ga + be;
        float t2 = (v.z - mean) * rstd * ga + be;
        float t3 = (v.w - mean) * rstd * ga + be;
        v.x = t0 / (1.f + __expf(-t0));
        v.y = t1 / (1.f + __expf(-t1));
        v.z = t2 / (1.f + __expf(-t2));
        v.w = t3 / (1.f + __expf(-t3));
        y4[i] = v;
    }
}

// ====================== 1x1 conv (proven) ==================================
template <int Cin, int Cout, int HW, int CO_T>
__global__ __launch_bounds__(256) void conv1x1_k(
    const float* __restrict__ x, const float* __restrict__ w,
    const float* __restrict__ bias, float* __restrict__ y)
{
    const int n = blockIdx.z;
    const int co0 = blockIdx.y * CO_T;
    const int s = blockIdx.x * 256 + threadIdx.x;
    const float* xp = x + (size_t)n * Cin * HW + s;

    float acc[CO_T];
    #pragma unroll
    for (int u = 0; u < CO_T; ++u) acc[u] = bias[co0 + u];

    for (int ci = 0; ci < Cin; ++ci) {
        float v = xp[(size_t)ci * HW];
        #pragma unroll
        for (int u = 0; u < CO_T; ++u)
            acc[u] = fmaf(v, w[(size_t)(co0 + u) * Cin + ci], acc[u]);
    }
    #pragma unroll
    for (int u = 0; u < CO_T; ++u)
        y[(size_t)(n * Cout + co0 + u) * HW + s] = acc[u];
}

// ============================== VQ (proven) ================================
__global__ __launch_bounds__(256) void cb_norm(
    const float* __restrict__ cb, float* __restrict__ cn)
{
    int j = blockIdx.x * 256 + threadIdx.x;
    const float* c = cb + (size_t)j * 32;
    float s = 0.f;
    #pragma unroll
    for (int k = 0; k < 32; ++k) s = fmaf(c[k], c[k], s);
    cn[j] = s;
}

__global__ __launch_bounds__(256) void vq_kernel(
    const float* __restrict__ z, const float* __restrict__ cb,
    const float* __restrict__ cn, float* __restrict__ q,
    float* __restrict__ idxf)
{
    const int row = blockIdx.x * 4 + (threadIdx.x >> 6);
    const int lane = threadIdx.x & 63;
    const float* zr = z + (size_t)row * 32;
    float zreg[32];
    #pragma unroll
    for (int k = 0; k < 32; ++k) zreg[k] = zr[k];
    float zn = 0.f;
    #pragma unroll
    for (int k = 0; k < 32; ++k) zn = fmaf(zreg[k], zreg[k], zn);

    float best = 3.4e38f;
    int bj = 0;
    for (int ii = 0; ii < 16; ++ii) {
        int j = lane * 16 + ii;
        const float* c = cb + (size_t)j * 32;
        float dot = 0.f;
        #pragma unroll
        for (int k = 0; k < 32; ++k) dot = fmaf(zreg[k], c[k], dot);
        float d = zn + cn[j] - 2.f * dot;
        if (d < best) { best = d; bj = j; }
    }
    #pragma unroll
    for (int off = 1; off < 64; off <<= 1) {
        float ob = __shfl_xor(best, off);
        int oj = __shfl_xor(bj, off);
        if (ob < best || (ob == best && oj < bj)) { best = ob; bj = oj; }
    }
    if (lane < 32) q[(size_t)row * 32 + lane] = cb[(size_t)bj * 32 + lane];
    if (lane == 0) idxf[row] = (float)bj;
}

// ======= fp32 convT (round-4 proven) — dec3 (Cout=3, tanh) =================
template <int Cin, int CO_T, int CICHUNK>
__device__ __forceinline__ void stage_weights(
    const float* __restrict__ wb, int ci0, float4* __restrict__ lds4)
{
    constexpr int W4 = CICHUNK * CO_T * 4;
    for (int g4 = threadIdx.x; g4 < W4; g4 += blockDim.x) {
        int u = g4 / (CICHUNK * 4);
        int r4 = g4 - u * (CICHUNK * 4);
        lds4[g4] = ((const float4*)(wb + (size_t)u * Cin * 16 + (size_t)ci0 * 16))[r4];
    }
}

template <int Cin, int Cout, int Hin, int Win, int CO_T, int CICHUNK, bool TANH>
__global__ __launch_bounds__(256) void convt2_lds(
    const float* __restrict__ x, const float* __restrict__ w,
    const float* __restrict__ bias, float* __restrict__ y)
{
    constexpr int Wt2 = Win / 2;
    __shared__ float4 wlds[CICHUNK * CO_T * 4];

    const int n = blockIdx.z;
    const int co0 = blockIdx.y * CO_T;
    const int local = blockIdx.x * 256 + threadIdx.x;
    const int jt = local & (Wt2 - 1);
    const int i = local / Wt2;
    const int j0 = jt << 1;

    const float* __restrict__ xn = x + (size_t)n * Cin * Hin * Win;
    const float* __restrict__ wb = w + (size_t)co0 * Cin * 16;

    const bool rm0 = (i > 0), rm2 = (i + 1 < Hin);
    const bool cmL = (jt > 0), cmR = (jt < Wt2 - 1);
    const int ro0 = rm0 ? (i - 1) : 0;
    const int ro2 = rm2 ? (i + 1) : 0;

    float acc[CO_T][2][4];
    #pragma unroll
    for (int u = 0; u < CO_T; ++u)
        #pragma unroll
        for (int p = 0; p < 2; ++p)
            acc[u][p][0] = acc[u][p][1] = acc[u][p][2] = acc[u][p][3] = 0.f;

    for (int ci0 = 0; ci0 < Cin; ci0 += CICHUNK) {
        if (ci0) __syncthreads();
        stage_weights<Cin, CO_T, CICHUNK>(wb, ci0, wlds);
        __syncthreads();

        for (int cic = 0; cic < CICHUNK; ++cic) {
            const int ci = ci0 + cic;
            const float* xp = xn + (size_t)ci * Hin * Win;
            float xr[3][4];
            {
                const int rows[3] = {ro0, i, ro2};
                const bool rvn[3] = {rm0, true, rm2};
                #pragma unroll
                for (int r = 0; r < 3; ++r) {
                    const float* rp = xp + (size_t)rows[r] * Win;
                    float2 m = *(const float2*)(rp + j0);
                    float eL = cmL ? rp[j0 - 1] : 0.f;
                    float eR = cmR ? rp[j0 + 2] : 0.f;
                    bool rk = rvn[r];
                    xr[r][0] = rk ? eL : 0.f;
                    xr[r][1] = rk ? m.x : 0.f;
                    xr[r][2] = rk ? m.y : 0.f;
                    xr[r][3] = rk ? eR : 0.f;
                }
            }
            #pragma unroll
            for (int u = 0; u < CO_T; ++u) {
                const int wbase = (cic * CO_T + u) * 4;
                float4 wq0 = wlds[wbase + 0];
                float4 wq1 = wlds[wbase + 1];
                float4 wq2 = wlds[wbase + 2];
                float4 wq3 = wlds[wbase + 3];
                #pragma unroll
                for (int p = 0; p < 2; ++p) {
                    float x00 = xr[0][p], x01 = xr[0][p + 1], x02 = xr[0][p + 2];
                    float x10 = xr[1][p], x11 = xr[1][p + 1], x12 = xr[1][p + 2];
                    float x20 = xr[2][p], x21 = xr[2][p + 1], x22 = xr[2][p + 2];
                    float* a = acc[u][p];
                    a[0] = fmaf(x00, wq0.x, a[0]); a[0] = fmaf(x01, wq0.z, a[0]);
                    a[0] = fmaf(x10, wq2.x, a[0]); a[0] = fmaf(x11, wq2.z, a[0]);
                    a[1] = fmaf(x01, wq0.y, a[1]); a[1] = fmaf(x02, wq0.w, a[1]);
                    a[1] = fmaf(x11, wq2.y, a[1]); a[1] = fmaf(x12, wq2.w, a[1]);
                    a[2] = fmaf(x10, wq1.x, a[2]); a[2] = fmaf(x11, wq1.z, a[2]);
                    a[2] = fmaf(x20, wq3.x, a[2]); a[2] = fmaf(x21, wq3.z, a[2]);
                    a[3] = fmaf(x11, wq1.y, a[3]); a[3] = fmaf(x12, wq1.w, a[3]);
                    a[3] = fmaf(x21, wq3.y, a[3]); a[3] = fmaf(x22, wq3.w, a[3]);
                }
            }
        }
    }

    constexpr int Hout = Hin * 2, Wout = Win * 2;
    #pragma unroll
    for (int u = 0; u < CO_T; ++u) {
        float b = bias[co0 + u];
        float r00 = acc[u][0][0] + b, r01 = acc[u][0][1] + b;
        float r02 = acc[u][1][0] + b, r03 = acc[u][1][1] + b;
        float r10 = acc[u][0][2] + b, r11 = acc[u][0][3] + b;
        float r12 = acc[u][1][2] + b, r13 = acc[u][1][3] + b;
        if (TANH) {
            r00 = tanhf(r00); r01 = tanhf(r01); r02 = tanhf(r02); r03 = tanhf(r03);
            r10 = tanhf(r10); r11 = tanhf(r11); r12 = tanhf(r12); r13 = tanhf(r13);
        }
        float* yp = y + (((size_t)(n * Cout + co0 + u)) * Hout + (i << 1)) * Wout + (jt << 2);
        float4 o;
        o.x = r00; o.y = r01; o.z = r02; o.w = r03; *(float4*)yp = o;
        o.x = r10; o.y = r11; o.z = r12; o.w = r13; *(float4*)(yp + Wout) = o;
    }
}

// ================================ launch ===================================
extern "C" void kernel_launch(void* const* d_in, const int* in_sizes, int n_in,
                              void* d_out, int out_size, void* d_ws, size_t ws_size,
                              hipStream_t stream)
{
    const float* x       = (const float*)d_in[0];
    const float* enc0_w  = (const float*)d_in[1];
    const float* enc0_b  = (const float*)d_in[2];
    const float* enc0_g  = (const float*)d_in[3];
    const float* enc0_bt = (const float*)d_in[4];
    const float* enc1_w  = (const float*)d_in[5];
    const float* enc1_b  = (const float*)d_in[6];
    const float* enc1_g  = (const float*)d_in[7];
    const float* enc1_bt = (const float*)d_in[8];
    const float* enc2_w  = (const float*)d_in[9];
    const float* enc2_b  = (const float*)d_in[10];
    const float* enc2_g  = (const float*)d_in[11];
    const float* enc2_bt = (const float*)d_in[12];
    const float* enc3_w  = (const float*)d_in[13];
    const float* enc3_b  = (const float*)d_in[14];
    const float* codebook= (const float*)d_in[15];
    const float* dec0_w  = (const float*)d_in[16];
    const float* dec0_b  = (const float*)d_in[17];
    const float* dec1_w  = (const float*)d_in[18];
    const float* dec1_b  = (const float*)d_in[19];
    const float* dec1_g  = (const float*)d_in[20];
    const float* dec1_bt = (const float*)d_in[21];
    const float* dec2_w  = (const float*)d_in[22];
    const float* dec2_b  = (const float*)d_in[23];
    const float* dec2_g  = (const float*)d_in[24];
    const float* dec2_bt = (const float*)d_in[25];
    const float* dec3_w  = (const float*)d_in[26];
    const float* dec3_b  = (const float*)d_in[27];

    float* ws = (float*)d_ws;
    float*  A  = ws;                       // 33,554,432 floats (134 MB)
    float*  B  = ws + 33554432;            // 16,777,216 floats (67 MB)
    float*  C  = ws + 50331648;            //  8,388,608 floats (33.6 MB)
    float*  Z  = ws + 58720256;            //    524,288 floats (2 MB)
    float*  CN = ws + 59244544;            //      1,024 floats
    float2* GP = (float2*)(ws + 59245568); //      8,192 float2 (gn partials)

    // split-weight scratch, time-multiplexed:
    ushort_t* WE1 = (ushort_t*)C;                 // enc1 (3.1 MB); C dead pre-enc2
    ushort_t* WE2 = (ushort_t*)A;                 // enc2 (12.6 MB); A dead post-enc1
    ushort_t* WD1 = (ushort_t*)C;                 // dec1 (4.2 MB); C dead post-enc3
    ushort_t* WD2 = (ushort_t*)(C + 4194304);     // dec2 (1 MB)

    float* out   = (float*)d_out;
    float* recon = out;                    // 3,145,728 floats
    float* qbuf  = out + 3145728;          //   524,288 floats
    float* idxf  = out + 3670016;          //    16,384 floats

    const dim3 blk(256);
    const dim3 blk512(512);
    const int K = 16;
    const dim3 gngrid(K, 512);

    // ---------------- encoder ----------------
    wsplit_enc<256, 128><<<dim3(2048), blk, 0, stream>>>(enc1_w, WE1);

    conv4s2_k<3, 128, 256, 256, 8><<<dim3(16, 16, 16), blk, 0, stream>>>(
        x, enc0_w, enc0_b, A);
    gn_stats<<<gngrid, blk, 0, stream>>>(A, GP, 14, 4, K);
    gn_apply<<<gngrid, blk, 0, stream>>>(A, enc0_g, enc0_bt, GP, 14, 4, K);

    // enc1: 16x128x128x128 -> 16x256x64x64  (8-wave, single-buffer pipelined)
    mfenc<128, 256, 128, 128><<<dim3(128, 1, 16), blk512, 0, stream>>>(
        A, WE1, enc1_b, B);

    wsplit_enc<512, 256><<<dim3(8192), blk, 0, stream>>>(enc2_w, WE2);

    gn_stats<<<gngrid, blk, 0, stream>>>(B, GP, 12, 8, K);
    gn_apply<<<gngrid, blk, 0, stream>>>(B, enc1_g, enc1_bt, GP, 12, 8, K);

    // enc2: -> 16x512x32x32  (8-wave, single-buffer pipelined)
    mfenc<256, 512, 64, 64><<<dim3(32, 2, 16), blk512, 0, stream>>>(
        B, WE2, enc2_b, C);
    gn_stats<<<gngrid, blk, 0, stream>>>(C, GP, 10, 16, K);
    gn_apply<<<gngrid, blk, 0, stream>>>(C, enc2_g, enc2_bt, GP, 10, 16, K);

    conv1x1_k<512, 32, 1024, 8><<<dim3(4, 4, 16), blk, 0, stream>>>(
        C, enc3_w, enc3_b, Z);

    // ---------------- VQ ----------------
    cb_norm<<<dim3(4), blk, 0, stream>>>(codebook, CN);
    vq_kernel<<<dim3(16384 / 4), blk, 0, stream>>>(Z, codebook, CN, qbuf, idxf);

    // ---------------- decoder ---------------------------------------------
    wsplit_convt<256, 512><<<dim3(8192), blk, 0, stream>>>(dec1_w, WD1);
    wsplit_convt<128, 256><<<dim3(2048), blk, 0, stream>>>(dec2_w, WD2);

    conv1x1_k<32, 512, 1024, 8><<<dim3(4, 64, 16), blk, 0, stream>>>(
        qbuf, dec0_w, dec0_b, A);

    // dec1: 16x512x32x32 -> 16x256x64x64  (dj-merged, pipelined)
    mfconvt<512, 256, 32, 32, 4, 1, 32><<<dim3(64, 2, 16), blk, 0, stream>>>(
        A, WD1, dec1_b, B);
    gn_stats<<<gngrid, blk, 0, stream>>>(B, GP, 12, 8, K);
    gn_apply<<<gngrid, blk, 0, stream>>>(B, dec1_g, dec1_bt, GP, 12, 8, K);

    // dec2: 16x256x64x64 -> 16x128x128x128  (dj-merged, pipelined)
    mfconvt<256, 128, 64, 64, 2, 2, 32><<<dim3(128, 2, 16), blk, 0, stream>>>(
        B, WD2, dec2_b, A);
    gn_stats<<<gngrid, blk, 0, stream>>>(A, GP, 14, 4, K);
    gn_apply<<<gngrid, blk, 0, stream>>>(A, dec2_g, dec2_bt, GP, 14, 4, K);

    convt2_lds<128, 3, 128, 128, 3, 128, true><<<dim3(32, 1, 16), blk, 0, stream>>>(
        A, dec3_w, dec3_b, recon);
}

// Round 7
// 2074.367 us; speedup vs baseline: 1.6436x; 1.0235x over previous
//
#include <hip/hip_runtime.h>
#include <hip/hip_bf16.h>
#include <math.h>

// ---------------------------------------------------------------------------
// VQGAN forward, round 16.
//  - mfenc v8: break the VGPR=128 occupancy wall (round-6: LDS halved but
//    occupancy stuck at 1 block/CU -> VGPR-bound at exactly the 4-waves/SIMD
//    pool boundary).
//    * staging spread across ALL 512 threads: thread = (ci-pair, 32-wide
//      column slot) -> per-thread staged regs 40 -> 24 (-16 VGPR), loads
//      128B/wave coalesced, 36 ds_write_b32/thread (was 60 on half the
//      threads). Same bits -> same LDS slots, one writer per slot ->
//      z bit-identical -> idx exact.
//    * __launch_bounds__(512, 4) pins allocation at 4 waves/EU (2 blocks/CU).
//    * keeps: single 52224B LDS buffer, 2 barriers/chunk, reg-pipelined
//      staging, fragment-order weight register dbuf, setprio.
//  - mfconvt v2 (round-14, dj-merged pipelined) unchanged.
// d_out = [recon 16*3*256*256 | q 16*32*32*32 | idx-as-float 16384]
// ---------------------------------------------------------------------------

#define EPS 1e-5f
typedef unsigned short ushort_t;
typedef unsigned int uint32;
typedef __attribute__((ext_vector_type(8))) short bf16x8;
typedef __attribute__((ext_vector_type(4))) float f32x4;
typedef __attribute__((ext_vector_type(4))) unsigned int u32x4;

__device__ __forceinline__ ushort_t f2bf(float x) {
    __hip_bfloat16 h = __float2bfloat16(x);
    return __builtin_bit_cast(ushort_t, h);
}
__device__ __forceinline__ float bf2f(ushort_t u) {
    __hip_bfloat16 h = __builtin_bit_cast(__hip_bfloat16, u);
    return __bfloat162float(h);
}
template <int NS>
__device__ __forceinline__ void splitNS(float x, ushort_t* p) {
    float r = x;
    #pragma unroll
    for (int s = 0; s < NS; ++s) {
        ushort_t u = f2bf(r);
        p[s] = u;
        if (s + 1 < NS) r -= bf2f(u);
    }
}

// ============ encoder weight pre-split: fragment-order layout ==============
template <int Cout, int Cin>
__global__ __launch_bounds__(256) void wsplit_enc(
    const float* __restrict__ w, ushort_t* __restrict__ o)
{
    constexpr int KCH = Cin / 32, CB = Cout / 16;
    int idx = blockIdx.x * 256 + threadIdx.x;
    if (idx >= Cout * Cin * 16) return;
    int tap = idx & 15;
    int ci  = (idx >> 4) % Cin;
    int co  = (idx >> 4) / Cin;
    ushort_t sp[3];
    splitNS<3>(w[idx], sp);
    const int kc = ci >> 5, q = (ci >> 3) & 3, e = ci & 7;
    const int cb = co >> 4, l15 = co & 15;
    const int lane = q * 16 + l15;
    #pragma unroll
    for (int s = 0; s < 3; ++s)
        o[((((size_t)(s * 16 + tap) * KCH + kc) * CB + cb) * 64 + lane) * 8 + e] = sp[s];
}

// A-fragment loader: one coalesced 1KB segment per (cf,s) wave load.
template <int KCH, int CB>
__device__ __forceinline__ void ldaf2(bf16x8 (&dst)[2][3],
    const ushort_t* __restrict__ wsp_t, int kc, int tap)
{
    #pragma unroll
    for (int cf = 0; cf < 2; ++cf)
        #pragma unroll
        for (int s = 0; s < 3; ++s)
            dst[cf][s] = *(const bf16x8*)(wsp_t +
                ((size_t)((s * 16 + tap) * KCH + kc) * CB + cf) * 512);
}

// ================= MFMA encoder conv k4 s2 p1: tap-GEMMs ===================
// v8: 512 threads all staging (ci-pair x 32-col slot), single LDS buffer,
// reg-pipelined staging, 2 barriers/chunk, launch_bounds(512,4).
template <int Cin, int Cout, int Hin, int Win>
__global__ __launch_bounds__(512, 4) void mfenc(
    const float* __restrict__ x, const ushort_t* __restrict__ wsp,
    const float* __restrict__ bias, float* __restrict__ y)
{
    constexpr int Hout = Hin / 2, Wout = Win / 2;
    constexpr int MB = 32;
    constexpr int MT = Wout / MB;
    constexpr int NCOL = 66;
    constexpr int KC = 32;
    constexpr int KCH = Cin / 32;
    constexpr int CB = Cout / 16;
    constexpr int BUFW = 3 * 4 * 4 * 68 * 8;       // ushorts (52224 B)
    __shared__ ushort_t Xs[BUFW];

    const int n  = blockIdx.z;
    const int oh = blockIdx.x / MT;
    const int mt = blockIdx.x % MT;
    const int M0 = mt * MB;
    const int co_base = blockIdx.y * 256;
    const int tid = threadIdx.x;
    const int wv = tid >> 6, lane = tid & 63;
    const int q = lane >> 4, l15 = lane & 15;
    const int co_w0 = co_base + wv * 32;           // 2 co-blocks per wave
    const int cb0 = (co_base >> 4) + wv * 2;
    const ushort_t* __restrict__ wsp_t = wsp + ((size_t)cb0 * 64 + lane) * 8;

    int ro[4]; bool rv[4];
    #pragma unroll
    for (int k = 0; k < 4; ++k) {
        int r = 2 * oh - 1 + k;
        rv[k] = (r >= 0) && (r < Hin);
        ro[k] = rv[k] ? r : 0;
    }

    f32x4 acc[2][2];
    #pragma unroll
    for (int a = 0; a < 2; ++a)
        #pragma unroll
        for (int b = 0; b < 2; ++b) acc[a][b] = (f32x4){0.f, 0.f, 0.f, 0.f};

    // staging ids: ci-pair + 32-wide column slot (all 512 threads stage)
    const int p16  = tid >> 5;            // 0..15 -> ci pair (2*p16, 2*p16+1)
    const int cg5  = tid & 31;            // column slot
    const int sciq = p16 >> 2;            // ci octet 0..3
    const int cieP = p16 & 3;             // dword index within octet

    float a0[4][3], a1[4][3];             // staged values in flight

    auto stage_load = [&](int ci0) {
        const float* b0 = x + (size_t)(n * Cin + ci0 + 2 * p16) * Hin * Win;
        const float* b1 = b0 + (size_t)Hin * Win;
        #pragma unroll
        for (int r = 0; r < 4; ++r) {
            const float* rp0 = b0 + (size_t)ro[r] * Win;
            const float* rp1 = b1 + (size_t)ro[r] * Win;
            #pragma unroll
            for (int t = 0; t < 3; ++t) {
                const int c = cg5 + 32 * t;
                const int gc = 2 * M0 - 1 + c;
                const bool ok = rv[r] && (c < NCOL) && (gc >= 0) && (gc < Win);
                a0[r][t] = ok ? rp0[gc] : 0.f;
                a1[r][t] = ok ? rp1[gc] : 0.f;
            }
        }
    };
    auto stage_write = [&]() {
        uint32* __restrict__ dst32 = (uint32*)Xs;
        #pragma unroll
        for (int r = 0; r < 4; ++r)
            #pragma unroll
            for (int t = 0; t < 3; ++t) {
                const int c = cg5 + 32 * t;
                if (c < NCOL) {
                    ushort_t s0[3], s1[3];
                    splitNS<3>(a0[r][t], s0);
                    splitNS<3>(a1[r][t], s1);
                    const int cpos = (c >> 1) + (c & 1) * 34;
                    #pragma unroll
                    for (int s = 0; s < 3; ++s)
                        dst32[((((s * 4 + r) * 4 + sciq) * 68) + cpos) * 4 + cieP] =
                            (uint32)s0[s] | ((uint32)s1[s] << 16);
                }
            }
    };

    bf16x8 afA[2][3], afB[2][3];
    ldaf2<KCH, CB>(afA, wsp_t, 0, 0);

    stage_load(0);
    stage_write();
    __syncthreads();

    for (int kc = 0; kc < KCH; ++kc) {
        // issue next chunk's global loads now; latency hides under MFMA
        if (kc + 1 < KCH) stage_load((kc + 1) * KC);
        __builtin_amdgcn_sched_barrier(0);   // pin load issue ahead of MFMA

        __builtin_amdgcn_s_setprio(1);
        #pragma unroll
        for (int tap = 0; tap < 16; ++tap) {
            bf16x8 (&cw)[2][3] = (tap & 1) ? afB : afA;
            bf16x8 (&nw)[2][3] = (tap & 1) ? afA : afB;
            if (tap < 15) {
                ldaf2<KCH, CB>(nw, wsp_t, kc, tap + 1);
            } else if (kc + 1 < KCH) {
                ldaf2<KCH, CB>(nw, wsp_t, kc + 1, 0);
            }

            const int kh = tap >> 2, kw = tap & 3;
            bf16x8 bx[2][3];
            const int cpbase = (kw >> 1) + (kw & 1) * 34;
            #pragma unroll
            for (int mf = 0; mf < 2; ++mf) {
                const int cpos = (mf * 16 + l15) + cpbase;
                #pragma unroll
                for (int s = 0; s < 3; ++s)
                    bx[mf][s] = *(const bf16x8*)(&Xs[((((s * 4 + kh) * 4 + q) * 68) + cpos) * 8]);
            }
            #pragma unroll
            for (int sa = 0; sa < 3; ++sa)
                #pragma unroll
                for (int sb = 0; sb < 3; ++sb) {
                    if (sa + sb >= 3) continue;
                    #pragma unroll
                    for (int cf = 0; cf < 2; ++cf)
                        #pragma unroll
                        for (int mf = 0; mf < 2; ++mf)
                            acc[cf][mf] = __builtin_amdgcn_mfma_f32_16x16x32_bf16(
                                cw[cf][sa], bx[mf][sb], acc[cf][mf], 0, 0, 0);
                }
        }
        __builtin_amdgcn_s_setprio(0);

        if (kc + 1 < KCH) {
            __syncthreads();                 // all reads of Xs done
            stage_write();                   // in-place refill
            __syncthreads();                 // writes visible
        }
    }

    #pragma unroll
    for (int cf = 0; cf < 2; ++cf)
        #pragma unroll
        for (int mf = 0; mf < 2; ++mf) {
            const int ow = M0 + mf * 16 + l15;
            #pragma unroll
            for (int rg = 0; rg < 4; ++rg) {
                const int co = co_w0 + cf * 16 + q * 4 + rg;
                y[(((size_t)n * Cout + co) * Hout + oh) * Wout + ow] =
                    acc[cf][mf][rg] + bias[co];
            }
        }
}

// ========= decoder weight pre-split v2: fragment-order layout ==============
template <int Cout, int Cin>
__global__ __launch_bounds__(256) void wsplit_convt(
    const float* __restrict__ w, ushort_t* __restrict__ o)
{
    constexpr int KST = Cin / 8;
    constexpr int CB = Cout / 16;
    int idx = blockIdx.x * 256 + threadIdx.x;
    if (idx >= 4 * KST * CB * 512) return;
    const int e = idx & 7;
    const int lane = (idx >> 3) & 63;
    int rest = idx >> 9;
    const int cb = rest % CB; rest /= CB;
    const int kst = rest % KST;
    const int p = rest / KST;
    const int q = lane >> 4, l15 = lane & 15;
    const int co = cb * 16 + l15;
    const int kf = kst * 32 + q * 8 + e;
    const int ci = kf >> 2, a = (kf >> 1) & 1, b = kf & 1;
    const int di = p >> 1, dj = p & 1;
    const float v = w[(((size_t)co * Cin + ci) * 4 + (2 * a + di)) * 4 + (2 * b + dj)];
    o[idx] = f2bf(v);
}

// ================= MFMA convT v2: dj-merged, pipelined =====================
template <int Cin, int Cout, int Hin, int Win, int CO_WAVES, int M_WAVES, int KC>
__global__ __launch_bounds__(256) void mfconvt(
    const float* __restrict__ x, const ushort_t* __restrict__ wsp,
    const float* __restrict__ bias, float* __restrict__ y)
{
    constexpr int NDp = Win / 2 + 2;
    constexpr int CO_B = CO_WAVES * 32;
    constexpr int KST = Cin / 8;
    constexpr int CB = Cout / 16;
    constexpr int KCH = Cin / KC;
    constexpr int SEGW = Win / 4;
    constexpr int SEGS = KC * 2 * SEGW;
    constexpr int NSEG = SEGS / 256;
    constexpr int BUFD = KC * 2 * 2 * NDp;         // dwords per LDS buffer
    static_assert(CO_WAVES * M_WAVES == 4, "4 waves");
    static_assert(M_WAVES * 32 == Win, "block spans full row");
    static_assert(KC % 8 == 0 && SEGS % 256 == 0, "seg mapping");
    static_assert((KC / 8) % 2 == 0, "even steps per chunk for wdbuf parity");
    __shared__ unsigned int Xs[2 * BUFD];

    const int bi = blockIdx.x;
    const int i  = bi >> 1;
    const int di = bi & 1;
    const int n = blockIdx.z;
    const int co_base = blockIdx.y * CO_B;
    const int tid = threadIdx.x;
    const int wv = tid >> 6, lane = tid & 63;
    const int cw = wv / M_WAVES, mw = wv % M_WAVES;
    const int co_w0 = co_base + cw * 32;
    const int cbw = (co_base >> 4) + cw * 2;
    const int m_w0 = mw * 32;
    const int q = lane >> 4, l15 = lane & 15;
    const ushort_t* __restrict__ wspL = wsp + (size_t)lane * 8;

    const int r0 = i - 1 + di, r1 = i + di;
    const bool v0 = (r0 >= 0), v1 = (r1 < Hin);
    const int r0c = v0 ? r0 : 0, r1c = v1 ? r1 : 0;

    f32x4 acc[2][2][2];                            // [cf][mf][dj]
    #pragma unroll
    for (int a = 0; a < 2; ++a)
        #pragma unroll
        for (int b = 0; b < 2; ++b)
            #pragma unroll
            for (int d = 0; d < 2; ++d) acc[a][b][d] = (f32x4){0.f, 0.f, 0.f, 0.f};

    int sc0[NSEG], sci[NSEG], sA[NSEG], sgr[NSEG]; bool sok[NSEG];
    #pragma unroll
    for (int j = 0; j < NSEG; ++j) {
        const int seg = tid + 256 * j;
        sc0[j] = (seg % SEGW) * 4;
        const int rem = seg / SEGW;
        sA[j] = rem & 1;
        sci[j] = rem >> 1;
        sok[j] = sA[j] ? v1 : v0;
        sgr[j] = sA[j] ? r1c : r0c;
    }

    float sv[NSEG][5];

    auto stage_load = [&](int ci0) {
        #pragma unroll
        for (int j = 0; j < NSEG; ++j) {
            const float* rp = x + ((size_t)(n * Cin + ci0 + sci[j]) * Hin + sgr[j]) * Win;
            const int c0 = sc0[j];
            sv[j][0] = (sok[j] && c0 > 0) ? rp[c0 - 1] : 0.f;
            #pragma unroll
            for (int t = 1; t < 5; ++t) sv[j][t] = sok[j] ? rp[c0 + t - 1] : 0.f;
        }
    };
    auto stage_write = [&](int buf) {
        unsigned int* __restrict__ dst = (unsigned int*)Xs + buf * BUFD;
        #pragma unroll
        for (int j = 0; j < NSEG; ++j) {
            ushort_t sp[5];
            #pragma unroll
            for (int t = 0; t < 5; ++t) sp[t] = f2bf(sv[j][t]);
            const int c0 = sc0[j];
            const int base = (sci[j] * 2 + sA[j]) * 2 * NDp;
            dst[base + (c0 >> 1)]           = (unsigned)sp[1] | ((unsigned)sp[2] << 16);
            dst[base + (c0 >> 1) + 1]       = (unsigned)sp[3] | ((unsigned)sp[4] << 16);
            dst[base + NDp + (c0 >> 1)]     = (unsigned)sp[0] | ((unsigned)sp[1] << 16);
            dst[base + NDp + (c0 >> 1) + 1] = (unsigned)sp[2] | ((unsigned)sp[3] << 16);
            if (c0 == Win - 4)
                dst[base + NDp + (Win >> 1)] = (unsigned)sp[4];
        }
    };

    auto ldw = [&](bf16x8 (&dst)[2][2], int g) {
        #pragma unroll
        for (int dj = 0; dj < 2; ++dj)
            #pragma unroll
            for (int cf = 0; cf < 2; ++cf)
                dst[dj][cf] = *(const bf16x8*)(wspL +
                    (((size_t)(2 * di + dj) * KST + g) * CB + cbw + cf) * 512);
    };

    bf16x8 afA[2][2], afB[2][2];
    ldw(afA, 0);

    stage_load(0);
    stage_write(0);
    __syncthreads();

    for (int kcI = 0; kcI < KCH; ++kcI) {
        const int cur = kcI & 1;
        const unsigned int* __restrict__ Xr = (unsigned int*)Xs + cur * BUFD;

        if (kcI + 1 < KCH) stage_load((kcI + 1) * KC);
        __builtin_amdgcn_sched_barrier(0);

        __builtin_amdgcn_s_setprio(1);
        #pragma unroll
        for (int csi = 0; csi < KC / 8; ++csi) {
            bf16x8 (&cw_)[2][2] = (csi & 1) ? afB : afA;
            bf16x8 (&nw_)[2][2] = (csi & 1) ? afA : afB;
            const int g = kcI * (KC / 8) + csi;
            if (g + 1 < KST) ldw(nw_, g + 1);

            const int ciA = csi * 8 + q * 2;
            bf16x8 bfr[2][2];                      // [dj][mf]
            #pragma unroll
            for (int dj = 0; dj < 2; ++dj)
                #pragma unroll
                for (int mf = 0; mf < 2; ++mf) {
                    const int m = m_w0 + mf * 16 + l15;
                    const int c = m - 1 + dj;
                    const int copy = c & 1;
                    const int idx = (c + 1) >> 1;
                    u32x4 bd;
                    bd.x = Xr[((ciA)     * 2 + 0) * 2 * NDp + copy * NDp + idx];
                    bd.y = Xr[((ciA)     * 2 + 1) * 2 * NDp + copy * NDp + idx];
                    bd.z = Xr[((ciA + 1) * 2 + 0) * 2 * NDp + copy * NDp + idx];
                    bd.w = Xr[((ciA + 1) * 2 + 1) * 2 * NDp + copy * NDp + idx];
                    bfr[dj][mf] = __builtin_bit_cast(bf16x8, bd);
                }
            #pragma unroll
            for (int cf = 0; cf < 2; ++cf)
                #pragma unroll
                for (int mf = 0; mf < 2; ++mf)
                    #pragma unroll
                    for (int dj = 0; dj < 2; ++dj)
                        acc[cf][mf][dj] = __builtin_amdgcn_mfma_f32_16x16x32_bf16(
                            cw_[dj][cf], bfr[dj][mf], acc[cf][mf][dj], 0, 0, 0);
        }
        __builtin_amdgcn_s_setprio(0);

        if (kcI + 1 < KCH) {
            stage_write(cur ^ 1);
            __syncthreads();
        }
    }

    constexpr int Ho2 = Hin * 2, Wo2 = Win * 2;
    const int orow = 2 * i + di;
    #pragma unroll
    for (int cf = 0; cf < 2; ++cf)
        #pragma unroll
        for (int mf = 0; mf < 2; ++mf) {
            const int ocol0 = 2 * (m_w0 + mf * 16 + l15);
            #pragma unroll
            for (int rg = 0; rg < 4; ++rg) {
                const int co = co_w0 + cf * 16 + q * 4 + rg;
                const float b = bias[co];
                float2 o2;
                o2.x = acc[cf][mf][0][rg] + b;
                o2.y = acc[cf][mf][1][rg] + b;
                *(float2*)&y[(((size_t)n * Cout + co) * Ho2 + orow) * Wo2 + ocol0] = o2;
            }
        }
}

// ============== conv k4 s2 p1 (round-3 proven fp32) — enc0 only ============
template <int Cin, int Cout, int Hin, int Win, int CO_T>
__global__ __launch_bounds__(256) void conv4s2_k(
    const float* __restrict__ x, const float* __restrict__ w,
    const float* __restrict__ bias, float* __restrict__ y)
{
    constexpr int Hout = Hin / 2, Wout = Win / 2, Wt = Wout / 4;
    const int n   = blockIdx.z;
    const int co0 = blockIdx.y * CO_T;
    const int local = blockIdx.x * 256 + threadIdx.x;
    const int wt = local & (Wt - 1);
    const int oh = local / Wt;
    const int iw0 = (wt << 3) - 1;
    const int ih0 = (oh << 1) - 1;

    const float* __restrict__ xn = x + (size_t)n * Cin * Hin * Win;
    const float* __restrict__ wb = w + (size_t)co0 * Cin * 16;

    const bool cL = (wt > 0);
    const bool cR = (wt < Wt - 1);

    float acc[CO_T][4];
    #pragma unroll
    for (int u = 0; u < CO_T; ++u)
        acc[u][0] = acc[u][1] = acc[u][2] = acc[u][3] = 0.f;

    bool rv[4]; int ro[4];
    #pragma unroll
    for (int k = 0; k < 4; ++k) {
        int r = ih0 + k;
        rv[k] = (r >= 0) && (r < Hin);
        ro[k] = rv[k] ? r : 0;
    }

    for (int ci = 0; ci < Cin; ++ci) {
        const float* xp = xn + (size_t)ci * Hin * Win;
        float xv[4][10];
        #pragma unroll
        for (int k = 0; k < 4; ++k) {
            const float* rp = xp + (size_t)ro[k] * Win;
            float4 m0 = *(const float4*)(rp + (wt << 3));
            float4 m1 = *(const float4*)(rp + (wt << 3) + 4);
            float e0 = cL ? rp[iw0] : 0.f;
            float e9 = cR ? rp[iw0 + 9] : 0.f;
            bool rk = rv[k];
            xv[k][0] = rk ? e0 : 0.f;
            xv[k][1] = rk ? m0.x : 0.f;
            xv[k][2] = rk ? m0.y : 0.f;
            xv[k][3] = rk ? m0.z : 0.f;
            xv[k][4] = rk ? m0.w : 0.f;
            xv[k][5] = rk ? m1.x : 0.f;
            xv[k][6] = rk ? m1.y : 0.f;
            xv[k][7] = rk ? m1.z : 0.f;
            xv[k][8] = rk ? m1.w : 0.f;
            xv[k][9] = rk ? e9 : 0.f;
        }
        #pragma unroll
        for (int u = 0; u < CO_T; ++u) {
            const float* wp = wb + ((size_t)u * Cin + ci) * 16;
            #pragma unroll
            for (int kh = 0; kh < 4; ++kh) {
                #pragma unroll
                for (int kw = 0; kw < 4; ++kw) {
                    float wv = wp[kh * 4 + kw];
                    acc[u][0] = fmaf(xv[kh][kw + 0], wv, acc[u][0]);
                    acc[u][1] = fmaf(xv[kh][kw + 2], wv, acc[u][1]);
                    acc[u][2] = fmaf(xv[kh][kw + 4], wv, acc[u][2]);
                    acc[u][3] = fmaf(xv[kh][kw + 6], wv, acc[u][3]);
                }
            }
        }
    }

    #pragma unroll
    for (int u = 0; u < CO_T; ++u) {
        float b = bias[co0 + u];
        float4 o;
        o.x = acc[u][0] + b; o.y = acc[u][1] + b;
        o.z = acc[u][2] + b; o.w = acc[u][3] + b;
        float* yp = y + (((size_t)(n * Cout + co0 + u)) * Hout + oh) * Wout + (wt << 2);
        *(float4*)yp = o;
    }
}

// ==================== GroupNorm 2-stage (proven) ===========================
__global__ __launch_bounds__(256) void gn_stats(
    const float* __restrict__ y, float2* __restrict__ part,
    int HWshift, int grpC, int K)
{
    const int kblk = blockIdx.x;
    const int bg = blockIdx.y;
    const int b = bg >> 5, g = bg & 31;
    const int C = grpC << 5;
    const size_t base = ((size_t)b * C + (size_t)g * grpC) << HWshift;
    const int count4 = (grpC << HWshift) >> 2;
    const int chunk4 = count4 / K;
    const int ofs4 = kblk * chunk4;
    const float4* y4 = (const float4*)(y + base);

    float s = 0.f, ss = 0.f;
    for (int i = ofs4 + threadIdx.x; i < ofs4 + chunk4; i += 256) {
        float4 v = y4[i];
        s += v.x + v.y + v.z + v.w;
        ss = fmaf(v.x, v.x, ss); ss = fmaf(v.y, v.y, ss);
        ss = fmaf(v.z, v.z, ss); ss = fmaf(v.w, v.w, ss);
    }
    __shared__ float sh0[256];
    __shared__ float sh1[256];
    sh0[threadIdx.x] = s; sh1[threadIdx.x] = ss;
    __syncthreads();
    for (int off = 128; off > 0; off >>= 1) {
        if (threadIdx.x < off) {
            sh0[threadIdx.x] += sh0[threadIdx.x + off];
            sh1[threadIdx.x] += sh1[threadIdx.x + off];
        }
        __syncthreads();
    }
    if (threadIdx.x == 0) {
        float2 pp; pp.x = sh0[0]; pp.y = sh1[0];
        part[bg * K + kblk] = pp;
    }
}

__global__ __launch_bounds__(256) void gn_apply(
    float* __restrict__ y, const float* __restrict__ gamma,
    const float* __restrict__ beta, const float2* __restrict__ part,
    int HWshift, int grpC, int K)
{
    const int kblk = blockIdx.x;
    const int bg = blockIdx.y;
    const int b = bg >> 5, g = bg & 31;
    const int C = grpC << 5;
    const size_t base = ((size_t)b * C + (size_t)g * grpC) << HWshift;
    const int count4 = (grpC << HWshift) >> 2;
    const int chunk4 = count4 / K;
    const int ofs4 = kblk * chunk4;
    float4* y4 = (float4*)(y + base);

    float s = 0.f, ss = 0.f;
    for (int k = 0; k < K; ++k) {
        float2 pp = part[bg * K + k];
        s += pp.x; ss += pp.y;
    }
    const float inv = 1.f / (float)(count4 * 4);
    const float mean = s * inv;
    const float var = ss * inv - mean * mean;
    const float rstd = rsqrtf(var + EPS);

    const int HW4shift = HWshift - 2;
    for (int i = ofs4 + threadIdx.x; i < ofs4 + chunk4; i += 256) {
        int c = g * grpC + (i >> HW4shift);
        float ga = gamma[c], be = beta[c];
        float4 v = y4[i];
        float t0 = (v.x - mean) * rstd * ga + be;
        float t1 = (v.y - mean) * rstd * ga + be;
        float t2 = (v.z - mean) * rstd * ga + be;
        float t3 = (v.w - mean) * rstd * ga + be;
        v.x = t0 / (1.f + __expf(-t0));
        v.y = t1 / (1.f + __expf(-t1));
        v.z = t2 / (1.f + __expf(-t2));
        v.w = t3 / (1.f + __expf(-t3));
        y4[i] = v;
    }
}

// ====================== 1x1 conv (proven) ==================================
template <int Cin, int Cout, int HW, int CO_T>
__global__ __launch_bounds__(256) void conv1x1_k(
    const float* __restrict__ x, const float* __restrict__ w,
    const float* __restrict__ bias, float* __restrict__ y)
{
    const int n = blockIdx.z;
    const int co0 = blockIdx.y * CO_T;
    const int s = blockIdx.x * 256 + threadIdx.x;
    const float* xp = x + (size_t)n * Cin * HW + s;

    float acc[CO_T];
    #pragma unroll
    for (int u = 0; u < CO_T; ++u) acc[u] = bias[co0 + u];

    for (int ci = 0; ci < Cin; ++ci) {
        float v = xp[(size_t)ci * HW];
        #pragma unroll
        for (int u = 0; u < CO_T; ++u)
            acc[u] = fmaf(v, w[(size_t)(co0 + u) * Cin + ci], acc[u]);
    }
    #pragma unroll
    for (int u = 0; u < CO_T; ++u)
        y[(size_t)(n * Cout + co0 + u) * HW + s] = acc[u];
}

// ============================== VQ (proven) ================================
__global__ __launch_bounds__(256) void cb_norm(
    const float* __restrict__ cb, float* __restrict__ cn)
{
    int j = blockIdx.x * 256 + threadIdx.x;
    const float* c = cb + (size_t)j * 32;
    float s = 0.f;
    #pragma unroll
    for (int k = 0; k < 32; ++k) s = fmaf(c[k], c[k], s);
    cn[j] = s;
}

__global__ __launch_bounds__(256) void vq_kernel(
    const float* __restrict__ z, const float* __restrict__ cb,
    const float* __restrict__ cn, float* __restrict__ q,
    float* __restrict__ idxf)
{
    const int row = blockIdx.x * 4 + (threadIdx.x >> 6);
    const int lane = threadIdx.x & 63;
    const float* zr = z + (size_t)row * 32;
    float zreg[32];
    #pragma unroll
    for (int k = 0; k < 32; ++k) zreg[k] = zr[k];
    float zn = 0.f;
    #pragma unroll
    for (int k = 0; k < 32; ++k) zn = fmaf(zreg[k], zreg[k], zn);

    float best = 3.4e38f;
    int bj = 0;
    for (int ii = 0; ii < 16; ++ii) {
        int j = lane * 16 + ii;
        const float* c = cb + (size_t)j * 32;
        float dot = 0.f;
        #pragma unroll
        for (int k = 0; k < 32; ++k) dot = fmaf(zreg[k], c[k], dot);
        float d = zn + cn[j] - 2.f * dot;
        if (d < best) { best = d; bj = j; }
    }
    #pragma unroll
    for (int off = 1; off < 64; off <<= 1) {
        float ob = __shfl_xor(best, off);
        int oj = __shfl_xor(bj, off);
        if (ob < best || (ob == best && oj < bj)) { best = ob; bj = oj; }
    }
    if (lane < 32) q[(size_t)row * 32 + lane] = cb[(size_t)bj * 32 + lane];
    if (lane == 0) idxf[row] = (float)bj;
}

// ======= fp32 convT (round-4 proven) — dec3 (Cout=3, tanh) =================
template <int Cin, int CO_T, int CICHUNK>
__device__ __forceinline__ void stage_weights(
    const float* __restrict__ wb, int ci0, float4* __restrict__ lds4)
{
    constexpr int W4 = CICHUNK * CO_T * 4;
    for (int g4 = threadIdx.x; g4 < W4; g4 += blockDim.x) {
        int u = g4 / (CICHUNK * 4);
        int r4 = g4 - u * (CICHUNK * 4);
        lds4[g4] = ((const float4*)(wb + (size_t)u * Cin * 16 + (size_t)ci0 * 16))[r4];
    }
}

template <int Cin, int Cout, int Hin, int Win, int CO_T, int CICHUNK, bool TANH>
__global__ __launch_bounds__(256) void convt2_lds(
    const float* __restrict__ x, const float* __restrict__ w,
    const float* __restrict__ bias, float* __restrict__ y)
{
    constexpr int Wt2 = Win / 2;
    __shared__ float4 wlds[CICHUNK * CO_T * 4];

    const int n = blockIdx.z;
    const int co0 = blockIdx.y * CO_T;
    const int local = blockIdx.x * 256 + threadIdx.x;
    const int jt = local & (Wt2 - 1);
    const int i = local / Wt2;
    const int j0 = jt << 1;

    const float* __restrict__ xn = x + (size_t)n * Cin * Hin * Win;
    const float* __restrict__ wb = w + (size_t)co0 * Cin * 16;

    const bool rm0 = (i > 0), rm2 = (i + 1 < Hin);
    const bool cmL = (jt > 0), cmR = (jt < Wt2 - 1);
    const int ro0 = rm0 ? (i - 1) : 0;
    const int ro2 = rm2 ? (i + 1) : 0;

    float acc[CO_T][2][4];
    #pragma unroll
    for (int u = 0; u < CO_T; ++u)
        #pragma unroll
        for (int p = 0; p < 2; ++p)
            acc[u][p][0] = acc[u][p][1] = acc[u][p][2] = acc[u][p][3] = 0.f;

    for (int ci0 = 0; ci0 < Cin; ci0 += CICHUNK) {
        if (ci0) __syncthreads();
        stage_weights<Cin, CO_T, CICHUNK>(wb, ci0, wlds);
        __syncthreads();

        for (int cic = 0; cic < CICHUNK; ++cic) {
            const int ci = ci0 + cic;
            const float* xp = xn + (size_t)ci * Hin * Win;
            float xr[3][4];
            {
                const int rows[3] = {ro0, i, ro2};
                const bool rvn[3] = {rm0, true, rm2};
                #pragma unroll
                for (int r = 0; r < 3; ++r) {
                    const float* rp = xp + (size_t)rows[r] * Win;
                    float2 m = *(const float2*)(rp + j0);
                    float eL = cmL ? rp[j0 - 1] : 0.f;
                    float eR = cmR ? rp[j0 + 2] : 0.f;
                    bool rk = rvn[r];
                    xr[r][0] = rk ? eL : 0.f;
                    xr[r][1] = rk ? m.x : 0.f;
                    xr[r][2] = rk ? m.y : 0.f;
                    xr[r][3] = rk ? eR : 0.f;
                }
            }
            #pragma unroll
            for (int u = 0; u < CO_T; ++u) {
                const int wbase = (cic * CO_T + u) * 4;
                float4 wq0 = wlds[wbase + 0];
                float4 wq1 = wlds[wbase + 1];
                float4 wq2 = wlds[wbase + 2];
                float4 wq3 = wlds[wbase + 3];
                #pragma unroll
                for (int p = 0; p < 2; ++p) {
                    float x00 = xr[0][p], x01 = xr[0][p + 1], x02 = xr[0][p + 2];
                    float x10 = xr[1][p], x11 = xr[1][p + 1], x12 = xr[1][p + 2];
                    float x20 = xr[2][p], x21 = xr[2][p + 1], x22 = xr[2][p + 2];
                    float* a = acc[u][p];
                    a[0] = fmaf(x00, wq0.x, a[0]); a[0] = fmaf(x01, wq0.z, a[0]);
                    a[0] = fmaf(x10, wq2.x, a[0]); a[0] = fmaf(x11, wq2.z, a[0]);
                    a[1] = fmaf(x01, wq0.y, a[1]); a[1] = fmaf(x02, wq0.w, a[1]);
                    a[1] = fmaf(x11, wq2.y, a[1]); a[1] = fmaf(x12, wq2.w, a[1]);
                    a[2] = fmaf(x10, wq1.x, a[2]); a[2] = fmaf(x11, wq1.z, a[2]);
                    a[2] = fmaf(x20, wq3.x, a[2]); a[2] = fmaf(x21, wq3.z, a[2]);
                    a[3] = fmaf(x11, wq1.y, a[3]); a[3] = fmaf(x12, wq1.w, a[3]);
                    a[3] = fmaf(x21, wq3.y, a[3]); a[3] = fmaf(x22, wq3.w, a[3]);
                }
            }
        }
    }

    constexpr int Hout = Hin * 2, Wout = Win * 2;
    #pragma unroll
    for (int u = 0; u < CO_T; ++u) {
        float b = bias[co0 + u];
        float r00 = acc[u][0][0] + b, r01 = acc[u][0][1] + b;
        float r02 = acc[u][1][0] + b, r03 = acc[u][1][1] + b;
        float r10 = acc[u][0][2] + b, r11 = acc[u][0][3] + b;
        float r12 = acc[u][1][2] + b, r13 = acc[u][1][3] + b;
        if (TANH) {
            r00 = tanhf(r00); r01 = tanhf(r01); r02 = tanhf(r02); r03 = tanhf(r03);
            r10 = tanhf(r10); r11 = tanhf(r11); r12 = tanhf(r12); r13 = tanhf(r13);
        }
        float* yp = y + (((size_t)(n * Cout + co0 + u)) * Hout + (i << 1)) * Wout + (jt << 2);
        float4 o;
        o.x = r00; o.y = r01; o.z = r02; o.w = r03; *(float4*)yp = o;
        o.x = r10; o.y = r11; o.z = r12; o.w = r13; *(float4*)(yp + Wout) = o;
    }
}

// ================================ launch ===================================
extern "C" void kernel_launch(void* const* d_in, const int* in_sizes, int n_in,
                              void* d_out, int out_size, void* d_ws, size_t ws_size,
                              hipStream_t stream)
{
    const float* x       = (const float*)d_in[0];
    const float* enc0_w  = (const float*)d_in[1];
    const float* enc0_b  = (const float*)d_in[2];
    const float* enc0_g  = (const float*)d_in[3];
    const float* enc0_bt = (const float*)d_in[4];
    const float* enc1_w  = (const float*)d_in[5];
    const float* enc1_b  = (const float*)d_in[6];
    const float* enc1_g  = (const float*)d_in[7];
    const float* enc1_bt = (const float*)d_in[8];
    const float* enc2_w  = (const float*)d_in[9];
    const float* enc2_b  = (const float*)d_in[10];
    const float* enc2_g  = (const float*)d_in[11];
    const float* enc2_bt = (const float*)d_in[12];
    const float* enc3_w  = (const float*)d_in[13];
    const float* enc3_b  = (const float*)d_in[14];
    const float* codebook= (const float*)d_in[15];
    const float* dec0_w  = (const float*)d_in[16];
    const float* dec0_b  = (const float*)d_in[17];
    const float* dec1_w  = (const float*)d_in[18];
    const float* dec1_b  = (const float*)d_in[19];
    const float* dec1_g  = (const float*)d_in[20];
    const float* dec1_bt = (const float*)d_in[21];
    const float* dec2_w  = (const float*)d_in[22];
    const float* dec2_b  = (const float*)d_in[23];
    const float* dec2_g  = (const float*)d_in[24];
    const float* dec2_bt = (const float*)d_in[25];
    const float* dec3_w  = (const float*)d_in[26];
    const float* dec3_b  = (const float*)d_in[27];

    float* ws = (float*)d_ws;
    float*  A  = ws;                       // 33,554,432 floats (134 MB)
    float*  B  = ws + 33554432;            // 16,777,216 floats (67 MB)
    float*  C  = ws + 50331648;            //  8,388,608 floats (33.6 MB)
    float*  Z  = ws + 58720256;            //    524,288 floats (2 MB)
    float*  CN = ws + 59244544;            //      1,024 floats
    float2* GP = (float2*)(ws + 59245568); //      8,192 float2 (gn partials)

    // split-weight scratch, time-multiplexed:
    ushort_t* WE1 = (ushort_t*)C;                 // enc1 (3.1 MB); C dead pre-enc2
    ushort_t* WE2 = (ushort_t*)A;                 // enc2 (12.6 MB); A dead post-enc1
    ushort_t* WD1 = (ushort_t*)C;                 // dec1 (4.2 MB); C dead post-enc3
    ushort_t* WD2 = (ushort_t*)(C + 4194304);     // dec2 (1 MB)

    float* out   = (float*)d_out;
    float* recon = out;                    // 3,145,728 floats
    float* qbuf  = out + 3145728;          //   524,288 floats
    float* idxf  = out + 3670016;          //    16,384 floats

    const dim3 blk(256);
    const dim3 blk512(512);
    const int K = 16;
    const dim3 gngrid(K, 512);

    // ---------------- encoder ----------------
    wsplit_enc<256, 128><<<dim3(2048), blk, 0, stream>>>(enc1_w, WE1);

    conv4s2_k<3, 128, 256, 256, 8><<<dim3(16, 16, 16), blk, 0, stream>>>(
        x, enc0_w, enc0_b, A);
    gn_stats<<<gngrid, blk, 0, stream>>>(A, GP, 14, 4, K);
    gn_apply<<<gngrid, blk, 0, stream>>>(A, enc0_g, enc0_bt, GP, 14, 4, K);

    // enc1: 16x128x128x128 -> 16x256x64x64  (8-wave, all-thread staging)
    mfenc<128, 256, 128, 128><<<dim3(128, 1, 16), blk512, 0, stream>>>(
        A, WE1, enc1_b, B);

    wsplit_enc<512, 256><<<dim3(8192), blk, 0, stream>>>(enc2_w, WE2);

    gn_stats<<<gngrid, blk, 0, stream>>>(B, GP, 12, 8, K);
    gn_apply<<<gngrid, blk, 0, stream>>>(B, enc1_g, enc1_bt, GP, 12, 8, K);

    // enc2: -> 16x512x32x32  (8-wave, all-thread staging)
    mfenc<256, 512, 64, 64><<<dim3(32, 2, 16), blk512, 0, stream>>>(
        B, WE2, enc2_b, C);
    gn_stats<<<gngrid, blk, 0, stream>>>(C, GP, 10, 16, K);
    gn_apply<<<gngrid, blk, 0, stream>>>(C, enc2_g, enc2_bt, GP, 10, 16, K);

    conv1x1_k<512, 32, 1024, 8><<<dim3(4, 4, 16), blk, 0, stream>>>(
        C, enc3_w, enc3_b, Z);

    // ---------------- VQ ----------------
    cb_norm<<<dim3(4), blk, 0, stream>>>(codebook, CN);
    vq_kernel<<<dim3(16384 / 4), blk, 0, stream>>>(Z, codebook, CN, qbuf, idxf);

    // ---------------- decoder ---------------------------------------------
    wsplit_convt<256, 512><<<dim3(8192), blk, 0, stream>>>(dec1_w, WD1);
    wsplit_convt<128, 256><<<dim3(2048), blk, 0, stream>>>(dec2_w, WD2);

    conv1x1_k<32, 512, 1024, 8><<<dim3(4, 64, 16), blk, 0, stream>>>(
        qbuf, dec0_w, dec0_b, A);

    // dec1: 16x512x32x32 -> 16x256x64x64  (dj-merged, pipelined)
    mfconvt<512, 256, 32, 32, 4, 1, 32><<<dim3(64, 2, 16), blk, 0, stream>>>(
        A, WD1, dec1_b, B);
    gn_stats<<<gngrid, blk, 0, stream>>>(B, GP, 12, 8, K);
    gn_apply<<<gngrid, blk, 0, stream>>>(B, dec1_g, dec1_bt, GP, 12, 8, K);

    // dec2: 16x256x64x64 -> 16x128x128x128  (dj-merged, pipelined)
    mfconvt<256, 128, 64, 64, 2, 2, 32><<<dim3(128, 2, 16), blk, 0, stream>>>(
        B, WD2, dec2_b, A);
    gn_stats<<<gngrid, blk, 0, stream>>>(A, GP, 14, 4, K);
    gn_apply<<<gngrid, blk, 0, stream>>>(A, dec2_g, dec2_bt, GP, 14, 4, K);

    convt2_lds<128, 3, 128, 128, 3, 128, true><<<dim3(32, 1, 16), blk, 0, stream>>>(
        A, dec3_w, dec3_b, recon);
}